// Round 1
// baseline (11104.147 us; speedup 1.0000x reference)
//
#include <hip/hip_runtime.h>
#include <math.h>

#define BATCH 4
#define SEQ   2048
#define DM    512
#define DI    1024
#define DS    16
#define DR    32
#define BL    (BATCH*SEQ)   // 8192 tokens

#define BMT 64
#define BNT 64
#define BKT 16

__device__ __forceinline__ float sigmoidf_(float x){ return 1.f/(1.f+expf(-x)); }

// ---------------- FFT filter as circulant kernel ----------------
// g[k] = mask[k] + fre[k] + i*fim[k];  r[j] = Re(ifft(g))[j]
__global__ void build_filter_kernel(const float* __restrict__ fre,
                                    const float* __restrict__ fim,
                                    const float* __restrict__ cut,
                                    float* __restrict__ rker)
{
    int j = threadIdx.x;  // 512 threads
    float c0 = cut[0];
    double acc = 0.0;
    for (int k = 0; k < 512; ++k) {
        float fr = (float)(k < 256 ? k : k - 512) / 512.0f;
        float mask = (fr >= c0 || fr <= -c0) ? 1.f : 0.f;
        double gre = (double)mask + (double)fre[k];
        double gim = (double)fim[k];
        int pr = (j * k) & 511;  // exact angle reduction
        double ang = 6.283185307179586476925286766559 * (double)pr / 512.0;
        acc += gre * cos(ang) - gim * sin(ang);
    }
    rker[j] = (float)(acc / 512.0);
}

// M[n][m] = r[(n-m) mod 512]  -> xi = x @ M^T
__global__ void circ_expand_kernel(const float* __restrict__ rker, float* __restrict__ Mc)
{
    int n = blockIdx.x, m = threadIdx.x;
    Mc[n*512 + m] = rker[(n - m) & 511];
}

// ---------------- generic tiled fp32 GEMM: C = epi(A @ W^T + bias) ----------------
// A: M x K (row stride lda), W: N x K (contiguous), C: M x N (row stride ldc)
// EPI: 0 none, 1 softplus, 2 gelu(exact), 3 silu.  accflag: C += v instead of C = v
template<int EPI>
__launch_bounds__(256)
__global__ void gemm_kernel(const float* __restrict__ A, int lda,
                            const float* __restrict__ W,
                            const float* __restrict__ bias,
                            float* __restrict__ C, int ldc,
                            int K, int accflag)
{
    __shared__ float As[BKT][BMT];
    __shared__ float Ws[BKT][BNT];
    int t  = threadIdx.x;
    int lr = t >> 2;          // 0..63 tile row
    int lc = (t & 3) << 2;    // 0,4,8,12 k offset
    const float* Ag = A + (size_t)(blockIdx.y*BMT + lr)*lda + lc;
    const float* Wg = W + (size_t)(blockIdx.x*BNT + lr)*K   + lc;
    int tm = (t & 15) << 2;
    int tn = (t >> 4) << 2;
    float acc[4][4] = {};
    for (int kt = 0; kt < K; kt += BKT) {
        float4 av = *(const float4*)(Ag + kt);
        float4 wv = *(const float4*)(Wg + kt);
        __syncthreads();
        As[lc+0][lr]=av.x; As[lc+1][lr]=av.y; As[lc+2][lr]=av.z; As[lc+3][lr]=av.w;
        Ws[lc+0][lr]=wv.x; Ws[lc+1][lr]=wv.y; Ws[lc+2][lr]=wv.z; Ws[lc+3][lr]=wv.w;
        __syncthreads();
        #pragma unroll
        for (int k = 0; k < BKT; ++k) {
            const float4 a4 = *(const float4*)&As[k][tm];
            const float4 w4 = *(const float4*)&Ws[k][tn];
            float ar[4] = {a4.x,a4.y,a4.z,a4.w};
            float wr[4] = {w4.x,w4.y,w4.z,w4.w};
            #pragma unroll
            for (int i=0;i<4;++i)
                #pragma unroll
                for (int j=0;j<4;++j)
                    acc[i][j] = fmaf(ar[i], wr[j], acc[i][j]);
        }
    }
    size_t crow = (size_t)(blockIdx.y*BMT + tm);
    int ccol = blockIdx.x*BNT + tn;
    #pragma unroll
    for (int i=0;i<4;++i) {
        float* Cp = C + (crow+i)*ldc + ccol;
        #pragma unroll
        for (int j=0;j<4;++j) {
            float v = acc[i][j];
            if (bias) v += bias[ccol+j];
            if (EPI==1) v = (v > 20.f) ? v : log1pf(expf(v));
            else if (EPI==2) v = 0.5f*v*(1.f+erff(v*0.70710678118654752440f));
            else if (EPI==3) v = v*sigmoidf_(v);
            if (accflag) Cp[j] += v; else Cp[j] = v;
        }
    }
}

// ---------------- depthwise causal conv (k=4) + silu ----------------
// input = x-part of xz (row stride 2048). rev: read time-reversed (branch 2).
__launch_bounds__(256)
__global__ void conv_silu_kernel(const float* __restrict__ xz,
                                 const float* __restrict__ cw,
                                 const float* __restrict__ cb,
                                 float* __restrict__ xc, int rev)
{
    size_t idx = (size_t)blockIdx.x*256 + threadIdx.x;  // BL*DI total
    int c = (int)(idx & (DI-1));
    size_t bl = idx >> 10;
    int l = (int)(bl & (SEQ-1));
    int b = (int)(bl >> 11);
    float accv = cb[c];
    #pragma unroll
    for (int k = 0; k < 4; ++k) {
        int ts = l + k - 3;
        if (ts >= 0) {
            int tin = rev ? (SEQ-1-ts) : ts;
            accv = fmaf(cw[c*4+k], xz[((size_t)b*SEQ + tin)*2048 + c], accv);
        }
    }
    xc[idx] = accv * sigmoidf_(accv);
}

// ---------------- xg = t1 * silu(t2) ----------------
__launch_bounds__(256)
__global__ void mul_silu_kernel(const float* __restrict__ t1, const float* __restrict__ t2,
                                float* __restrict__ o, int n)
{
    int i = blockIdx.x*256 + threadIdx.x;
    if (i < n) { float z = t2[i]; o[i] = t1[i] * (z * sigmoidf_(z)); }
}

// ---------------- selective scan: one thread per (b, d_inner) ----------------
__launch_bounds__(64)
__global__ void scan_kernel(const float* __restrict__ dl,  // delta  BLxDI
                            const float* __restrict__ xc,  // conv+silu BLxDI
                            const float* __restrict__ xd,  // x_dbl BLx64 (B at 32, C at 48)
                            const float* __restrict__ xz,  // z at col DI, stride 2048
                            const float* __restrict__ A_log,
                            const float* __restrict__ Dp,
                            float* __restrict__ yg, int rev)
{
    int gid = blockIdx.x*64 + threadIdx.x;  // 0..4095
    int b = gid >> 10;
    int d = gid & (DI-1);
    float An[DS];
    #pragma unroll
    for (int n=0;n<DS;++n) An[n] = -expf(A_log[d*DS+n]);
    float Dd = Dp[d];
    float h[DS];
    #pragma unroll
    for (int n=0;n<DS;++n) h[n] = 0.f;
    __shared__ float sBC[64];
    for (int t = 0; t < SEQ; ++t) {
        size_t row = (size_t)b*SEQ + t;
        __syncthreads();
        sBC[threadIdx.x] = xd[row*64 + threadIdx.x];
        __syncthreads();
        float dv = dl[row*DI + d];
        float uv = xc[row*DI + d];
        int tz = rev ? (SEQ-1-t) : t;
        float zv = xz[((size_t)b*SEQ + tz)*2048 + DI + d];
        float du = dv*uv;
        float y = 0.f;
        #pragma unroll
        for (int n=0;n<DS;++n) {
            float dA = expf(dv*An[n]);
            h[n] = fmaf(dA, h[n], du*sBC[DR+n]);
            y = fmaf(h[n], sBC[DR+DS+n], y);
        }
        yg[row*DI + d] = (y + uv*Dd) * (zv * sigmoidf_(zv));
    }
}

// ---------------- layernorm over d=512 (optional residual) ----------------
__launch_bounds__(256)
__global__ void ln_kernel(const float* __restrict__ a, const float* __restrict__ res,
                          const float* __restrict__ g, const float* __restrict__ bta,
                          float* __restrict__ out, float eps)
{
    size_t row = blockIdx.x;
    int t = threadIdx.x;
    const float* ap = a + row*DM;
    float v0 = ap[t], v1 = ap[t+256];
    if (res) { const float* rp = res + row*DM; v0 += rp[t]; v1 += rp[t+256]; }
    float s = v0+v1, q = v0*v0 + v1*v1;
    #pragma unroll
    for (int o=32;o>0;o>>=1){ s += __shfl_xor(s,o); q += __shfl_xor(q,o); }
    __shared__ float ss[4], sq[4];
    int w = t>>6;
    if ((t&63)==0){ ss[w]=s; sq[w]=q; }
    __syncthreads();
    s = ss[0]+ss[1]+ss[2]+ss[3];
    q = sq[0]+sq[1]+sq[2]+sq[3];
    float mean = s * (1.f/DM);
    float var  = q * (1.f/DM) - mean*mean;
    var = var < 0.f ? 0.f : var;
    float rstd = rsqrtf(var + eps);
    out[row*DM+t]     = (v0-mean)*rstd*g[t]     + bta[t];
    out[row*DM+t+256] = (v1-mean)*rstd*g[t+256] + bta[t+256];
}

// ---------------- v = ha*hb + ha + mo ; hs = LN(v) ----------------
__launch_bounds__(256)
__global__ void gate_ln_kernel(const float* __restrict__ ha, const float* __restrict__ hb,
                               const float* __restrict__ mo,
                               const float* __restrict__ g, const float* __restrict__ bta,
                               float* __restrict__ out, float eps)
{
    size_t row = blockIdx.x;
    int t = threadIdx.x;
    size_t i0 = row*DM + t, i1 = i0 + 256;
    float a0 = ha[i0], a1 = ha[i1];
    float v0 = fmaf(a0, hb[i0], a0) + mo[i0];
    float v1 = fmaf(a1, hb[i1], a1) + mo[i1];
    float s = v0+v1, q = v0*v0 + v1*v1;
    #pragma unroll
    for (int o=32;o>0;o>>=1){ s += __shfl_xor(s,o); q += __shfl_xor(q,o); }
    __shared__ float ss[4], sq[4];
    int w = t>>6;
    if ((t&63)==0){ ss[w]=s; sq[w]=q; }
    __syncthreads();
    s = ss[0]+ss[1]+ss[2]+ss[3];
    q = sq[0]+sq[1]+sq[2]+sq[3];
    float mean = s * (1.f/DM);
    float var  = q * (1.f/DM) - mean*mean;
    var = var < 0.f ? 0.f : var;
    float rstd = rsqrtf(var + eps);
    out[i0] = (v0-mean)*rstd*g[t]     + bta[t];
    out[i1] = (v1-mean)*rstd*g[t+256] + bta[t+256];
}

// ================= host side =================
static void launch_gemm(int epi, const float* A, int lda, const float* W, const float* bias,
                        float* C, int ldc, int N, int K, int accf, hipStream_t s)
{
    dim3 g(N/BNT, BL/BMT);
    switch (epi) {
    case 0: gemm_kernel<0><<<g,256,0,s>>>(A,lda,W,bias,C,ldc,K,accf); break;
    case 1: gemm_kernel<1><<<g,256,0,s>>>(A,lda,W,bias,C,ldc,K,accf); break;
    case 2: gemm_kernel<2><<<g,256,0,s>>>(A,lda,W,bias,C,ldc,K,accf); break;
    case 3: gemm_kernel<3><<<g,256,0,s>>>(A,lda,W,bias,C,ldc,K,accf); break;
    }
}

extern "C" void kernel_launch(void* const* d_in, const int* in_sizes, int n_in,
                              void* d_out, int out_size, void* d_ws, size_t ws_size,
                              hipStream_t stream)
{
    const float* x        = (const float*)d_in[0];
    const float* fre      = (const float*)d_in[1];
    const float* fim      = (const float*)d_in[2];
    const float* cutoff   = (const float*)d_in[3];
    const float* ln0_g    = (const float*)d_in[4];
    const float* ln0_b    = (const float*)d_in[5];
    const float* l1_w     = (const float*)d_in[6];
    const float* l1_b     = (const float*)d_in[7];
    const float* l2_w     = (const float*)d_in[8];
    const float* l2_b     = (const float*)d_in[9];
    const float* in_w     = (const float*)d_in[10];
    const float* conv_w   = (const float*)d_in[11];
    const float* conv_b   = (const float*)d_in[12];
    const float* xproj_w  = (const float*)d_in[13];
    const float* dt_w     = (const float*)d_in[14];
    const float* dt_b     = (const float*)d_in[15];
    const float* A_log    = (const float*)d_in[16];
    const float* Dp       = (const float*)d_in[17];
    const float* out_w    = (const float*)d_in[18];
    const float* ln1_g    = (const float*)d_in[19];
    const float* ln1_b    = (const float*)d_in[20];
    const float* d1_w     = (const float*)d_in[21];
    const float* d1_b     = (const float*)d_in[22];
    const float* d2_w     = (const float*)d_in[23];
    const float* d2_b     = (const float*)d_in[24];
    const float* ln2_g    = (const float*)d_in[25];
    const float* ln2_b    = (const float*)d_in[26];
    const float* ffn_w1   = (const float*)d_in[27];
    const float* ffn_b1   = (const float*)d_in[28];
    const float* ffn_w2   = (const float*)d_in[29];
    const float* ffn_b2   = (const float*)d_in[30];
    const float* ffn_ln_g = (const float*)d_in[31];
    const float* ffn_ln_b = (const float*)d_in[32];

    float* ws = (float*)d_ws;
    float* RK = ws;                   // 512   (pad 1024)
    float* MC = RK + 1024;            // 512*512
    float* XN = MC + 512*512;         // BL*DM   (xn; later hs)
    float* XG = XN + (size_t)BL*DM;   // BL*DM   (xg; later mo)
    float* T1 = XG + (size_t)BL*DM;   // BL*DM
    float* T2 = T1 + (size_t)BL*DM;   // BL*DM
    float* XZ = T2 + (size_t)BL*DM;   // BL*2048 (xz; later ffn hidden)
    float* XC = XZ + (size_t)BL*2048; // BL*DI
    float* XD = XC + (size_t)BL*DI;   // BL*64
    float* DL = XD + (size_t)BL*64;   // BL*DI
    float* YG = DL + (size_t)BL*DI;   // BL*DI  (first BL*DM also used as xi)
    float* MS = YG + (size_t)BL*DI;   // BL*DM
    float* XI = YG;                   // alias (xi consumed before scans run)
    float* OUT = (float*)d_out;

    // 1) frequency filter as circulant GEMM, then LN(xi + x)
    build_filter_kernel<<<1,512,0,stream>>>(fre, fim, cutoff, RK);
    circ_expand_kernel<<<512,512,0,stream>>>(RK, MC);
    launch_gemm(0, x,DM, MC, nullptr, XI,DM, DM, DM, 0, stream);
    ln_kernel<<<BL,256,0,stream>>>(XI, x, ln0_g, ln0_b, XN, 1e-5f);

    // 2) xg = (xn@l1^T+b1) * silu(xn@l2^T+b2)
    launch_gemm(0, XN,DM, l1_w, l1_b, T1,DM, DM, DM, 0, stream);
    launch_gemm(0, XN,DM, l2_w, l2_b, T2,DM, DM, DM, 0, stream);
    mul_silu_kernel<<<(BL*DM)/256,256,0,stream>>>(T1, T2, XG, BL*DM);

    // 3) three mamba branches accumulated into MS
    // branches 0 (xg) and 1 (xg reversed) share xz
    launch_gemm(0, XG,DM, in_w, nullptr, XZ,2048, 2*DI, DM, 0, stream);
    for (int br = 0; br < 3; ++br) {
        if (br == 2)  // branch 3 uses raw x
            launch_gemm(0, x,DM, in_w, nullptr, XZ,2048, 2*DI, DM, 0, stream);
        int rev = (br == 1) ? 1 : 0;
        conv_silu_kernel<<<(BL*DI)/256,256,0,stream>>>(XZ, conv_w, conv_b, XC, rev);
        launch_gemm(0, XC,DI, xproj_w, nullptr, XD,64, 64, DI, 0, stream);
        launch_gemm(1, XD,64, dt_w, dt_b, DL,DI, DI, DR, 0, stream);   // softplus
        scan_kernel<<<(BATCH*DI)/64,64,0,stream>>>(DL, XC, XD, XZ, A_log, Dp, YG, rev);
        launch_gemm(0, YG,DI, out_w, nullptr, MS,DM, DM, DI, (br==0)?0:1, stream);
    }

    // 4) mo = LN(m1+m2+m3)
    ln_kernel<<<BL,256,0,stream>>>(MS, nullptr, ln1_g, ln1_b, XG, 1e-12f);

    // 5) ha/hb gate + LN -> hs (in XN)
    launch_gemm(3, XG,DM, d1_w, d1_b, T2,DM, DM, DM, 0, stream);   // hb = silu(...)
    launch_gemm(0, XG,DM, d2_w, d2_b, T1,DM, DM, DM, 0, stream);   // ha
    gate_ln_kernel<<<BL,256,0,stream>>>(T1, T2, XG, ln2_g, ln2_b, XN, 1e-12f);

    // 6) FFN: gelu(hs@w1^T+b1) @ w2^T + b2 ; out = LN(h + hs)
    launch_gemm(2, XN,DM, ffn_w1, ffn_b1, XZ,2048, 4*DM, DM, 0, stream);  // gelu
    launch_gemm(0, XZ,2048, ffn_w2, ffn_b2, T1,DM, DM, 4*DM, 0, stream);
    ln_kernel<<<BL,256,0,stream>>>(T1, XN, ffn_ln_g, ffn_ln_b, OUT, 1e-12f);
}

// Round 3
// 3105.006 us; speedup vs baseline: 3.5762x; 3.5762x over previous
//
#include <hip/hip_runtime.h>
#include <math.h>

#define BATCH 4
#define SEQ   2048
#define DM    512
#define DI    1024
#define DS    16
#define DR    32
#define BL    (BATCH*SEQ)   // 8192 tokens

#define CH 64               // scan chunk length
#define NC (SEQ/CH)         // 32 chunks per sequence

#define BMT 64
#define BNT 64
#define BKT 16

__device__ __forceinline__ float sigmoidf_(float x){ return 1.f/(1.f+expf(-x)); }

// ---------------- FFT filter as circulant kernel ----------------
__global__ void build_filter_kernel(const float* __restrict__ fre,
                                    const float* __restrict__ fim,
                                    const float* __restrict__ cut,
                                    float* __restrict__ rker)
{
    int j = threadIdx.x;  // 512 threads
    float c0 = cut[0];
    double acc = 0.0;
    for (int k = 0; k < 512; ++k) {
        float fr = (float)(k < 256 ? k : k - 512) / 512.0f;
        float mask = (fr >= c0 || fr <= -c0) ? 1.f : 0.f;
        double gre = (double)mask + (double)fre[k];
        double gim = (double)fim[k];
        int pr = (j * k) & 511;  // exact angle reduction
        double ang = 6.283185307179586476925286766559 * (double)pr / 512.0;
        acc += gre * cos(ang) - gim * sin(ang);
    }
    rker[j] = (float)(acc / 512.0);
}

__global__ void circ_expand_kernel(const float* __restrict__ rker, float* __restrict__ Mc)
{
    int n = blockIdx.x, m = threadIdx.x;
    Mc[n*512 + m] = rker[(n - m) & 511];
}

// ---------------- generic tiled fp32 GEMM: C = epi(A @ W^T + bias) ----------------
template<int EPI>
__launch_bounds__(256)
__global__ void gemm_kernel(const float* __restrict__ A, int lda,
                            const float* __restrict__ W,
                            const float* __restrict__ bias,
                            float* __restrict__ C, int ldc,
                            int K, int accflag)
{
    __shared__ float As[BKT][BMT];
    __shared__ float Ws[BKT][BNT];
    int t  = threadIdx.x;
    int lr = t >> 2;
    int lc = (t & 3) << 2;
    const float* Ag = A + (size_t)(blockIdx.y*BMT + lr)*lda + lc;
    const float* Wg = W + (size_t)(blockIdx.x*BNT + lr)*K   + lc;
    int tm = (t & 15) << 2;
    int tn = (t >> 4) << 2;
    float acc[4][4] = {};
    for (int kt = 0; kt < K; kt += BKT) {
        float4 av = *(const float4*)(Ag + kt);
        float4 wv = *(const float4*)(Wg + kt);
        __syncthreads();
        As[lc+0][lr]=av.x; As[lc+1][lr]=av.y; As[lc+2][lr]=av.z; As[lc+3][lr]=av.w;
        Ws[lc+0][lr]=wv.x; Ws[lc+1][lr]=wv.y; Ws[lc+2][lr]=wv.z; Ws[lc+3][lr]=wv.w;
        __syncthreads();
        #pragma unroll
        for (int k = 0; k < BKT; ++k) {
            const float4 a4 = *(const float4*)&As[k][tm];
            const float4 w4 = *(const float4*)&Ws[k][tn];
            float ar[4] = {a4.x,a4.y,a4.z,a4.w};
            float wr[4] = {w4.x,w4.y,w4.z,w4.w};
            #pragma unroll
            for (int i=0;i<4;++i)
                #pragma unroll
                for (int j=0;j<4;++j)
                    acc[i][j] = fmaf(ar[i], wr[j], acc[i][j]);
        }
    }
    size_t crow = (size_t)(blockIdx.y*BMT + tm);
    int ccol = blockIdx.x*BNT + tn;
    #pragma unroll
    for (int i=0;i<4;++i) {
        float* Cp = C + (crow+i)*ldc + ccol;
        #pragma unroll
        for (int j=0;j<4;++j) {
            float v = acc[i][j];
            if (bias) v += bias[ccol+j];
            if (EPI==1) v = (v > 20.f) ? v : log1pf(expf(v));
            else if (EPI==2) v = 0.5f*v*(1.f+erff(v*0.70710678118654752440f));
            else if (EPI==3) v = v*sigmoidf_(v);
            if (accflag) Cp[j] += v; else Cp[j] = v;
        }
    }
}

// ---------------- depthwise causal conv (k=4) + silu ----------------
__launch_bounds__(256)
__global__ void conv_silu_kernel(const float* __restrict__ xz,
                                 const float* __restrict__ cw,
                                 const float* __restrict__ cb,
                                 float* __restrict__ xc, int rev)
{
    size_t idx = (size_t)blockIdx.x*256 + threadIdx.x;
    int c = (int)(idx & (DI-1));
    size_t bl = idx >> 10;
    int l = (int)(bl & (SEQ-1));
    int b = (int)(bl >> 11);
    float accv = cb[c];
    #pragma unroll
    for (int k = 0; k < 4; ++k) {
        int ts = l + k - 3;
        if (ts >= 0) {
            int tin = rev ? (SEQ-1-ts) : ts;
            accv = fmaf(cw[c*4+k], xz[((size_t)b*SEQ + tin)*2048 + c], accv);
        }
    }
    xc[idx] = accv * sigmoidf_(accv);
}

__launch_bounds__(256)
__global__ void mul_silu_kernel(const float* __restrict__ t1, const float* __restrict__ t2,
                                float* __restrict__ o, int n)
{
    int i = blockIdx.x*256 + threadIdx.x;
    if (i < n) { float z = t2[i]; o[i] = t1[i] * (z * sigmoidf_(z)); }
}

// ================= chunked parallel selective scan =================
// h[t] = exp(dv*A)*h[t-1] + dv*u*B[t];  y[t] = <h[t], C[t]>
// Phase A: per-(b,chunk,d) local scan from h=0 -> h_out, and P = prod(dA).
__launch_bounds__(256)
__global__ void scan_ph_a(const float* __restrict__ dl,
                          const float* __restrict__ xc,
                          const float* __restrict__ xd,
                          const float* __restrict__ A_log,
                          float* __restrict__ hout,
                          float* __restrict__ aprod)
{
    int d = blockIdx.x*256 + threadIdx.x;   // 0..1023
    int c = blockIdx.y;                     // chunk
    int b = blockIdx.z;
    float An[DS];
    #pragma unroll
    for (int n=0;n<DS;++n) An[n] = -expf(A_log[d*DS+n]);
    float h[DS], P[DS];
    #pragma unroll
    for (int n=0;n<DS;++n) { h[n]=0.f; P[n]=1.f; }
    size_t row0 = (size_t)b*SEQ + (size_t)c*CH;
    for (int t=0;t<CH;++t) {
        size_t row = row0 + t;
        float dv = dl[row*DI + d];
        float uv = xc[row*DI + d];
        float du = dv*uv;
        float Bv[DS];
        *(float4*)&Bv[0]  = *(const float4*)(xd + row*64 + 32);
        *(float4*)&Bv[4]  = *(const float4*)(xd + row*64 + 36);
        *(float4*)&Bv[8]  = *(const float4*)(xd + row*64 + 40);
        *(float4*)&Bv[12] = *(const float4*)(xd + row*64 + 44);
        #pragma unroll
        for (int n=0;n<DS;++n) {
            float dA = expf(dv*An[n]);
            h[n] = fmaf(dA, h[n], du*Bv[n]);
            P[n] *= dA;
        }
    }
    size_t o = (((size_t)b*NC + c)*DI + d)*DS;
    #pragma unroll
    for (int q=0;q<4;++q) {
        *(float4*)(hout  + o + 4*q) = make_float4(h[4*q],h[4*q+1],h[4*q+2],h[4*q+3]);
        *(float4*)(aprod + o + 4*q) = make_float4(P[4*q],P[4*q+1],P[4*q+2],P[4*q+3]);
    }
}

// Phase B: sequential over chunks only. One thread per (b,d,n) = 65536.
__launch_bounds__(256)
__global__ void scan_ph_b(const float* __restrict__ hout,
                          const float* __restrict__ aprod,
                          float* __restrict__ hin)
{
    int idx = blockIdx.x*256 + threadIdx.x;  // b*(DI*DS)+dn
    int b  = idx >> 14;
    int dn = idx & (DI*DS - 1);
    float hc = 0.f;
    for (int c=0;c<NC;++c) {
        size_t o = ((size_t)b*NC + c)*(DI*DS) + dn;
        hin[o] = hc;
        hc = fmaf(aprod[o], hc, hout[o]);
    }
}

// Phase C: local scan seeded with h_in, fused y/D/z-gate epilogue.
__launch_bounds__(256)
__global__ void scan_ph_c(const float* __restrict__ dl,
                          const float* __restrict__ xc,
                          const float* __restrict__ xd,
                          const float* __restrict__ xz,
                          const float* __restrict__ A_log,
                          const float* __restrict__ Dp,
                          const float* __restrict__ hin,
                          float* __restrict__ yg, int rev)
{
    int d = blockIdx.x*256 + threadIdx.x;
    int c = blockIdx.y;
    int b = blockIdx.z;
    float An[DS];
    #pragma unroll
    for (int n=0;n<DS;++n) An[n] = -expf(A_log[d*DS+n]);
    float h[DS];
    size_t o = (((size_t)b*NC + c)*DI + d)*DS;
    #pragma unroll
    for (int q=0;q<4;++q) {
        float4 hv = *(const float4*)(hin + o + 4*q);
        h[4*q]=hv.x; h[4*q+1]=hv.y; h[4*q+2]=hv.z; h[4*q+3]=hv.w;
    }
    float Dd = Dp[d];
    size_t row0 = (size_t)b*SEQ + (size_t)c*CH;
    for (int t=0;t<CH;++t) {
        size_t row = row0 + t;
        float dv = dl[row*DI + d];
        float uv = xc[row*DI + d];
        float du = dv*uv;
        float Bv[DS], Cv[DS];
        *(float4*)&Bv[0]  = *(const float4*)(xd + row*64 + 32);
        *(float4*)&Bv[4]  = *(const float4*)(xd + row*64 + 36);
        *(float4*)&Bv[8]  = *(const float4*)(xd + row*64 + 40);
        *(float4*)&Bv[12] = *(const float4*)(xd + row*64 + 44);
        *(float4*)&Cv[0]  = *(const float4*)(xd + row*64 + 48);
        *(float4*)&Cv[4]  = *(const float4*)(xd + row*64 + 52);
        *(float4*)&Cv[8]  = *(const float4*)(xd + row*64 + 56);
        *(float4*)&Cv[12] = *(const float4*)(xd + row*64 + 60);
        int l = c*CH + t;
        int tz = rev ? (SEQ-1-l) : l;
        float zv = xz[((size_t)b*SEQ + tz)*2048 + DI + d];
        float y = 0.f;
        #pragma unroll
        for (int n=0;n<DS;++n) {
            float dA = expf(dv*An[n]);
            h[n] = fmaf(dA, h[n], du*Bv[n]);
            y = fmaf(h[n], Cv[n], y);
        }
        yg[row*DI + d] = (y + uv*Dd) * (zv * sigmoidf_(zv));
    }
}

// ---------------- layernorm over d=512 (optional residual) ----------------
__launch_bounds__(256)
__global__ void ln_kernel(const float* __restrict__ a, const float* __restrict__ res,
                          const float* __restrict__ g, const float* __restrict__ bta,
                          float* __restrict__ out, float eps)
{
    size_t row = blockIdx.x;
    int t = threadIdx.x;
    const float* ap = a + row*DM;
    float v0 = ap[t], v1 = ap[t+256];
    if (res) { const float* rp = res + row*DM; v0 += rp[t]; v1 += rp[t+256]; }
    float s = v0+v1, q = v0*v0 + v1*v1;
    #pragma unroll
    for (int o=32;o>0;o>>=1){ s += __shfl_xor(s,o); q += __shfl_xor(q,o); }
    __shared__ float ss[4], sq[4];
    int w = t>>6;
    if ((t&63)==0){ ss[w]=s; sq[w]=q; }
    __syncthreads();
    s = ss[0]+ss[1]+ss[2]+ss[3];
    q = sq[0]+sq[1]+sq[2]+sq[3];
    float mean = s * (1.f/DM);
    float var  = q * (1.f/DM) - mean*mean;
    var = var < 0.f ? 0.f : var;
    float rstd = rsqrtf(var + eps);
    out[row*DM+t]     = (v0-mean)*rstd*g[t]     + bta[t];
    out[row*DM+t+256] = (v1-mean)*rstd*g[t+256] + bta[t+256];
}

__launch_bounds__(256)
__global__ void gate_ln_kernel(const float* __restrict__ ha, const float* __restrict__ hb,
                               const float* __restrict__ mo,
                               const float* __restrict__ g, const float* __restrict__ bta,
                               float* __restrict__ out, float eps)
{
    size_t row = blockIdx.x;
    int t = threadIdx.x;
    size_t i0 = row*DM + t, i1 = i0 + 256;
    float a0 = ha[i0], a1 = ha[i1];
    float v0 = fmaf(a0, hb[i0], a0) + mo[i0];
    float v1 = fmaf(a1, hb[i1], a1) + mo[i1];
    float s = v0+v1, q = v0*v0 + v1*v1;
    #pragma unroll
    for (int o=32;o>0;o>>=1){ s += __shfl_xor(s,o); q += __shfl_xor(q,o); }
    __shared__ float ss[4], sq[4];
    int w = t>>6;
    if ((t&63)==0){ ss[w]=s; sq[w]=q; }
    __syncthreads();
    s = ss[0]+ss[1]+ss[2]+ss[3];
    q = sq[0]+sq[1]+sq[2]+sq[3];
    float mean = s * (1.f/DM);
    float var  = q * (1.f/DM) - mean*mean;
    var = var < 0.f ? 0.f : var;
    float rstd = rsqrtf(var + eps);
    out[i0] = (v0-mean)*rstd*g[t]     + bta[t];
    out[i1] = (v1-mean)*rstd*g[t+256] + bta[t+256];
}

// ================= host side =================
static void launch_gemm(int epi, const float* A, int lda, const float* W, const float* bias,
                        float* C, int ldc, int N, int K, int accf, hipStream_t s)
{
    dim3 g(N/BNT, BL/BMT);
    switch (epi) {
    case 0: gemm_kernel<0><<<g,256,0,s>>>(A,lda,W,bias,C,ldc,K,accf); break;
    case 1: gemm_kernel<1><<<g,256,0,s>>>(A,lda,W,bias,C,ldc,K,accf); break;
    case 2: gemm_kernel<2><<<g,256,0,s>>>(A,lda,W,bias,C,ldc,K,accf); break;
    case 3: gemm_kernel<3><<<g,256,0,s>>>(A,lda,W,bias,C,ldc,K,accf); break;
    }
}

extern "C" void kernel_launch(void* const* d_in, const int* in_sizes, int n_in,
                              void* d_out, int out_size, void* d_ws, size_t ws_size,
                              hipStream_t stream)
{
    const float* x        = (const float*)d_in[0];
    const float* fre      = (const float*)d_in[1];
    const float* fim      = (const float*)d_in[2];
    const float* cutoff   = (const float*)d_in[3];
    const float* ln0_g    = (const float*)d_in[4];
    const float* ln0_b    = (const float*)d_in[5];
    const float* l1_w     = (const float*)d_in[6];
    const float* l1_b     = (const float*)d_in[7];
    const float* l2_w     = (const float*)d_in[8];
    const float* l2_b     = (const float*)d_in[9];
    const float* in_w     = (const float*)d_in[10];
    const float* conv_w   = (const float*)d_in[11];
    const float* conv_b   = (const float*)d_in[12];
    const float* xproj_w  = (const float*)d_in[13];
    const float* dt_w     = (const float*)d_in[14];
    const float* dt_b     = (const float*)d_in[15];
    const float* A_log    = (const float*)d_in[16];
    const float* Dp       = (const float*)d_in[17];
    const float* out_w    = (const float*)d_in[18];
    const float* ln1_g    = (const float*)d_in[19];
    const float* ln1_b    = (const float*)d_in[20];
    const float* d1_w     = (const float*)d_in[21];
    const float* d1_b     = (const float*)d_in[22];
    const float* d2_w     = (const float*)d_in[23];
    const float* d2_b     = (const float*)d_in[24];
    const float* ln2_g    = (const float*)d_in[25];
    const float* ln2_b    = (const float*)d_in[26];
    const float* ffn_w1   = (const float*)d_in[27];
    const float* ffn_b1   = (const float*)d_in[28];
    const float* ffn_w2   = (const float*)d_in[29];
    const float* ffn_b2   = (const float*)d_in[30];
    const float* ffn_ln_g = (const float*)d_in[31];
    const float* ffn_ln_b = (const float*)d_in[32];

    float* ws = (float*)d_ws;
    float* RK = ws;                   // 512   (pad 1024)
    float* MC = RK + 1024;            // 512*512
    float* XN = MC + 512*512;         // BL*DM   (xn; later hs)
    float* XG = XN + (size_t)BL*DM;   // BL*DM   (xg; later mo)
    float* T1 = XG + (size_t)BL*DM;   // BL*DM  (dead during branch loop)
    float* T2 = T1 + (size_t)BL*DM;   // BL*DM  (dead during branch loop)
    float* XZ = T2 + (size_t)BL*DM;   // BL*2048 (xz; later ffn hidden)
    float* XC = XZ + (size_t)BL*2048; // BL*DI
    float* XD = XC + (size_t)BL*DI;   // BL*64
    float* DL = XD + (size_t)BL*64;   // BL*DI
    float* YG = DL + (size_t)BL*DI;   // BL*DI  (first BL*DM also used as xi)
    float* MS = YG + (size_t)BL*DI;   // BL*DM
    const size_t SCNT = (size_t)BATCH*NC*DI*DS;   // 2M floats
    // scan state buffers ALIAS T1/T2 (dead during the branch loop):
    float* HOUT = T1;                  // SCNT (8 MB)
    float* APR  = T1 + SCNT;           // SCNT (fills rest of T1 exactly)
    float* HIN  = T2;                  // SCNT (first half of T2)
    float* XI = YG;                    // alias (xi consumed before scans run)
    float* OUT = (float*)d_out;

    // 1) frequency filter as circulant GEMM, then LN(xi + x)
    build_filter_kernel<<<1,512,0,stream>>>(fre, fim, cutoff, RK);
    circ_expand_kernel<<<512,512,0,stream>>>(RK, MC);
    launch_gemm(0, x,DM, MC, nullptr, XI,DM, DM, DM, 0, stream);
    ln_kernel<<<BL,256,0,stream>>>(XI, x, ln0_g, ln0_b, XN, 1e-5f);

    // 2) xg = (xn@l1^T+b1) * silu(xn@l2^T+b2)
    launch_gemm(0, XN,DM, l1_w, l1_b, T1,DM, DM, DM, 0, stream);
    launch_gemm(0, XN,DM, l2_w, l2_b, T2,DM, DM, DM, 0, stream);
    mul_silu_kernel<<<(BL*DM)/256,256,0,stream>>>(T1, T2, XG, BL*DM);

    // 3) three mamba branches accumulated into MS
    launch_gemm(0, XG,DM, in_w, nullptr, XZ,2048, 2*DI, DM, 0, stream);
    for (int br = 0; br < 3; ++br) {
        if (br == 2)
            launch_gemm(0, x,DM, in_w, nullptr, XZ,2048, 2*DI, DM, 0, stream);
        int rev = (br == 1) ? 1 : 0;
        conv_silu_kernel<<<(BL*DI)/256,256,0,stream>>>(XZ, conv_w, conv_b, XC, rev);
        launch_gemm(0, XC,DI, xproj_w, nullptr, XD,64, 64, DI, 0, stream);
        launch_gemm(1, XD,64, dt_w, dt_b, DL,DI, DI, DR, 0, stream);   // softplus
        // chunked parallel scan
        {
            dim3 ga(DI/256, NC, BATCH);
            scan_ph_a<<<ga,256,0,stream>>>(DL, XC, XD, A_log, HOUT, APR);
            scan_ph_b<<<(BATCH*DI*DS)/256,256,0,stream>>>(HOUT, APR, HIN);
            scan_ph_c<<<ga,256,0,stream>>>(DL, XC, XD, XZ, A_log, Dp, HIN, YG, rev);
        }
        launch_gemm(0, YG,DI, out_w, nullptr, MS,DM, DM, DI, (br==0)?0:1, stream);
    }

    // 4) mo = LN(m1+m2+m3)
    ln_kernel<<<BL,256,0,stream>>>(MS, nullptr, ln1_g, ln1_b, XG, 1e-12f);

    // 5) ha/hb gate + LN -> hs (in XN)
    launch_gemm(3, XG,DM, d1_w, d1_b, T2,DM, DM, DM, 0, stream);   // hb = silu(...)
    launch_gemm(0, XG,DM, d2_w, d2_b, T1,DM, DM, DM, 0, stream);   // ha
    gate_ln_kernel<<<BL,256,0,stream>>>(T1, T2, XG, ln2_g, ln2_b, XN, 1e-12f);

    // 6) FFN: gelu(hs@w1^T+b1) @ w2^T + b2 ; out = LN(h + hs)
    launch_gemm(2, XN,DM, ffn_w1, ffn_b1, XZ,2048, 4*DM, DM, 0, stream);  // gelu
    launch_gemm(0, XZ,2048, ffn_w2, ffn_b2, T1,DM, DM, 4*DM, 0, stream);
    ln_kernel<<<BL,256,0,stream>>>(T1, XN, ffn_ln_g, ffn_ln_b, OUT, 1e-12f);
}

// Round 4
// 1722.597 us; speedup vs baseline: 6.4462x; 1.8025x over previous
//
#include <hip/hip_runtime.h>
#include <math.h>

#define BATCH 4
#define SEQ   2048
#define DM    512
#define DI    1024
#define DS    16
#define DR    32
#define BL    (BATCH*SEQ)   // 8192 tokens

#define CH 64               // scan chunk length
#define NC (SEQ/CH)         // 32 chunks per sequence

#define BMT 64
#define BNT 64
#define BKT 16

typedef __attribute__((ext_vector_type(8))) short short8_t;   // 8 bf16 = 4 VGPRs
typedef __attribute__((ext_vector_type(4))) float f32x4_t;    // MFMA acc

__device__ __forceinline__ float sigmoidf_(float x){ return 1.f/(1.f+expf(-x)); }

// fp32 -> bf16 (round to nearest even), as raw ushort bits
__device__ __forceinline__ unsigned short f2bf(float f){
    unsigned int u = __float_as_uint(f);
    unsigned int r = (u + 0x7fffu + ((u >> 16) & 1u)) >> 16;
    return (unsigned short)r;
}

// ---------------- FFT filter as circulant kernel (parallel) ----------------
// g[k] = mask[k] + fre[k] + i*fim[k];  r[j] = Re(ifft(g))[j]
// grid 512 (one block per j), block 256
__global__ void build_filter_kernel(const float* __restrict__ fre,
                                    const float* __restrict__ fim,
                                    const float* __restrict__ cut,
                                    float* __restrict__ rker)
{
    int j = blockIdx.x;
    int t = threadIdx.x;
    float c0 = cut[0];
    double acc = 0.0;
    for (int k = t; k < 512; k += 256) {
        float fr = (float)(k < 256 ? k : k - 512) / 512.0f;
        float mask = (fr >= c0 || fr <= -c0) ? 1.f : 0.f;
        double gre = (double)mask + (double)fre[k];
        double gim = (double)fim[k];
        int pr = (j * k) & 511;  // exact angle reduction
        double ang = 6.283185307179586476925286766559 * (double)pr / 512.0;
        acc += gre * cos(ang) - gim * sin(ang);
    }
    #pragma unroll
    for (int o = 32; o > 0; o >>= 1) acc += __shfl_xor(acc, o);
    __shared__ double sd[4];
    int w = t >> 6;
    if ((t & 63) == 0) sd[w] = acc;
    __syncthreads();
    if (t == 0) rker[j] = (float)((sd[0] + sd[1] + sd[2] + sd[3]) / 512.0);
}

__global__ void circ_expand_kernel(const float* __restrict__ rker, float* __restrict__ Mc)
{
    int n = blockIdx.x, m = threadIdx.x;
    Mc[n*512 + m] = rker[(n - m) & 511];
}

// ---------------- fp32 tiled GEMM (small/odd shapes): C = epi(A @ W^T + bias) ----------------
template<int EPI>
__launch_bounds__(256)
__global__ void gemm_kernel(const float* __restrict__ A, int lda,
                            const float* __restrict__ W,
                            const float* __restrict__ bias,
                            float* __restrict__ C, int ldc,
                            int K, int accflag)
{
    __shared__ float As[BKT][BMT];
    __shared__ float Ws[BKT][BNT];
    int t  = threadIdx.x;
    int lr = t >> 2;
    int lc = (t & 3) << 2;
    const float* Ag = A + (size_t)(blockIdx.y*BMT + lr)*lda + lc;
    const float* Wg = W + (size_t)(blockIdx.x*BNT + lr)*K   + lc;
    int tm = (t & 15) << 2;
    int tn = (t >> 4) << 2;
    float acc[4][4] = {};
    for (int kt = 0; kt < K; kt += BKT) {
        float4 av = *(const float4*)(Ag + kt);
        float4 wv = *(const float4*)(Wg + kt);
        __syncthreads();
        As[lc+0][lr]=av.x; As[lc+1][lr]=av.y; As[lc+2][lr]=av.z; As[lc+3][lr]=av.w;
        Ws[lc+0][lr]=wv.x; Ws[lc+1][lr]=wv.y; Ws[lc+2][lr]=wv.z; Ws[lc+3][lr]=wv.w;
        __syncthreads();
        #pragma unroll
        for (int k = 0; k < BKT; ++k) {
            const float4 a4 = *(const float4*)&As[k][tm];
            const float4 w4 = *(const float4*)&Ws[k][tn];
            float ar[4] = {a4.x,a4.y,a4.z,a4.w};
            float wr[4] = {w4.x,w4.y,w4.z,w4.w};
            #pragma unroll
            for (int i=0;i<4;++i)
                #pragma unroll
                for (int j=0;j<4;++j)
                    acc[i][j] = fmaf(ar[i], wr[j], acc[i][j]);
        }
    }
    size_t crow = (size_t)(blockIdx.y*BMT + tm);
    int ccol = blockIdx.x*BNT + tn;
    #pragma unroll
    for (int i=0;i<4;++i) {
        float* Cp = C + (crow+i)*ldc + ccol;
        #pragma unroll
        for (int j=0;j<4;++j) {
            float v = acc[i][j];
            if (bias) v += bias[ccol+j];
            if (EPI==1) v = (v > 20.f) ? v : log1pf(expf(v));
            else if (EPI==2) v = 0.5f*v*(1.f+erff(v*0.70710678118654752440f));
            else if (EPI==3) v = v*sigmoidf_(v);
            if (accflag) Cp[j] += v; else Cp[j] = v;
        }
    }
}

// ---------------- bf16 MFMA GEMM: C = epi(A @ W^T + bias) ----------------
// A: M x K fp32 (row stride lda), W: N x K fp32 (contiguous), C: M x N fp32 (stride ldc)
// fp32->bf16 conversion fused into LDS staging. 128x128 tile, BK=32.
// 4 waves in 2x2; each wave computes 64x64 via 4x4 frags of mfma_f32_16x16x32_bf16.
// LDS rows padded to 40 bf16 (80 B, 16B-aligned) for low-conflict ds_read_b128.
#define LDP 40
template<int EPI>
__launch_bounds__(256)
__global__ void mfma_gemm(const float* __restrict__ A, int lda,
                          const float* __restrict__ W,
                          const float* __restrict__ bias,
                          float* __restrict__ C, int ldc,
                          int K, int accflag)
{
    __shared__ __align__(16) short As[128*LDP];
    __shared__ __align__(16) short Bs[128*LDP];
    int t = threadIdx.x;
    int lane = t & 63;
    int w  = t >> 6;
    int wr = w >> 1, wc = w & 1;
    int l15 = lane & 15, quad = lane >> 4;

    int srow = t >> 1;            // staging row 0..127
    int scol = (t & 1) << 4;      // k offset 0 or 16
    const int tileM = blockIdx.y * 128;
    const int tileN = blockIdx.x * 128;
    const float* Ag = A + (size_t)(tileM + srow)*lda + scol;
    const float* Wg = W + (size_t)(tileN + srow)*K   + scol;

    f32x4_t acc[4][4];
    #pragma unroll
    for (int i=0;i<4;++i)
        #pragma unroll
        for (int j=0;j<4;++j)
            acc[i][j] = (f32x4_t){0.f,0.f,0.f,0.f};

    for (int kt = 0; kt < K; kt += 32) {
        float4 a0 = *(const float4*)(Ag + kt + 0);
        float4 a1 = *(const float4*)(Ag + kt + 4);
        float4 a2 = *(const float4*)(Ag + kt + 8);
        float4 a3 = *(const float4*)(Ag + kt + 12);
        float4 b0 = *(const float4*)(Wg + kt + 0);
        float4 b1 = *(const float4*)(Wg + kt + 4);
        float4 b2 = *(const float4*)(Wg + kt + 8);
        float4 b3 = *(const float4*)(Wg + kt + 12);
        short8_t ap0, ap1, bp0, bp1;
        ap0[0]=f2bf(a0.x); ap0[1]=f2bf(a0.y); ap0[2]=f2bf(a0.z); ap0[3]=f2bf(a0.w);
        ap0[4]=f2bf(a1.x); ap0[5]=f2bf(a1.y); ap0[6]=f2bf(a1.z); ap0[7]=f2bf(a1.w);
        ap1[0]=f2bf(a2.x); ap1[1]=f2bf(a2.y); ap1[2]=f2bf(a2.z); ap1[3]=f2bf(a2.w);
        ap1[4]=f2bf(a3.x); ap1[5]=f2bf(a3.y); ap1[6]=f2bf(a3.z); ap1[7]=f2bf(a3.w);
        bp0[0]=f2bf(b0.x); bp0[1]=f2bf(b0.y); bp0[2]=f2bf(b0.z); bp0[3]=f2bf(b0.w);
        bp0[4]=f2bf(b1.x); bp0[5]=f2bf(b1.y); bp0[6]=f2bf(b1.z); bp0[7]=f2bf(b1.w);
        bp1[0]=f2bf(b2.x); bp1[1]=f2bf(b2.y); bp1[2]=f2bf(b2.z); bp1[3]=f2bf(b2.w);
        bp1[4]=f2bf(b3.x); bp1[5]=f2bf(b3.y); bp1[6]=f2bf(b3.z); bp1[7]=f2bf(b3.w);
        __syncthreads();
        *(short8_t*)&As[srow*LDP + scol]     = ap0;
        *(short8_t*)&As[srow*LDP + scol + 8] = ap1;
        *(short8_t*)&Bs[srow*LDP + scol]     = bp0;
        *(short8_t*)&Bs[srow*LDP + scol + 8] = bp1;
        __syncthreads();
        short8_t af[4], bfv[4];
        #pragma unroll
        for (int mi=0;mi<4;++mi)
            af[mi] = *(const short8_t*)&As[(wr*64 + mi*16 + l15)*LDP + quad*8];
        #pragma unroll
        for (int ni=0;ni<4;++ni)
            bfv[ni] = *(const short8_t*)&Bs[(wc*64 + ni*16 + l15)*LDP + quad*8];
        #pragma unroll
        for (int mi=0;mi<4;++mi)
            #pragma unroll
            for (int ni=0;ni<4;++ni)
                acc[mi][ni] = __builtin_amdgcn_mfma_f32_16x16x32_bf16(af[mi], bfv[ni], acc[mi][ni], 0, 0, 0);
    }

    // epilogue: C/D layout col=lane&15, row=quad*4+reg  [m89/m91]
    #pragma unroll
    for (int mi=0;mi<4;++mi) {
        #pragma unroll
        for (int ni=0;ni<4;++ni) {
            int gm0 = tileM + wr*64 + mi*16 + quad*4;
            int gn  = tileN + wc*64 + ni*16 + l15;
            float bv = bias ? bias[gn] : 0.f;
            #pragma unroll
            for (int r=0;r<4;++r) {
                float v = acc[mi][ni][r] + bv;
                if (EPI==1) v = (v > 20.f) ? v : log1pf(expf(v));
                else if (EPI==2) v = 0.5f*v*(1.f+erff(v*0.70710678118654752440f));
                else if (EPI==3) v = v*sigmoidf_(v);
                float* Cp = C + (size_t)(gm0 + r)*ldc + gn;
                if (accflag) *Cp += v; else *Cp = v;
            }
        }
    }
}

// ---------------- depthwise causal conv (k=4) + silu ----------------
__launch_bounds__(256)
__global__ void conv_silu_kernel(const float* __restrict__ xz,
                                 const float* __restrict__ cw,
                                 const float* __restrict__ cb,
                                 float* __restrict__ xc, int rev)
{
    size_t idx = (size_t)blockIdx.x*256 + threadIdx.x;
    int c = (int)(idx & (DI-1));
    size_t bl = idx >> 10;
    int l = (int)(bl & (SEQ-1));
    int b = (int)(bl >> 11);
    float accv = cb[c];
    #pragma unroll
    for (int k = 0; k < 4; ++k) {
        int ts = l + k - 3;
        if (ts >= 0) {
            int tin = rev ? (SEQ-1-ts) : ts;
            accv = fmaf(cw[c*4+k], xz[((size_t)b*SEQ + tin)*2048 + c], accv);
        }
    }
    xc[idx] = accv * sigmoidf_(accv);
}

__launch_bounds__(256)
__global__ void mul_silu_kernel(const float* __restrict__ t1, const float* __restrict__ t2,
                                float* __restrict__ o, int n)
{
    int i = blockIdx.x*256 + threadIdx.x;
    if (i < n) { float z = t2[i]; o[i] = t1[i] * (z * sigmoidf_(z)); }
}

// ================= chunked parallel selective scan =================
__launch_bounds__(256)
__global__ void scan_ph_a(const float* __restrict__ dl,
                          const float* __restrict__ xc,
                          const float* __restrict__ xd,
                          const float* __restrict__ A_log,
                          float* __restrict__ hout,
                          float* __restrict__ aprod)
{
    int d = blockIdx.x*256 + threadIdx.x;
    int c = blockIdx.y;
    int b = blockIdx.z;
    float An[DS];
    #pragma unroll
    for (int n=0;n<DS;++n) An[n] = -expf(A_log[d*DS+n]);
    float h[DS], P[DS];
    #pragma unroll
    for (int n=0;n<DS;++n) { h[n]=0.f; P[n]=1.f; }
    size_t row0 = (size_t)b*SEQ + (size_t)c*CH;
    for (int t=0;t<CH;++t) {
        size_t row = row0 + t;
        float dv = dl[row*DI + d];
        float uv = xc[row*DI + d];
        float du = dv*uv;
        float Bv[DS];
        *(float4*)&Bv[0]  = *(const float4*)(xd + row*64 + 32);
        *(float4*)&Bv[4]  = *(const float4*)(xd + row*64 + 36);
        *(float4*)&Bv[8]  = *(const float4*)(xd + row*64 + 40);
        *(float4*)&Bv[12] = *(const float4*)(xd + row*64 + 44);
        #pragma unroll
        for (int n=0;n<DS;++n) {
            float dA = expf(dv*An[n]);
            h[n] = fmaf(dA, h[n], du*Bv[n]);
            P[n] *= dA;
        }
    }
    size_t o = (((size_t)b*NC + c)*DI + d)*DS;
    #pragma unroll
    for (int q=0;q<4;++q) {
        *(float4*)(hout  + o + 4*q) = make_float4(h[4*q],h[4*q+1],h[4*q+2],h[4*q+3]);
        *(float4*)(aprod + o + 4*q) = make_float4(P[4*q],P[4*q+1],P[4*q+2],P[4*q+3]);
    }
}

__launch_bounds__(256)
__global__ void scan_ph_b(const float* __restrict__ hout,
                          const float* __restrict__ aprod,
                          float* __restrict__ hin)
{
    int idx = blockIdx.x*256 + threadIdx.x;
    int b  = idx >> 14;
    int dn = idx & (DI*DS - 1);
    float hc = 0.f;
    for (int c=0;c<NC;++c) {
        size_t o = ((size_t)b*NC + c)*(DI*DS) + dn;
        hin[o] = hc;
        hc = fmaf(aprod[o], hc, hout[o]);
    }
}

__launch_bounds__(256)
__global__ void scan_ph_c(const float* __restrict__ dl,
                          const float* __restrict__ xc,
                          const float* __restrict__ xd,
                          const float* __restrict__ xz,
                          const float* __restrict__ A_log,
                          const float* __restrict__ Dp,
                          const float* __restrict__ hin,
                          float* __restrict__ yg, int rev)
{
    int d = blockIdx.x*256 + threadIdx.x;
    int c = blockIdx.y;
    int b = blockIdx.z;
    float An[DS];
    #pragma unroll
    for (int n=0;n<DS;++n) An[n] = -expf(A_log[d*DS+n]);
    float h[DS];
    size_t o = (((size_t)b*NC + c)*DI + d)*DS;
    #pragma unroll
    for (int q=0;q<4;++q) {
        float4 hv = *(const float4*)(hin + o + 4*q);
        h[4*q]=hv.x; h[4*q+1]=hv.y; h[4*q+2]=hv.z; h[4*q+3]=hv.w;
    }
    float Dd = Dp[d];
    size_t row0 = (size_t)b*SEQ + (size_t)c*CH;
    for (int t=0;t<CH;++t) {
        size_t row = row0 + t;
        float dv = dl[row*DI + d];
        float uv = xc[row*DI + d];
        float du = dv*uv;
        float Bv[DS], Cv[DS];
        *(float4*)&Bv[0]  = *(const float4*)(xd + row*64 + 32);
        *(float4*)&Bv[4]  = *(const float4*)(xd + row*64 + 36);
        *(float4*)&Bv[8]  = *(const float4*)(xd + row*64 + 40);
        *(float4*)&Bv[12] = *(const float4*)(xd + row*64 + 44);
        *(float4*)&Cv[0]  = *(const float4*)(xd + row*64 + 48);
        *(float4*)&Cv[4]  = *(const float4*)(xd + row*64 + 52);
        *(float4*)&Cv[8]  = *(const float4*)(xd + row*64 + 56);
        *(float4*)&Cv[12] = *(const float4*)(xd + row*64 + 60);
        int l = c*CH + t;
        int tz = rev ? (SEQ-1-l) : l;
        float zv = xz[((size_t)b*SEQ + tz)*2048 + DI + d];
        float y = 0.f;
        #pragma unroll
        for (int n=0;n<DS;++n) {
            float dA = expf(dv*An[n]);
            h[n] = fmaf(dA, h[n], du*Bv[n]);
            y = fmaf(h[n], Cv[n], y);
        }
        yg[row*DI + d] = (y + uv*Dd) * (zv * sigmoidf_(zv));
    }
}

// ---------------- layernorm over d=512 (optional residual) ----------------
__launch_bounds__(256)
__global__ void ln_kernel(const float* __restrict__ a, const float* __restrict__ res,
                          const float* __restrict__ g, const float* __restrict__ bta,
                          float* __restrict__ out, float eps)
{
    size_t row = blockIdx.x;
    int t = threadIdx.x;
    const float* ap = a + row*DM;
    float v0 = ap[t], v1 = ap[t+256];
    if (res) { const float* rp = res + row*DM; v0 += rp[t]; v1 += rp[t+256]; }
    float s = v0+v1, q = v0*v0 + v1*v1;
    #pragma unroll
    for (int o=32;o>0;o>>=1){ s += __shfl_xor(s,o); q += __shfl_xor(q,o); }
    __shared__ float ss[4], sq[4];
    int w = t>>6;
    if ((t&63)==0){ ss[w]=s; sq[w]=q; }
    __syncthreads();
    s = ss[0]+ss[1]+ss[2]+ss[3];
    q = sq[0]+sq[1]+sq[2]+sq[3];
    float mean = s * (1.f/DM);
    float var  = q * (1.f/DM) - mean*mean;
    var = var < 0.f ? 0.f : var;
    float rstd = rsqrtf(var + eps);
    out[row*DM+t]     = (v0-mean)*rstd*g[t]     + bta[t];
    out[row*DM+t+256] = (v1-mean)*rstd*g[t+256] + bta[t+256];
}

__launch_bounds__(256)
__global__ void gate_ln_kernel(const float* __restrict__ ha, const float* __restrict__ hb,
                               const float* __restrict__ mo,
                               const float* __restrict__ g, const float* __restrict__ bta,
                               float* __restrict__ out, float eps)
{
    size_t row = blockIdx.x;
    int t = threadIdx.x;
    size_t i0 = row*DM + t, i1 = i0 + 256;
    float a0 = ha[i0], a1 = ha[i1];
    float v0 = fmaf(a0, hb[i0], a0) + mo[i0];
    float v1 = fmaf(a1, hb[i1], a1) + mo[i1];
    float s = v0+v1, q = v0*v0 + v1*v1;
    #pragma unroll
    for (int o=32;o>0;o>>=1){ s += __shfl_xor(s,o); q += __shfl_xor(q,o); }
    __shared__ float ss[4], sq[4];
    int w = t>>6;
    if ((t&63)==0){ ss[w]=s; sq[w]=q; }
    __syncthreads();
    s = ss[0]+ss[1]+ss[2]+ss[3];
    q = sq[0]+sq[1]+sq[2]+sq[3];
    float mean = s * (1.f/DM);
    float var  = q * (1.f/DM) - mean*mean;
    var = var < 0.f ? 0.f : var;
    float rstd = rsqrtf(var + eps);
    out[i0] = (v0-mean)*rstd*g[t]     + bta[t];
    out[i1] = (v1-mean)*rstd*g[t+256] + bta[t+256];
}

// ================= host side =================
static void launch_gemm(int epi, const float* A, int lda, const float* W, const float* bias,
                        float* C, int ldc, int N, int K, int accf, hipStream_t s)
{
    dim3 g(N/BNT, BL/BMT);
    switch (epi) {
    case 0: gemm_kernel<0><<<g,256,0,s>>>(A,lda,W,bias,C,ldc,K,accf); break;
    case 1: gemm_kernel<1><<<g,256,0,s>>>(A,lda,W,bias,C,ldc,K,accf); break;
    case 2: gemm_kernel<2><<<g,256,0,s>>>(A,lda,W,bias,C,ldc,K,accf); break;
    case 3: gemm_kernel<3><<<g,256,0,s>>>(A,lda,W,bias,C,ldc,K,accf); break;
    }
}

static void launch_mfma(int epi, const float* A, int lda, const float* W, const float* bias,
                        float* C, int ldc, int N, int K, int accf, hipStream_t s)
{
    dim3 g(N/128, BL/128);
    switch (epi) {
    case 0: mfma_gemm<0><<<g,256,0,s>>>(A,lda,W,bias,C,ldc,K,accf); break;
    case 1: mfma_gemm<1><<<g,256,0,s>>>(A,lda,W,bias,C,ldc,K,accf); break;
    case 2: mfma_gemm<2><<<g,256,0,s>>>(A,lda,W,bias,C,ldc,K,accf); break;
    case 3: mfma_gemm<3><<<g,256,0,s>>>(A,lda,W,bias,C,ldc,K,accf); break;
    }
}

extern "C" void kernel_launch(void* const* d_in, const int* in_sizes, int n_in,
                              void* d_out, int out_size, void* d_ws, size_t ws_size,
                              hipStream_t stream)
{
    const float* x        = (const float*)d_in[0];
    const float* fre      = (const float*)d_in[1];
    const float* fim      = (const float*)d_in[2];
    const float* cutoff   = (const float*)d_in[3];
    const float* ln0_g    = (const float*)d_in[4];
    const float* ln0_b    = (const float*)d_in[5];
    const float* l1_w     = (const float*)d_in[6];
    const float* l1_b     = (const float*)d_in[7];
    const float* l2_w     = (const float*)d_in[8];
    const float* l2_b     = (const float*)d_in[9];
    const float* in_w     = (const float*)d_in[10];
    const float* conv_w   = (const float*)d_in[11];
    const float* conv_b   = (const float*)d_in[12];
    const float* xproj_w  = (const float*)d_in[13];
    const float* dt_w     = (const float*)d_in[14];
    const float* dt_b     = (const float*)d_in[15];
    const float* A_log    = (const float*)d_in[16];
    const float* Dp       = (const float*)d_in[17];
    const float* out_w    = (const float*)d_in[18];
    const float* ln1_g    = (const float*)d_in[19];
    const float* ln1_b    = (const float*)d_in[20];
    const float* d1_w     = (const float*)d_in[21];
    const float* d1_b     = (const float*)d_in[22];
    const float* d2_w     = (const float*)d_in[23];
    const float* d2_b     = (const float*)d_in[24];
    const float* ln2_g    = (const float*)d_in[25];
    const float* ln2_b    = (const float*)d_in[26];
    const float* ffn_w1   = (const float*)d_in[27];
    const float* ffn_b1   = (const float*)d_in[28];
    const float* ffn_w2   = (const float*)d_in[29];
    const float* ffn_b2   = (const float*)d_in[30];
    const float* ffn_ln_g = (const float*)d_in[31];
    const float* ffn_ln_b = (const float*)d_in[32];

    float* ws = (float*)d_ws;
    float* RK = ws;                   // 512   (pad 1024)
    float* MC = RK + 1024;            // 512*512
    float* XN = MC + 512*512;         // BL*DM   (xn; later hs)
    float* XG = XN + (size_t)BL*DM;   // BL*DM   (xg; later mo)
    float* T1 = XG + (size_t)BL*DM;   // BL*DM  (dead during branch loop)
    float* T2 = T1 + (size_t)BL*DM;   // BL*DM  (dead during branch loop)
    float* XZ = T2 + (size_t)BL*DM;   // BL*2048 (xz; later ffn hidden)
    float* XC = XZ + (size_t)BL*2048; // BL*DI
    float* XD = XC + (size_t)BL*DI;   // BL*64
    float* DL = XD + (size_t)BL*64;   // BL*DI
    float* YG = DL + (size_t)BL*DI;   // BL*DI  (first BL*DM also used as xi)
    float* MS = YG + (size_t)BL*DI;   // BL*DM
    const size_t SCNT = (size_t)BATCH*NC*DI*DS;   // 2M floats
    // scan state buffers ALIAS T1/T2 (dead during the branch loop):
    float* HOUT = T1;                  // SCNT (8 MB)
    float* APR  = T1 + SCNT;           // SCNT (fills rest of T1 exactly)
    float* HIN  = T2;                  // SCNT (first half of T2)
    float* XI = YG;                    // alias (xi consumed before scans run)
    float* OUT = (float*)d_out;

    // 1) frequency filter as circulant GEMM (fp32 — input-most op), then LN(xi + x)
    build_filter_kernel<<<512,256,0,stream>>>(fre, fim, cutoff, RK);
    circ_expand_kernel<<<512,512,0,stream>>>(RK, MC);
    launch_gemm(0, x,DM, MC, nullptr, XI,DM, DM, DM, 0, stream);
    ln_kernel<<<BL,256,0,stream>>>(XI, x, ln0_g, ln0_b, XN, 1e-5f);

    // 2) xg = (xn@l1^T+b1) * silu(xn@l2^T+b2)   [bf16 MFMA]
    launch_mfma(0, XN,DM, l1_w, l1_b, T1,DM, DM, DM, 0, stream);
    launch_mfma(0, XN,DM, l2_w, l2_b, T2,DM, DM, DM, 0, stream);
    mul_silu_kernel<<<(BL*DM)/256,256,0,stream>>>(T1, T2, XG, BL*DM);

    // 3) three mamba branches accumulated into MS
    launch_mfma(0, XG,DM, in_w, nullptr, XZ,2048, 2*DI, DM, 0, stream);
    for (int br = 0; br < 3; ++br) {
        if (br == 2)
            launch_mfma(0, x,DM, in_w, nullptr, XZ,2048, 2*DI, DM, 0, stream);
        int rev = (br == 1) ? 1 : 0;
        conv_silu_kernel<<<(BL*DI)/256,256,0,stream>>>(XZ, conv_w, conv_b, XC, rev);
        launch_gemm(0, XC,DI, xproj_w, nullptr, XD,64, 64, DI, 0, stream);      // fp32 (N=64)
        launch_gemm(1, XD,64, dt_w, dt_b, DL,DI, DI, DR, 0, stream);            // fp32 (K=32), softplus
        {
            dim3 ga(DI/256, NC, BATCH);
            scan_ph_a<<<ga,256,0,stream>>>(DL, XC, XD, A_log, HOUT, APR);
            scan_ph_b<<<(BATCH*DI*DS)/256,256,0,stream>>>(HOUT, APR, HIN);
            scan_ph_c<<<ga,256,0,stream>>>(DL, XC, XD, XZ, A_log, Dp, HIN, YG, rev);
        }
        launch_mfma(0, YG,DI, out_w, nullptr, MS,DM, DM, DI, (br==0)?0:1, stream);
    }

    // 4) mo = LN(m1+m2+m3)
    ln_kernel<<<BL,256,0,stream>>>(MS, nullptr, ln1_g, ln1_b, XG, 1e-12f);

    // 5) ha/hb gate + LN -> hs (in XN)
    launch_mfma(3, XG,DM, d1_w, d1_b, T2,DM, DM, DM, 0, stream);   // hb = silu(...)
    launch_mfma(0, XG,DM, d2_w, d2_b, T1,DM, DM, DM, 0, stream);   // ha
    gate_ln_kernel<<<BL,256,0,stream>>>(T1, T2, XG, ln2_g, ln2_b, XN, 1e-12f);

    // 6) FFN: gelu(hs@w1^T+b1) @ w2^T + b2 ; out = LN(h + hs)
    launch_mfma(2, XN,DM, ffn_w1, ffn_b1, XZ,2048, 4*DM, DM, 0, stream);  // gelu
    launch_mfma(0, XZ,2048, ffn_w2, ffn_b2, T1,DM, DM, 4*DM, 0, stream);
    ln_kernel<<<BL,256,0,stream>>>(T1, XN, ffn_ln_g, ffn_ln_b, OUT, 1e-12f);
}

// Round 5
// 1610.308 us; speedup vs baseline: 6.8957x; 1.0697x over previous
//
#include <hip/hip_runtime.h>
#include <hip/hip_bf16.h>
#include <math.h>

#define BATCH 4
#define SEQ   2048
#define DM    512
#define DI    1024
#define DS    16
#define DR    32
#define BL    (BATCH*SEQ)   // 8192 tokens

#define CH 64               // scan chunk length
#define NC (SEQ/CH)         // 32 chunks per sequence

#define BMT 64
#define BNT 64
#define BKT 16

typedef __attribute__((ext_vector_type(8))) short short8_t;   // 8 bf16 = 4 VGPRs
typedef __attribute__((ext_vector_type(4))) float f32x4_t;    // MFMA acc

__device__ __forceinline__ float sigmoidf_(float x){ return 1.f/(1.f+expf(-x)); }

// packed fp32x2 -> bf16x2 (RNE) via v_cvt_pk_bf16_f32
__device__ __forceinline__ unsigned int pkbf(float x, float y){
    __hip_bfloat162 p = __float22bfloat162_rn(make_float2(x, y));
    return *reinterpret_cast<unsigned int*>(&p);
}
union S8U { short8_t s; unsigned int u[4]; };

// ---------------- FFT filter as circulant kernel (parallel) ----------------
__global__ void build_filter_kernel(const float* __restrict__ fre,
                                    const float* __restrict__ fim,
                                    const float* __restrict__ cut,
                                    float* __restrict__ rker)
{
    int j = blockIdx.x;
    int t = threadIdx.x;
    float c0 = cut[0];
    double acc = 0.0;
    for (int k = t; k < 512; k += 256) {
        float fr = (float)(k < 256 ? k : k - 512) / 512.0f;
        float mask = (fr >= c0 || fr <= -c0) ? 1.f : 0.f;
        double gre = (double)mask + (double)fre[k];
        double gim = (double)fim[k];
        int pr = (j * k) & 511;  // exact angle reduction
        double ang = 6.283185307179586476925286766559 * (double)pr / 512.0;
        acc += gre * cos(ang) - gim * sin(ang);
    }
    #pragma unroll
    for (int o = 32; o > 0; o >>= 1) acc += __shfl_xor(acc, o);
    __shared__ double sd[4];
    int w = t >> 6;
    if ((t & 63) == 0) sd[w] = acc;
    __syncthreads();
    if (t == 0) rker[j] = (float)((sd[0] + sd[1] + sd[2] + sd[3]) / 512.0);
}

__global__ void circ_expand_kernel(const float* __restrict__ rker, float* __restrict__ Mc)
{
    int n = blockIdx.x, m = threadIdx.x;
    Mc[n*512 + m] = rker[(n - m) & 511];
}

// ---------------- fp32 tiled GEMM (small/odd shapes) ----------------
template<int EPI>
__launch_bounds__(256)
__global__ void gemm_kernel(const float* __restrict__ A, int lda,
                            const float* __restrict__ W,
                            const float* __restrict__ bias,
                            float* __restrict__ C, int ldc,
                            int K, int accflag)
{
    __shared__ float As[BKT][BMT];
    __shared__ float Ws[BKT][BNT];
    int t  = threadIdx.x;
    int lr = t >> 2;
    int lc = (t & 3) << 2;
    const float* Ag = A + (size_t)(blockIdx.y*BMT + lr)*lda + lc;
    const float* Wg = W + (size_t)(blockIdx.x*BNT + lr)*K   + lc;
    int tm = (t & 15) << 2;
    int tn = (t >> 4) << 2;
    float acc[4][4] = {};
    for (int kt = 0; kt < K; kt += BKT) {
        float4 av = *(const float4*)(Ag + kt);
        float4 wv = *(const float4*)(Wg + kt);
        __syncthreads();
        As[lc+0][lr]=av.x; As[lc+1][lr]=av.y; As[lc+2][lr]=av.z; As[lc+3][lr]=av.w;
        Ws[lc+0][lr]=wv.x; Ws[lc+1][lr]=wv.y; Ws[lc+2][lr]=wv.z; Ws[lc+3][lr]=wv.w;
        __syncthreads();
        #pragma unroll
        for (int k = 0; k < BKT; ++k) {
            const float4 a4 = *(const float4*)&As[k][tm];
            const float4 w4 = *(const float4*)&Ws[k][tn];
            float ar[4] = {a4.x,a4.y,a4.z,a4.w};
            float wr[4] = {w4.x,w4.y,w4.z,w4.w};
            #pragma unroll
            for (int i=0;i<4;++i)
                #pragma unroll
                for (int j=0;j<4;++j)
                    acc[i][j] = fmaf(ar[i], wr[j], acc[i][j]);
        }
    }
    size_t crow = (size_t)(blockIdx.y*BMT + tm);
    int ccol = blockIdx.x*BNT + tn;
    #pragma unroll
    for (int i=0;i<4;++i) {
        float* Cp = C + (crow+i)*ldc + ccol;
        #pragma unroll
        for (int j=0;j<4;++j) {
            float v = acc[i][j];
            if (bias) v += bias[ccol+j];
            if (EPI==1) v = (v > 20.f) ? v : log1pf(expf(v));
            else if (EPI==2) v = 0.5f*v*(1.f+erff(v*0.70710678118654752440f));
            else if (EPI==3) v = v*sigmoidf_(v);
            if (accflag) Cp[j] += v; else Cp[j] = v;
        }
    }
}

// ---------------- bf16 MFMA GEMM: C = epi(A @ W^T + bias) ----------------
// fp32->bf16 via packed cvt; next K-tile prefetched across frag-read+MFMA.
// EPI: 0 none, 1 softplus, 2 gelu, 3 silu, 4 emul*silu(v)
#define LDP 40
template<int EPI>
__launch_bounds__(256)
__global__ void mfma_gemm(const float* __restrict__ A, int lda,
                          const float* __restrict__ W,
                          const float* __restrict__ bias,
                          const float* __restrict__ emul,
                          float* __restrict__ C, int ldc,
                          int K, int accflag)
{
    __shared__ __align__(16) short As[128*LDP];
    __shared__ __align__(16) short Bs[128*LDP];
    int t = threadIdx.x;
    int lane = t & 63;
    int w  = t >> 6;
    int wr = w >> 1, wc = w & 1;
    int l15 = lane & 15, quad = lane >> 4;

    int srow = t >> 1;            // staging row 0..127
    int scol = (t & 1) << 4;      // k offset 0 or 16
    const int tileM = blockIdx.y * 128;
    const int tileN = blockIdx.x * 128;
    const float* Ag = A + (size_t)(tileM + srow)*lda + scol;
    const float* Wg = W + (size_t)(tileN + srow)*K   + scol;

    f32x4_t acc[4][4];
    #pragma unroll
    for (int i=0;i<4;++i)
        #pragma unroll
        for (int j=0;j<4;++j)
            acc[i][j] = (f32x4_t){0.f,0.f,0.f,0.f};

    // preload K-tile 0
    float4 a0 = *(const float4*)(Ag + 0);
    float4 a1 = *(const float4*)(Ag + 4);
    float4 a2 = *(const float4*)(Ag + 8);
    float4 a3 = *(const float4*)(Ag + 12);
    float4 b0 = *(const float4*)(Wg + 0);
    float4 b1 = *(const float4*)(Wg + 4);
    float4 b2 = *(const float4*)(Wg + 8);
    float4 b3 = *(const float4*)(Wg + 12);

    for (int kt = 0; kt < K; kt += 32) {
        S8U ap0, ap1, bp0, bp1;
        ap0.u[0]=pkbf(a0.x,a0.y); ap0.u[1]=pkbf(a0.z,a0.w);
        ap0.u[2]=pkbf(a1.x,a1.y); ap0.u[3]=pkbf(a1.z,a1.w);
        ap1.u[0]=pkbf(a2.x,a2.y); ap1.u[1]=pkbf(a2.z,a2.w);
        ap1.u[2]=pkbf(a3.x,a3.y); ap1.u[3]=pkbf(a3.z,a3.w);
        bp0.u[0]=pkbf(b0.x,b0.y); bp0.u[1]=pkbf(b0.z,b0.w);
        bp0.u[2]=pkbf(b1.x,b1.y); bp0.u[3]=pkbf(b1.z,b1.w);
        bp1.u[0]=pkbf(b2.x,b2.y); bp1.u[1]=pkbf(b2.z,b2.w);
        bp1.u[2]=pkbf(b3.x,b3.y); bp1.u[3]=pkbf(b3.z,b3.w);
        __syncthreads();
        *(short8_t*)&As[srow*LDP + scol]     = ap0.s;
        *(short8_t*)&As[srow*LDP + scol + 8] = ap1.s;
        *(short8_t*)&Bs[srow*LDP + scol]     = bp0.s;
        *(short8_t*)&Bs[srow*LDP + scol + 8] = bp1.s;
        __syncthreads();
        // prefetch next K-tile (stays in flight across frag reads + MFMA)
        int kn = kt + 32; if (kn >= K) kn = 0;
        a0 = *(const float4*)(Ag + kn + 0);
        a1 = *(const float4*)(Ag + kn + 4);
        a2 = *(const float4*)(Ag + kn + 8);
        a3 = *(const float4*)(Ag + kn + 12);
        b0 = *(const float4*)(Wg + kn + 0);
        b1 = *(const float4*)(Wg + kn + 4);
        b2 = *(const float4*)(Wg + kn + 8);
        b3 = *(const float4*)(Wg + kn + 12);
        short8_t af[4], bfv[4];
        #pragma unroll
        for (int mi=0;mi<4;++mi)
            af[mi] = *(const short8_t*)&As[(wr*64 + mi*16 + l15)*LDP + quad*8];
        #pragma unroll
        for (int ni=0;ni<4;++ni)
            bfv[ni] = *(const short8_t*)&Bs[(wc*64 + ni*16 + l15)*LDP + quad*8];
        #pragma unroll
        for (int mi=0;mi<4;++mi)
            #pragma unroll
            for (int ni=0;ni<4;++ni)
                acc[mi][ni] = __builtin_amdgcn_mfma_f32_16x16x32_bf16(af[mi], bfv[ni], acc[mi][ni], 0, 0, 0);
    }

    // epilogue: C/D layout col=lane&15, row=quad*4+reg
    #pragma unroll
    for (int mi=0;mi<4;++mi) {
        #pragma unroll
        for (int ni=0;ni<4;++ni) {
            int gm0 = tileM + wr*64 + mi*16 + quad*4;
            int gn  = tileN + wc*64 + ni*16 + l15;
            float bv = bias ? bias[gn] : 0.f;
            #pragma unroll
            for (int r=0;r<4;++r) {
                size_t off = (size_t)(gm0 + r)*ldc + gn;
                float v = acc[mi][ni][r] + bv;
                if (EPI==1) v = (v > 20.f) ? v : log1pf(expf(v));
                else if (EPI==2) v = 0.5f*v*(1.f+erff(v*0.70710678118654752440f));
                else if (EPI==3) v = v*sigmoidf_(v);
                else if (EPI==4) v = emul[off] * (v*sigmoidf_(v));
                if (accflag) C[off] += v; else C[off] = v;
            }
        }
    }
}

// ---------------- depthwise causal conv (k=4) + silu ----------------
__launch_bounds__(256)
__global__ void conv_silu_kernel(const float* __restrict__ xz,
                                 const float* __restrict__ cw,
                                 const float* __restrict__ cb,
                                 float* __restrict__ xc, int rev)
{
    size_t idx = (size_t)blockIdx.x*256 + threadIdx.x;
    int c = (int)(idx & (DI-1));
    size_t bl = idx >> 10;
    int l = (int)(bl & (SEQ-1));
    int b = (int)(bl >> 11);
    float accv = cb[c];
    #pragma unroll
    for (int k = 0; k < 4; ++k) {
        int ts = l + k - 3;
        if (ts >= 0) {
            int tin = rev ? (SEQ-1-ts) : ts;
            accv = fmaf(cw[c*4+k], xz[((size_t)b*SEQ + tin)*2048 + c], accv);
        }
    }
    xc[idx] = accv * sigmoidf_(accv);
}

// ================= chunked parallel selective scan =================
__launch_bounds__(256)
__global__ void scan_ph_a(const float* __restrict__ dl,
                          const float* __restrict__ xc,
                          const float* __restrict__ xd,
                          const float* __restrict__ A_log,
                          float* __restrict__ hout,
                          float* __restrict__ aprod)
{
    int d = blockIdx.x*256 + threadIdx.x;
    int c = blockIdx.y;
    int b = blockIdx.z;
    float An[DS];
    #pragma unroll
    for (int n=0;n<DS;++n) An[n] = -expf(A_log[d*DS+n]);
    float h[DS], P[DS];
    #pragma unroll
    for (int n=0;n<DS;++n) { h[n]=0.f; P[n]=1.f; }
    size_t row0 = (size_t)b*SEQ + (size_t)c*CH;
    for (int t=0;t<CH;++t) {
        size_t row = row0 + t;
        float dv = dl[row*DI + d];
        float uv = xc[row*DI + d];
        float du = dv*uv;
        float Bv[DS];
        *(float4*)&Bv[0]  = *(const float4*)(xd + row*64 + 32);
        *(float4*)&Bv[4]  = *(const float4*)(xd + row*64 + 36);
        *(float4*)&Bv[8]  = *(const float4*)(xd + row*64 + 40);
        *(float4*)&Bv[12] = *(const float4*)(xd + row*64 + 44);
        #pragma unroll
        for (int n=0;n<DS;++n) {
            float dA = expf(dv*An[n]);
            h[n] = fmaf(dA, h[n], du*Bv[n]);
            P[n] *= dA;
        }
    }
    size_t o = (((size_t)b*NC + c)*DI + d)*DS;
    #pragma unroll
    for (int q=0;q<4;++q) {
        *(float4*)(hout  + o + 4*q) = make_float4(h[4*q],h[4*q+1],h[4*q+2],h[4*q+3]);
        *(float4*)(aprod + o + 4*q) = make_float4(P[4*q],P[4*q+1],P[4*q+2],P[4*q+3]);
    }
}

__launch_bounds__(256)
__global__ void scan_ph_b(const float* __restrict__ hout,
                          const float* __restrict__ aprod,
                          float* __restrict__ hin)
{
    int idx = blockIdx.x*256 + threadIdx.x;
    int b  = idx >> 14;
    int dn = idx & (DI*DS - 1);
    float hc = 0.f;
    for (int c=0;c<NC;++c) {
        size_t o = ((size_t)b*NC + c)*(DI*DS) + dn;
        hin[o] = hc;
        hc = fmaf(aprod[o], hc, hout[o]);
    }
}

__launch_bounds__(256)
__global__ void scan_ph_c(const float* __restrict__ dl,
                          const float* __restrict__ xc,
                          const float* __restrict__ xd,
                          const float* __restrict__ xz,
                          const float* __restrict__ A_log,
                          const float* __restrict__ Dp,
                          const float* __restrict__ hin,
                          float* __restrict__ yg, int rev, int accf)
{
    int d = blockIdx.x*256 + threadIdx.x;
    int c = blockIdx.y;
    int b = blockIdx.z;
    float An[DS];
    #pragma unroll
    for (int n=0;n<DS;++n) An[n] = -expf(A_log[d*DS+n]);
    float h[DS];
    size_t o = (((size_t)b*NC + c)*DI + d)*DS;
    #pragma unroll
    for (int q=0;q<4;++q) {
        float4 hv = *(const float4*)(hin + o + 4*q);
        h[4*q]=hv.x; h[4*q+1]=hv.y; h[4*q+2]=hv.z; h[4*q+3]=hv.w;
    }
    float Dd = Dp[d];
    size_t row0 = (size_t)b*SEQ + (size_t)c*CH;
    for (int t=0;t<CH;++t) {
        size_t row = row0 + t;
        float dv = dl[row*DI + d];
        float uv = xc[row*DI + d];
        float du = dv*uv;
        float Bv[DS], Cv[DS];
        *(float4*)&Bv[0]  = *(const float4*)(xd + row*64 + 32);
        *(float4*)&Bv[4]  = *(const float4*)(xd + row*64 + 36);
        *(float4*)&Bv[8]  = *(const float4*)(xd + row*64 + 40);
        *(float4*)&Bv[12] = *(const float4*)(xd + row*64 + 44);
        *(float4*)&Cv[0]  = *(const float4*)(xd + row*64 + 48);
        *(float4*)&Cv[4]  = *(const float4*)(xd + row*64 + 52);
        *(float4*)&Cv[8]  = *(const float4*)(xd + row*64 + 56);
        *(float4*)&Cv[12] = *(const float4*)(xd + row*64 + 60);
        int l = c*CH + t;
        int tz = rev ? (SEQ-1-l) : l;
        float zv = xz[((size_t)b*SEQ + tz)*2048 + DI + d];
        float y = 0.f;
        #pragma unroll
        for (int n=0;n<DS;++n) {
            float dA = expf(dv*An[n]);
            h[n] = fmaf(dA, h[n], du*Bv[n]);
            y = fmaf(h[n], Cv[n], y);
        }
        float val = (y + uv*Dd) * (zv * sigmoidf_(zv));
        if (accf) yg[row*DI + d] += val; else yg[row*DI + d] = val;
    }
}

// ---------------- layernorm over d=512 (optional residual) ----------------
__launch_bounds__(256)
__global__ void ln_kernel(const float* __restrict__ a, const float* __restrict__ res,
                          const float* __restrict__ g, const float* __restrict__ bta,
                          float* __restrict__ out, float eps)
{
    size_t row = blockIdx.x;
    int t = threadIdx.x;
    const float* ap = a + row*DM;
    float v0 = ap[t], v1 = ap[t+256];
    if (res) { const float* rp = res + row*DM; v0 += rp[t]; v1 += rp[t+256]; }
    float s = v0+v1, q = v0*v0 + v1*v1;
    #pragma unroll
    for (int o=32;o>0;o>>=1){ s += __shfl_xor(s,o); q += __shfl_xor(q,o); }
    __shared__ float ss[4], sq[4];
    int w = t>>6;
    if ((t&63)==0){ ss[w]=s; sq[w]=q; }
    __syncthreads();
    s = ss[0]+ss[1]+ss[2]+ss[3];
    q = sq[0]+sq[1]+sq[2]+sq[3];
    float mean = s * (1.f/DM);
    float var  = q * (1.f/DM) - mean*mean;
    var = var < 0.f ? 0.f : var;
    float rstd = rsqrtf(var + eps);
    out[row*DM+t]     = (v0-mean)*rstd*g[t]     + bta[t];
    out[row*DM+t+256] = (v1-mean)*rstd*g[t+256] + bta[t+256];
}

__launch_bounds__(256)
__global__ void gate_ln_kernel(const float* __restrict__ ha, const float* __restrict__ hb,
                               const float* __restrict__ mo,
                               const float* __restrict__ g, const float* __restrict__ bta,
                               float* __restrict__ out, float eps)
{
    size_t row = blockIdx.x;
    int t = threadIdx.x;
    size_t i0 = row*DM + t, i1 = i0 + 256;
    float a0 = ha[i0], a1 = ha[i1];
    float v0 = fmaf(a0, hb[i0], a0) + mo[i0];
    float v1 = fmaf(a1, hb[i1], a1) + mo[i1];
    float s = v0+v1, q = v0*v0 + v1*v1;
    #pragma unroll
    for (int o=32;o>0;o>>=1){ s += __shfl_xor(s,o); q += __shfl_xor(q,o); }
    __shared__ float ss[4], sq[4];
    int w = t>>6;
    if ((t&63)==0){ ss[w]=s; sq[w]=q; }
    __syncthreads();
    s = ss[0]+ss[1]+ss[2]+ss[3];
    q = sq[0]+sq[1]+sq[2]+sq[3];
    float mean = s * (1.f/DM);
    float var  = q * (1.f/DM) - mean*mean;
    var = var < 0.f ? 0.f : var;
    float rstd = rsqrtf(var + eps);
    out[i0] = (v0-mean)*rstd*g[t]     + bta[t];
    out[i1] = (v1-mean)*rstd*g[t+256] + bta[t+256];
}

// ================= host side =================
static void launch_gemm(int epi, const float* A, int lda, const float* W, const float* bias,
                        float* C, int ldc, int N, int K, int accf, hipStream_t s)
{
    dim3 g(N/BNT, BL/BMT);
    switch (epi) {
    case 0: gemm_kernel<0><<<g,256,0,s>>>(A,lda,W,bias,C,ldc,K,accf); break;
    case 1: gemm_kernel<1><<<g,256,0,s>>>(A,lda,W,bias,C,ldc,K,accf); break;
    case 2: gemm_kernel<2><<<g,256,0,s>>>(A,lda,W,bias,C,ldc,K,accf); break;
    case 3: gemm_kernel<3><<<g,256,0,s>>>(A,lda,W,bias,C,ldc,K,accf); break;
    }
}

static void launch_mfma(int epi, const float* A, int lda, const float* W, const float* bias,
                        const float* emul, float* C, int ldc, int N, int K, int accf,
                        hipStream_t s)
{
    dim3 g(N/128, BL/128);
    switch (epi) {
    case 0: mfma_gemm<0><<<g,256,0,s>>>(A,lda,W,bias,emul,C,ldc,K,accf); break;
    case 1: mfma_gemm<1><<<g,256,0,s>>>(A,lda,W,bias,emul,C,ldc,K,accf); break;
    case 2: mfma_gemm<2><<<g,256,0,s>>>(A,lda,W,bias,emul,C,ldc,K,accf); break;
    case 3: mfma_gemm<3><<<g,256,0,s>>>(A,lda,W,bias,emul,C,ldc,K,accf); break;
    case 4: mfma_gemm<4><<<g,256,0,s>>>(A,lda,W,bias,emul,C,ldc,K,accf); break;
    }
}

extern "C" void kernel_launch(void* const* d_in, const int* in_sizes, int n_in,
                              void* d_out, int out_size, void* d_ws, size_t ws_size,
                              hipStream_t stream)
{
    const float* x        = (const float*)d_in[0];
    const float* fre      = (const float*)d_in[1];
    const float* fim      = (const float*)d_in[2];
    const float* cutoff   = (const float*)d_in[3];
    const float* ln0_g    = (const float*)d_in[4];
    const float* ln0_b    = (const float*)d_in[5];
    const float* l1_w     = (const float*)d_in[6];
    const float* l1_b     = (const float*)d_in[7];
    const float* l2_w     = (const float*)d_in[8];
    const float* l2_b     = (const float*)d_in[9];
    const float* in_w     = (const float*)d_in[10];
    const float* conv_w   = (const float*)d_in[11];
    const float* conv_b   = (const float*)d_in[12];
    const float* xproj_w  = (const float*)d_in[13];
    const float* dt_w     = (const float*)d_in[14];
    const float* dt_b     = (const float*)d_in[15];
    const float* A_log    = (const float*)d_in[16];
    const float* Dp       = (const float*)d_in[17];
    const float* out_w    = (const float*)d_in[18];
    const float* ln1_g    = (const float*)d_in[19];
    const float* ln1_b    = (const float*)d_in[20];
    const float* d1_w     = (const float*)d_in[21];
    const float* d1_b     = (const float*)d_in[22];
    const float* d2_w     = (const float*)d_in[23];
    const float* d2_b     = (const float*)d_in[24];
    const float* ln2_g    = (const float*)d_in[25];
    const float* ln2_b    = (const float*)d_in[26];
    const float* ffn_w1   = (const float*)d_in[27];
    const float* ffn_b1   = (const float*)d_in[28];
    const float* ffn_w2   = (const float*)d_in[29];
    const float* ffn_b2   = (const float*)d_in[30];
    const float* ffn_ln_g = (const float*)d_in[31];
    const float* ffn_ln_b = (const float*)d_in[32];

    float* ws = (float*)d_ws;
    float* RK = ws;                   // 512   (pad 1024)
    float* MC = RK + 1024;            // 512*512
    float* XN = MC + 512*512;         // BL*DM   (xn; later hs)
    float* XG = XN + (size_t)BL*DM;   // BL*DM   (xg; later mo)
    float* T1 = XG + (size_t)BL*DM;   // BL*DM  (dead during branch loop)
    float* T2 = T1 + (size_t)BL*DM;   // BL*DM  (dead during branch loop)
    float* XZ = T2 + (size_t)BL*DM;   // BL*2048 (xz; later ffn hidden)
    float* XC = XZ + (size_t)BL*2048; // BL*DI
    float* XD = XC + (size_t)BL*DI;   // BL*64
    float* DL = XD + (size_t)BL*64;   // BL*DI
    float* YG = DL + (size_t)BL*DI;   // BL*DI  (first BL*DM also used as xi)
    float* MS = YG + (size_t)BL*DI;   // BL*DM
    const size_t SCNT = (size_t)BATCH*NC*DI*DS;   // 2M floats
    // scan state buffers ALIAS T1/T2 (dead during the branch loop):
    float* HOUT = T1;                  // SCNT (8 MB)
    float* APR  = T1 + SCNT;           // SCNT (fills rest of T1 exactly)
    float* HIN  = T2;                  // SCNT (first half of T2)
    float* XI = YG;                    // alias (xi consumed before scans run)
    float* OUT = (float*)d_out;

    // 1) frequency filter as circulant GEMM (fp32 — input-most op), then LN(xi + x)
    build_filter_kernel<<<512,256,0,stream>>>(fre, fim, cutoff, RK);
    circ_expand_kernel<<<512,512,0,stream>>>(RK, MC);
    launch_gemm(0, x,DM, MC, nullptr, XI,DM, DM, DM, 0, stream);
    ln_kernel<<<BL,256,0,stream>>>(XI, x, ln0_g, ln0_b, XN, 1e-5f);

    // 2) xg = (xn@l1^T+b1) * silu(xn@l2^T+b2)   [silu-mul fused into l2 epilogue]
    launch_mfma(0, XN,DM, l1_w, l1_b, nullptr, T1,DM, DM, DM, 0, stream);
    launch_mfma(4, XN,DM, l2_w, l2_b, T1,      XG,DM, DM, DM, 0, stream);

    // 3) three mamba branches; yg accumulated in-place, ONE out_proj after
    launch_mfma(0, XG,DM, in_w, nullptr, nullptr, XZ,2048, 2*DI, DM, 0, stream);
    for (int br = 0; br < 3; ++br) {
        if (br == 2)
            launch_mfma(0, x,DM, in_w, nullptr, nullptr, XZ,2048, 2*DI, DM, 0, stream);
        int rev = (br == 1) ? 1 : 0;
        conv_silu_kernel<<<(BL*DI)/256,256,0,stream>>>(XZ, conv_w, conv_b, XC, rev);
        launch_gemm(0, XC,DI, xproj_w, nullptr, XD,64, 64, DI, 0, stream);      // fp32 (N=64)
        launch_gemm(1, XD,64, dt_w, dt_b, DL,DI, DI, DR, 0, stream);            // fp32 softplus
        {
            dim3 ga(DI/256, NC, BATCH);
            scan_ph_a<<<ga,256,0,stream>>>(DL, XC, XD, A_log, HOUT, APR);
            scan_ph_b<<<(BATCH*DI*DS)/256,256,0,stream>>>(HOUT, APR, HIN);
            scan_ph_c<<<ga,256,0,stream>>>(DL, XC, XD, XZ, A_log, Dp, HIN, YG, rev, (br==0)?0:1);
        }
    }
    launch_mfma(0, YG,DI, out_w, nullptr, nullptr, MS,DM, DM, DI, 0, stream);

    // 4) mo = LN(m1+m2+m3)
    ln_kernel<<<BL,256,0,stream>>>(MS, nullptr, ln1_g, ln1_b, XG, 1e-12f);

    // 5) ha/hb gate + LN -> hs (in XN)
    launch_mfma(3, XG,DM, d1_w, d1_b, nullptr, T2,DM, DM, DM, 0, stream);   // hb = silu(...)
    launch_mfma(0, XG,DM, d2_w, d2_b, nullptr, T1,DM, DM, DM, 0, stream);   // ha
    gate_ln_kernel<<<BL,256,0,stream>>>(T1, T2, XG, ln2_g, ln2_b, XN, 1e-12f);

    // 6) FFN: gelu(hs@w1^T+b1) @ w2^T + b2 ; out = LN(h + hs)
    launch_mfma(2, XN,DM, ffn_w1, ffn_b1, nullptr, XZ,2048, 4*DM, DM, 0, stream);  // gelu
    launch_mfma(0, XZ,2048, ffn_w2, ffn_b2, nullptr, T1,DM, DM, 4*DM, 0, stream);
    ln_kernel<<<BL,256,0,stream>>>(T1, XN, ffn_ln_g, ffn_ln_b, OUT, 1e-12f);
}

// Round 6
// 1378.953 us; speedup vs baseline: 8.0526x; 1.1678x over previous
//
#include <hip/hip_runtime.h>
#include <math.h>

#define BATCH 4
#define SEQ   2048
#define DM    512
#define DI    1024
#define DS    16
#define DR    32
#define BL    (BATCH*SEQ)   // 8192 tokens

#define CH 64               // scan chunk length
#define NC (SEQ/CH)         // 32 chunks per sequence

#define BMT 64
#define BNT 64
#define BKT 16

typedef __attribute__((ext_vector_type(8))) short short8_t;   // 8 bf16 = 4 VGPRs
typedef __attribute__((ext_vector_type(4))) float f32x4_t;    // MFMA acc
typedef unsigned short ushort_t;

__device__ __forceinline__ float sigmoidf_(float x){ return 1.f/(1.f+expf(-x)); }

// fp32 -> bf16 bits (RNE)
__device__ __forceinline__ ushort_t f2bf(float f){
    unsigned int u = __float_as_uint(f);
    unsigned int r = (u + 0x7fffu + ((u >> 16) & 1u)) >> 16;
    return (ushort_t)r;
}
__device__ __forceinline__ float bf2f(ushort_t b){
    return __uint_as_float(((unsigned int)b) << 16);
}

// async global->LDS, 16 B per lane; LDS dest = wave-uniform base + lane*16
__device__ __forceinline__ void gload16(const ushort_t* g, ushort_t* lds){
    __builtin_amdgcn_global_load_lds(
        (const __attribute__((address_space(1))) unsigned int*)g,
        (__attribute__((address_space(3))) unsigned int*)lds, 16, 0, 0);
}

// ---------------- FFT filter as circulant kernel (parallel) ----------------
__global__ void build_filter_kernel(const float* __restrict__ fre,
                                    const float* __restrict__ fim,
                                    const float* __restrict__ cut,
                                    float* __restrict__ rker)
{
    int j = blockIdx.x;
    int t = threadIdx.x;
    float c0 = cut[0];
    double acc = 0.0;
    for (int k = t; k < 512; k += 256) {
        float fr = (float)(k < 256 ? k : k - 512) / 512.0f;
        float mask = (fr >= c0 || fr <= -c0) ? 1.f : 0.f;
        double gre = (double)mask + (double)fre[k];
        double gim = (double)fim[k];
        int pr = (j * k) & 511;  // exact angle reduction
        double ang = 6.283185307179586476925286766559 * (double)pr / 512.0;
        acc += gre * cos(ang) - gim * sin(ang);
    }
    #pragma unroll
    for (int o = 32; o > 0; o >>= 1) acc += __shfl_xor(acc, o);
    __shared__ double sd[4];
    int w = t >> 6;
    if ((t & 63) == 0) sd[w] = acc;
    __syncthreads();
    if (t == 0) rker[j] = (float)((sd[0] + sd[1] + sd[2] + sd[3]) / 512.0);
}

// circulant weight, directly bf16: Mc[n][m] = r[(n-m) mod 512]
__global__ void circ_expand_kernel(const float* __restrict__ rker, ushort_t* __restrict__ Mc)
{
    int n = blockIdx.x, m = threadIdx.x;
    Mc[n*512 + m] = f2bf(rker[(n - m) & 511]);
}

// fp32 -> bf16 cast, 4 elems/thread
__global__ void cast4_kernel(const float* __restrict__ in, ushort_t* __restrict__ out, int n4)
{
    int i = blockIdx.x*256 + threadIdx.x;
    if (i < n4) {
        float4 v = ((const float4*)in)[i];
        ushort_t o0 = f2bf(v.x), o1 = f2bf(v.y), o2 = f2bf(v.z), o3 = f2bf(v.w);
        unsigned int lo = (unsigned int)o0 | ((unsigned int)o1 << 16);
        unsigned int hi = (unsigned int)o2 | ((unsigned int)o3 << 16);
        ((uint2*)out)[i] = make_uint2(lo, hi);
    }
}

// xproj weight: 64x1024 fp32 -> 128x1024 bf16 with zero-padded rows 64..127
__global__ void cast_xproj_kernel(const float* __restrict__ in, ushort_t* __restrict__ out)
{
    int i = blockIdx.x*256 + threadIdx.x;  // 131072 total
    int r = i >> 10;
    out[i] = (r < 64) ? f2bf(in[i]) : (ushort_t)0;
}

// ---------------- fp32 tiled GEMM (dt only): C = softplus(A @ W^T + bias) ----------------
__launch_bounds__(256)
__global__ void gemm_sp_kernel(const float* __restrict__ A, int lda,
                               const float* __restrict__ W,
                               const float* __restrict__ bias,
                               float* __restrict__ C, int ldc, int K)
{
    __shared__ float As[BKT][BMT];
    __shared__ float Ws[BKT][BNT];
    int t  = threadIdx.x;
    int lr = t >> 2;
    int lc = (t & 3) << 2;
    const float* Ag = A + (size_t)(blockIdx.y*BMT + lr)*lda + lc;
    const float* Wg = W + (size_t)(blockIdx.x*BNT + lr)*K   + lc;
    int tm = (t & 15) << 2;
    int tn = (t >> 4) << 2;
    float acc[4][4] = {};
    for (int kt = 0; kt < K; kt += BKT) {
        float4 av = *(const float4*)(Ag + kt);
        float4 wv = *(const float4*)(Wg + kt);
        __syncthreads();
        As[lc+0][lr]=av.x; As[lc+1][lr]=av.y; As[lc+2][lr]=av.z; As[lc+3][lr]=av.w;
        Ws[lc+0][lr]=wv.x; Ws[lc+1][lr]=wv.y; Ws[lc+2][lr]=wv.z; Ws[lc+3][lr]=wv.w;
        __syncthreads();
        #pragma unroll
        for (int k = 0; k < BKT; ++k) {
            const float4 a4 = *(const float4*)&As[k][tm];
            const float4 w4 = *(const float4*)&Ws[k][tn];
            float ar[4] = {a4.x,a4.y,a4.z,a4.w};
            float wr[4] = {w4.x,w4.y,w4.z,w4.w};
            #pragma unroll
            for (int i=0;i<4;++i)
                #pragma unroll
                for (int j=0;j<4;++j)
                    acc[i][j] = fmaf(ar[i], wr[j], acc[i][j]);
        }
    }
    size_t crow = (size_t)(blockIdx.y*BMT + tm);
    int ccol = blockIdx.x*BNT + tn;
    #pragma unroll
    for (int i=0;i<4;++i) {
        float* Cp = C + (crow+i)*ldc + ccol;
        #pragma unroll
        for (int j=0;j<4;++j) {
            float v = acc[i][j] + bias[ccol+j];
            Cp[j] = (v > 20.f) ? v : log1pf(expf(v));
        }
    }
}

// ---------------- bf16-native MFMA GEMM (m97 structure) ----------------
// C[m][n] = epi( sum_k A[m][k]*W[n][k] + bias[n] )
// A: M x K bf16 (row stride lda), W: N x K bf16 (contiguous rows of K)
// 128x128 tile, BK=32, 4 waves 2x2, each wave 64x64 via 4x4 frags 16x16x32.
// Staging via global_load_lds width=16 (no VGPR roundtrip, no padding allowed).
// EPI: 0 none, 2 gelu, 3 silu, 4 emul*silu.  C and Cb (bf16 mirror) nullable.
template<int EPI>
__launch_bounds__(256)
__global__ void bgemm(const ushort_t* __restrict__ A, int lda,
                      const ushort_t* __restrict__ W,
                      const float* __restrict__ bias,
                      const float* __restrict__ emul,
                      float* __restrict__ C,
                      ushort_t* __restrict__ Cb,
                      int ldc, int K, int Nvalid, int accflag)
{
    __shared__ __align__(16) ushort_t As[128*32];
    __shared__ __align__(16) ushort_t Bs[128*32];
    int t = threadIdx.x;
    int lane = t & 63;
    int w  = t >> 6;
    int wr = w >> 1, wc = w & 1;
    int l15 = lane & 15, quad = lane >> 4;
    const int tileM = blockIdx.y * 128;
    const int tileN = blockIdx.x * 128;

    // staging addressing: wave w, inst i covers LDS bytes [w*2048 + i*1024, +1024)
    // lane l -> row w*32 + i*16 + (l>>2), col (l&3)*8 (bf16 elems)
    int srow = w*32 + (lane >> 2);
    int scol = (lane & 3) * 8;
    const ushort_t* gA0 = A + (size_t)(tileM + srow)*lda + scol;
    const ushort_t* gA1 = gA0 + (size_t)16*lda;
    const ushort_t* gW0 = W + (size_t)(tileN + srow)*K + scol;
    const ushort_t* gW1 = gW0 + (size_t)16*K;
    ushort_t* ldsA = As + w*1024;   // wave-uniform
    ushort_t* ldsB = Bs + w*1024;

    f32x4_t acc[4][4];
    #pragma unroll
    for (int i=0;i<4;++i)
        #pragma unroll
        for (int j=0;j<4;++j)
            acc[i][j] = (f32x4_t){0.f,0.f,0.f,0.f};

    for (int kt = 0; kt < K; kt += 32) {
        __syncthreads();   // previous iter's ds_reads done before overwrite
        gload16(gA0 + kt, ldsA);
        gload16(gA1 + kt, ldsA + 512);
        gload16(gW0 + kt, ldsB);
        gload16(gW1 + kt, ldsB + 512);
        __syncthreads();   // compiler drains vmcnt(0) -> staged data visible
        short8_t af[4], bfv[4];
        #pragma unroll
        for (int mi=0;mi<4;++mi)
            af[mi] = *(const short8_t*)&As[(wr*64 + mi*16 + l15)*32 + quad*8];
        #pragma unroll
        for (int ni=0;ni<4;++ni)
            bfv[ni] = *(const short8_t*)&Bs[(wc*64 + ni*16 + l15)*32 + quad*8];
        #pragma unroll
        for (int mi=0;mi<4;++mi)
            #pragma unroll
            for (int ni=0;ni<4;++ni)
                acc[mi][ni] = __builtin_amdgcn_mfma_f32_16x16x32_bf16(af[mi], bfv[ni], acc[mi][ni], 0, 0, 0);
    }

    // epilogue: C/D layout col=lane&15, row=quad*4+reg
    #pragma unroll
    for (int mi=0;mi<4;++mi) {
        #pragma unroll
        for (int ni=0;ni<4;++ni) {
            int gm0 = tileM + wr*64 + mi*16 + quad*4;
            int gn  = tileN + wc*64 + ni*16 + l15;
            if (gn >= Nvalid) continue;
            float bv = bias ? bias[gn] : 0.f;
            #pragma unroll
            for (int r=0;r<4;++r) {
                size_t off = (size_t)(gm0 + r)*ldc + gn;
                float v = acc[mi][ni][r] + bv;
                if (EPI==2) v = 0.5f*v*(1.f+erff(v*0.70710678118654752440f));
                else if (EPI==3) v = v*sigmoidf_(v);
                else if (EPI==4) v = emul[off] * (v*sigmoidf_(v));
                if (C) { if (accflag) C[off] += v; else C[off] = v; }
                if (Cb) Cb[off] = f2bf(v);
            }
        }
    }
}

// ---------------- depthwise causal conv (k=4) + silu -> bf16 ----------------
__launch_bounds__(256)
__global__ void conv_silu_kernel(const float* __restrict__ xz,
                                 const float* __restrict__ cw,
                                 const float* __restrict__ cb,
                                 ushort_t* __restrict__ xcb, int rev)
{
    size_t idx = (size_t)blockIdx.x*256 + threadIdx.x;
    int c = (int)(idx & (DI-1));
    size_t bl = idx >> 10;
    int l = (int)(bl & (SEQ-1));
    int b = (int)(bl >> 11);
    float accv = cb[c];
    #pragma unroll
    for (int k = 0; k < 4; ++k) {
        int ts = l + k - 3;
        if (ts >= 0) {
            int tin = rev ? (SEQ-1-ts) : ts;
            accv = fmaf(cw[c*4+k], xz[((size_t)b*SEQ + tin)*2048 + c], accv);
        }
    }
    xcb[idx] = f2bf(accv * sigmoidf_(accv));
}

// ================= chunked parallel selective scan (u read as bf16) =================
__launch_bounds__(256)
__global__ void scan_ph_a(const float* __restrict__ dl,
                          const ushort_t* __restrict__ xcb,
                          const float* __restrict__ xd,
                          const float* __restrict__ A_log,
                          float* __restrict__ hout,
                          float* __restrict__ aprod)
{
    int d = blockIdx.x*256 + threadIdx.x;
    int c = blockIdx.y;
    int b = blockIdx.z;
    float An[DS];
    #pragma unroll
    for (int n=0;n<DS;++n) An[n] = -expf(A_log[d*DS+n]);
    float h[DS], P[DS];
    #pragma unroll
    for (int n=0;n<DS;++n) { h[n]=0.f; P[n]=1.f; }
    size_t row0 = (size_t)b*SEQ + (size_t)c*CH;
    for (int t=0;t<CH;++t) {
        size_t row = row0 + t;
        float dv = dl[row*DI + d];
        float uv = bf2f(xcb[row*DI + d]);
        float du = dv*uv;
        float Bv[DS];
        *(float4*)&Bv[0]  = *(const float4*)(xd + row*64 + 32);
        *(float4*)&Bv[4]  = *(const float4*)(xd + row*64 + 36);
        *(float4*)&Bv[8]  = *(const float4*)(xd + row*64 + 40);
        *(float4*)&Bv[12] = *(const float4*)(xd + row*64 + 44);
        #pragma unroll
        for (int n=0;n<DS;++n) {
            float dA = expf(dv*An[n]);
            h[n] = fmaf(dA, h[n], du*Bv[n]);
            P[n] *= dA;
        }
    }
    size_t o = (((size_t)b*NC + c)*DI + d)*DS;
    #pragma unroll
    for (int q=0;q<4;++q) {
        *(float4*)(hout  + o + 4*q) = make_float4(h[4*q],h[4*q+1],h[4*q+2],h[4*q+3]);
        *(float4*)(aprod + o + 4*q) = make_float4(P[4*q],P[4*q+1],P[4*q+2],P[4*q+3]);
    }
}

__launch_bounds__(256)
__global__ void scan_ph_b(const float* __restrict__ hout,
                          const float* __restrict__ aprod,
                          float* __restrict__ hin)
{
    int idx = blockIdx.x*256 + threadIdx.x;
    int b  = idx >> 14;
    int dn = idx & (DI*DS - 1);
    float hc = 0.f;
    for (int c=0;c<NC;++c) {
        size_t o = ((size_t)b*NC + c)*(DI*DS) + dn;
        hin[o] = hc;
        hc = fmaf(aprod[o], hc, hout[o]);
    }
}

__launch_bounds__(256)
__global__ void scan_ph_c(const float* __restrict__ dl,
                          const ushort_t* __restrict__ xcb,
                          const float* __restrict__ xd,
                          const float* __restrict__ xz,
                          const float* __restrict__ A_log,
                          const float* __restrict__ Dp,
                          const float* __restrict__ hin,
                          float* __restrict__ yg, int rev, int accf)
{
    int d = blockIdx.x*256 + threadIdx.x;
    int c = blockIdx.y;
    int b = blockIdx.z;
    float An[DS];
    #pragma unroll
    for (int n=0;n<DS;++n) An[n] = -expf(A_log[d*DS+n]);
    float h[DS];
    size_t o = (((size_t)b*NC + c)*DI + d)*DS;
    #pragma unroll
    for (int q=0;q<4;++q) {
        float4 hv = *(const float4*)(hin + o + 4*q);
        h[4*q]=hv.x; h[4*q+1]=hv.y; h[4*q+2]=hv.z; h[4*q+3]=hv.w;
    }
    float Dd = Dp[d];
    size_t row0 = (size_t)b*SEQ + (size_t)c*CH;
    for (int t=0;t<CH;++t) {
        size_t row = row0 + t;
        float dv = dl[row*DI + d];
        float uv = bf2f(xcb[row*DI + d]);
        float du = dv*uv;
        float Bv[DS], Cv[DS];
        *(float4*)&Bv[0]  = *(const float4*)(xd + row*64 + 32);
        *(float4*)&Bv[4]  = *(const float4*)(xd + row*64 + 36);
        *(float4*)&Bv[8]  = *(const float4*)(xd + row*64 + 40);
        *(float4*)&Bv[12] = *(const float4*)(xd + row*64 + 44);
        *(float4*)&Cv[0]  = *(const float4*)(xd + row*64 + 48);
        *(float4*)&Cv[4]  = *(const float4*)(xd + row*64 + 52);
        *(float4*)&Cv[8]  = *(const float4*)(xd + row*64 + 56);
        *(float4*)&Cv[12] = *(const float4*)(xd + row*64 + 60);
        int l = c*CH + t;
        int tz = rev ? (SEQ-1-l) : l;
        float zv = xz[((size_t)b*SEQ + tz)*2048 + DI + d];
        float y = 0.f;
        #pragma unroll
        for (int n=0;n<DS;++n) {
            float dA = expf(dv*An[n]);
            h[n] = fmaf(dA, h[n], du*Bv[n]);
            y = fmaf(h[n], Cv[n], y);
        }
        float val = (y + uv*Dd) * (zv * sigmoidf_(zv));
        if (accf) yg[row*DI + d] += val; else yg[row*DI + d] = val;
    }
}

// ---------------- layernorm over d=512 (optional residual + bf16 mirror) ----------------
__launch_bounds__(256)
__global__ void ln_kernel(const float* __restrict__ a, const float* __restrict__ res,
                          const float* __restrict__ g, const float* __restrict__ bta,
                          float* __restrict__ out, ushort_t* __restrict__ outb, float eps)
{
    size_t row = blockIdx.x;
    int t = threadIdx.x;
    const float* ap = a + row*DM;
    float v0 = ap[t], v1 = ap[t+256];
    if (res) { const float* rp = res + row*DM; v0 += rp[t]; v1 += rp[t+256]; }
    float s = v0+v1, q = v0*v0 + v1*v1;
    #pragma unroll
    for (int o=32;o>0;o>>=1){ s += __shfl_xor(s,o); q += __shfl_xor(q,o); }
    __shared__ float ss[4], sq[4];
    int w = t>>6;
    if ((t&63)==0){ ss[w]=s; sq[w]=q; }
    __syncthreads();
    s = ss[0]+ss[1]+ss[2]+ss[3];
    q = sq[0]+sq[1]+sq[2]+sq[3];
    float mean = s * (1.f/DM);
    float var  = q * (1.f/DM) - mean*mean;
    var = var < 0.f ? 0.f : var;
    float rstd = rsqrtf(var + eps);
    float o0 = (v0-mean)*rstd*g[t]     + bta[t];
    float o1 = (v1-mean)*rstd*g[t+256] + bta[t+256];
    if (out) { out[row*DM+t] = o0; out[row*DM+t+256] = o1; }
    if (outb){ outb[row*DM+t] = f2bf(o0); outb[row*DM+t+256] = f2bf(o1); }
}

__launch_bounds__(256)
__global__ void gate_ln_kernel(const float* __restrict__ ha, const float* __restrict__ hb,
                               const float* __restrict__ mo,
                               const float* __restrict__ g, const float* __restrict__ bta,
                               float* __restrict__ out, ushort_t* __restrict__ outb, float eps)
{
    size_t row = blockIdx.x;
    int t = threadIdx.x;
    size_t i0 = row*DM + t, i1 = i0 + 256;
    float a0 = ha[i0], a1 = ha[i1];
    float v0 = fmaf(a0, hb[i0], a0) + mo[i0];
    float v1 = fmaf(a1, hb[i1], a1) + mo[i1];
    float s = v0+v1, q = v0*v0 + v1*v1;
    #pragma unroll
    for (int o=32;o>0;o>>=1){ s += __shfl_xor(s,o); q += __shfl_xor(q,o); }
    __shared__ float ss[4], sq[4];
    int w = t>>6;
    if ((t&63)==0){ ss[w]=s; sq[w]=q; }
    __syncthreads();
    s = ss[0]+ss[1]+ss[2]+ss[3];
    q = sq[0]+sq[1]+sq[2]+sq[3];
    float mean = s * (1.f/DM);
    float var  = q * (1.f/DM) - mean*mean;
    var = var < 0.f ? 0.f : var;
    float rstd = rsqrtf(var + eps);
    float o0 = (v0-mean)*rstd*g[t]     + bta[t];
    float o1 = (v1-mean)*rstd*g[t+256] + bta[t+256];
    out[i0] = o0; out[i1] = o1;
    outb[row*DM+t] = f2bf(o0); outb[row*DM+t+256] = f2bf(o1);
}

// ================= host side =================
static void launch_bgemm(int epi, const ushort_t* A, int lda, const ushort_t* W,
                         const float* bias, const float* emul,
                         float* C, ushort_t* Cb, int ldc, int Ngrid, int K,
                         int Nvalid, int accf, hipStream_t s)
{
    dim3 g(Ngrid/128, BL/128);
    switch (epi) {
    case 0: bgemm<0><<<g,256,0,s>>>(A,lda,W,bias,emul,C,Cb,ldc,K,Nvalid,accf); break;
    case 2: bgemm<2><<<g,256,0,s>>>(A,lda,W,bias,emul,C,Cb,ldc,K,Nvalid,accf); break;
    case 3: bgemm<3><<<g,256,0,s>>>(A,lda,W,bias,emul,C,Cb,ldc,K,Nvalid,accf); break;
    case 4: bgemm<4><<<g,256,0,s>>>(A,lda,W,bias,emul,C,Cb,ldc,K,Nvalid,accf); break;
    }
}

static void cast4(const float* in, ushort_t* out, int n, hipStream_t s)
{
    cast4_kernel<<<(n/4 + 255)/256, 256, 0, s>>>(in, out, n/4);
}

extern "C" void kernel_launch(void* const* d_in, const int* in_sizes, int n_in,
                              void* d_out, int out_size, void* d_ws, size_t ws_size,
                              hipStream_t stream)
{
    const float* x        = (const float*)d_in[0];
    const float* fre      = (const float*)d_in[1];
    const float* fim      = (const float*)d_in[2];
    const float* cutoff   = (const float*)d_in[3];
    const float* ln0_g    = (const float*)d_in[4];
    const float* ln0_b    = (const float*)d_in[5];
    const float* l1_w     = (const float*)d_in[6];
    const float* l1_b     = (const float*)d_in[7];
    const float* l2_w     = (const float*)d_in[8];
    const float* l2_b     = (const float*)d_in[9];
    const float* in_w     = (const float*)d_in[10];
    const float* conv_w   = (const float*)d_in[11];
    const float* conv_b   = (const float*)d_in[12];
    const float* xproj_w  = (const float*)d_in[13];
    const float* dt_w     = (const float*)d_in[14];
    const float* dt_b     = (const float*)d_in[15];
    const float* A_log    = (const float*)d_in[16];
    const float* Dp       = (const float*)d_in[17];
    const float* out_w    = (const float*)d_in[18];
    const float* ln1_g    = (const float*)d_in[19];
    const float* ln1_b    = (const float*)d_in[20];
    const float* d1_w     = (const float*)d_in[21];
    const float* d1_b     = (const float*)d_in[22];
    const float* d2_w     = (const float*)d_in[23];
    const float* d2_b     = (const float*)d_in[24];
    const float* ln2_g    = (const float*)d_in[25];
    const float* ln2_b    = (const float*)d_in[26];
    const float* ffn_w1   = (const float*)d_in[27];
    const float* ffn_b1   = (const float*)d_in[28];
    const float* ffn_w2   = (const float*)d_in[29];
    const float* ffn_b2   = (const float*)d_in[30];
    const float* ffn_ln_g = (const float*)d_in[31];
    const float* ffn_ln_b = (const float*)d_in[32];

    float* ws = (float*)d_ws;
    // ---- fp32 regions ----
    float* RK = ws;                        // 1024 floats
    float* WF = RK + 1024;                 // weight bf16 pool: 2,555,904 floats of backing
    float* XN = WF + 2555904;              // BL*DM fp32 (hs; xn fp32 unused but written)
    float* XG = XN + (size_t)BL*DM;        // BL*DM fp32 (mo)
    float* T1 = XG + (size_t)BL*DM;        // BL*DM fp32 (l1-out/ha; HOUT+APR alias)
    float* T2 = T1 + (size_t)BL*DM;        // BL*DM fp32 (hb; HIN first half; XBx second half)
    float* XZ = T2 + (size_t)BL*DM;        // BL*2048 fp32 (xz; FHb bf16 aliases)
    float* XCF = XZ + (size_t)BL*2048;     // BL*DI/2 floats backing XCb (bf16)
    float* XD = XCF + (size_t)BL*DI/2;     // BL*64 fp32
    float* DL = XD + (size_t)BL*64;        // BL*DI fp32 (delta; YGb+MOb alias after)
    float* YG = DL + (size_t)BL*DI;        // BL*DI fp32 (branch-accumulated scan out; xi alias)
    float* MS = YG + (size_t)BL*DI;        // BL*DM fp32 (branch sum; XNb+XGb alias)
    // ---- bf16 weight pool (inside WF) ----
    ushort_t* MCb  = (ushort_t*)WF;        // 512*512
    ushort_t* L1b  = MCb  + 262144;        // 512*512
    ushort_t* L2b  = L1b  + 262144;
    ushort_t* INb  = L2b  + 262144;        // 2048*512
    ushort_t* OUTb = INb  + 1048576;       // 512*1024
    ushort_t* D1b  = OUTb + 524288;
    ushort_t* D2b  = D1b  + 262144;
    ushort_t* F1b  = D2b  + 262144;        // 2048*512
    ushort_t* F2b  = F1b  + 1048576;       // 512*2048
    ushort_t* XPb  = F2b  + 1048576;       // 128*1024 (padded xproj)
    // ---- bf16 activation mirrors (aliased into dead fp32 regions) ----
    const size_t SCNT = (size_t)BATCH*NC*DI*DS;       // 2,097,152 floats
    float*    HOUT = T1;                              // branches only
    float*    APR  = T1 + SCNT;
    float*    HIN  = T2;                              // first half of T2
    ushort_t* XBx  = (ushort_t*)(T2 + SCNT);          // bf16 x  (second half of T2)
    ushort_t* XCb  = (ushort_t*)XCF;                  // bf16 conv-out (u)
    ushort_t* FHb  = (ushort_t*)XZ;                   // bf16 ffn hidden (stage 6)
    ushort_t* YGb  = (ushort_t*)DL;                   // bf16 yg (after branches; DL dead)
    ushort_t* MOb  = (ushort_t*)(DL + (size_t)BL*DI/2); // bf16 mo
    ushort_t* XNb  = (ushort_t*)MS;                   // bf16 xn / hs (first half of MS)
    ushort_t* XGb  = (ushort_t*)(MS + (size_t)BL*DM/2); // bf16 xg (second half of MS)
    float* XI = YG;                                   // xi alias (consumed before br0 scan)
    float* OUT = (float*)d_out;

    // 0) weight conversions (once per launch)
    cast4(l1_w,  L1b,  512*512,  stream);
    cast4(l2_w,  L2b,  512*512,  stream);
    cast4(in_w,  INb,  2048*512, stream);
    cast4(out_w, OUTb, 512*1024, stream);
    cast4(d1_w,  D1b,  512*512,  stream);
    cast4(d2_w,  D2b,  512*512,  stream);
    cast4(ffn_w1,F1b,  2048*512, stream);
    cast4(ffn_w2,F2b,  512*2048, stream);
    cast_xproj_kernel<<<512,256,0,stream>>>(xproj_w, XPb);
    cast4(x, XBx, BL*DM, stream);

    // 1) frequency filter as circulant bf16 GEMM, then LN(xi + x)
    build_filter_kernel<<<512,256,0,stream>>>(fre, fim, cutoff, RK);
    circ_expand_kernel<<<512,512,0,stream>>>(RK, MCb);
    launch_bgemm(0, XBx,DM, MCb, nullptr, nullptr, XI,nullptr, DM, DM, DM, DM, 0, stream);
    ln_kernel<<<BL,256,0,stream>>>(XI, x, ln0_g, ln0_b, XN, XNb, 1e-5f);

    // 2) xg = (xn@l1^T+b1) * silu(xn@l2^T+b2)  -> bf16-only XGb
    launch_bgemm(0, XNb,DM, L1b, l1_b, nullptr, T1,nullptr, DM, DM, DM, DM, 0, stream);
    launch_bgemm(4, XNb,DM, L2b, l2_b, T1, nullptr,XGb, DM, DM, DM, DM, 0, stream);

    // 3) three mamba branches; yg accumulated fp32 in YG
    launch_bgemm(0, XGb,DM, INb, nullptr, nullptr, XZ,nullptr, 2048, 2048, DM, 2048, 0, stream);
    for (int br = 0; br < 3; ++br) {
        if (br == 2)
            launch_bgemm(0, XBx,DM, INb, nullptr, nullptr, XZ,nullptr, 2048, 2048, DM, 2048, 0, stream);
        int rev = (br == 1) ? 1 : 0;
        conv_silu_kernel<<<(BL*DI)/256,256,0,stream>>>(XZ, conv_w, conv_b, XCb, rev);
        // xproj: N=64 via 128-padded weight, epilogue masked to 64
        launch_bgemm(0, XCb,DI, XPb, nullptr, nullptr, XD,nullptr, 64, 128, DI, 64, 0, stream);
        gemm_sp_kernel<<<dim3(DI/BNT, BL/BMT),256,0,stream>>>(XD,64, dt_w, dt_b, DL,DI, DR);
        {
            dim3 ga(DI/256, NC, BATCH);
            scan_ph_a<<<ga,256,0,stream>>>(DL, XCb, XD, A_log, HOUT, APR);
            scan_ph_b<<<(BATCH*DI*DS)/256,256,0,stream>>>(HOUT, APR, HIN);
            scan_ph_c<<<ga,256,0,stream>>>(DL, XCb, XD, XZ, A_log, Dp, HIN, YG, rev, (br==0)?0:1);
        }
    }
    // cast accumulated yg -> bf16 (DL dead), single out_proj
    cast4(YG, YGb, BL*DI, stream);
    launch_bgemm(0, YGb,DI, OUTb, nullptr, nullptr, MS,nullptr, DM, DM, DI, DM, 0, stream);

    // 4) mo = LN(m1+m2+m3)
    ln_kernel<<<BL,256,0,stream>>>(MS, nullptr, ln1_g, ln1_b, XG, MOb, 1e-12f);

    // 5) ha/hb gate + LN -> hs
    launch_bgemm(3, MOb,DM, D1b, d1_b, nullptr, T2,nullptr, DM, DM, DM, DM, 0, stream);  // hb
    launch_bgemm(0, MOb,DM, D2b, d2_b, nullptr, T1,nullptr, DM, DM, DM, DM, 0, stream);  // ha
    gate_ln_kernel<<<BL,256,0,stream>>>(T1, T2, XG, ln2_g, ln2_b, XN, XNb, 1e-12f);

    // 6) FFN: gelu(hs@w1^T+b1) -> bf16 hidden; @w2^T + b2 ; out = LN(h + hs)
    launch_bgemm(2, XNb,DM, F1b, ffn_b1, nullptr, nullptr,FHb, 2048, 2048, DM, 2048, 0, stream);
    launch_bgemm(0, FHb,2048, F2b, ffn_b2, nullptr, T1,nullptr, DM, DM, 2048, DM, 0, stream);
    ln_kernel<<<BL,256,0,stream>>>(T1, XN, ffn_ln_g, ffn_ln_b, OUT, nullptr, 1e-12f);
}

// Round 7
// 1129.550 us; speedup vs baseline: 9.8306x; 1.2208x over previous
//
#include <hip/hip_runtime.h>
#include <math.h>

#define BATCH 4
#define SEQ   2048
#define DM    512
#define DI    1024
#define DS    16
#define DR    32
#define BL    (BATCH*SEQ)   // 8192 tokens

#define CH 64               // scan chunk length
#define NC (SEQ/CH)         // 32 chunks per sequence

#define BMT 64
#define BNT 64
#define BKT 16

typedef __attribute__((ext_vector_type(8))) short short8_t;   // 8 bf16 = 4 VGPRs
typedef __attribute__((ext_vector_type(4))) float f32x4_t;    // MFMA acc
typedef unsigned short ushort_t;

// fast sigmoid: v_exp_f32 + v_rcp_f32 (1-2 ulp; fine vs bf16-level tolerance)
__device__ __forceinline__ float sigmoidf_(float x){
    return __builtin_amdgcn_rcpf(1.f + __expf(-x));
}

// fp32 -> bf16 bits (RNE)
__device__ __forceinline__ ushort_t f2bf(float f){
    unsigned int u = __float_as_uint(f);
    unsigned int r = (u + 0x7fffu + ((u >> 16) & 1u)) >> 16;
    return (ushort_t)r;
}
__device__ __forceinline__ float bf2f(ushort_t b){
    return __uint_as_float(((unsigned int)b) << 16);
}

// async global->LDS, 16 B per lane; LDS dest = wave-uniform base + lane*16
__device__ __forceinline__ void gload16(const ushort_t* g, ushort_t* lds){
    __builtin_amdgcn_global_load_lds(
        (const __attribute__((address_space(1))) unsigned int*)g,
        (__attribute__((address_space(3))) unsigned int*)lds, 16, 0, 0);
}

// ---------------- FFT filter as circulant kernel (parallel) ----------------
__global__ void build_filter_kernel(const float* __restrict__ fre,
                                    const float* __restrict__ fim,
                                    const float* __restrict__ cut,
                                    float* __restrict__ rker)
{
    int j = blockIdx.x;
    int t = threadIdx.x;
    float c0 = cut[0];
    double acc = 0.0;
    for (int k = t; k < 512; k += 256) {
        float fr = (float)(k < 256 ? k : k - 512) / 512.0f;
        float mask = (fr >= c0 || fr <= -c0) ? 1.f : 0.f;
        double gre = (double)mask + (double)fre[k];
        double gim = (double)fim[k];
        int pr = (j * k) & 511;  // exact angle reduction
        double ang = 6.283185307179586476925286766559 * (double)pr / 512.0;
        acc += gre * cos(ang) - gim * sin(ang);
    }
    #pragma unroll
    for (int o = 32; o > 0; o >>= 1) acc += __shfl_xor(acc, o);
    __shared__ double sd[4];
    int w = t >> 6;
    if ((t & 63) == 0) sd[w] = acc;
    __syncthreads();
    if (t == 0) rker[j] = (float)((sd[0] + sd[1] + sd[2] + sd[3]) / 512.0);
}

// circulant weight, directly bf16: Mc[n][m] = r[(n-m) mod 512]
__global__ void circ_expand_kernel(const float* __restrict__ rker, ushort_t* __restrict__ Mc)
{
    int n = blockIdx.x, m = threadIdx.x;
    Mc[n*512 + m] = f2bf(rker[(n - m) & 511]);
}

// fp32 -> bf16 cast, 4 elems/thread
__global__ void cast4_kernel(const float* __restrict__ in, ushort_t* __restrict__ out, int n4)
{
    int i = blockIdx.x*256 + threadIdx.x;
    if (i < n4) {
        float4 v = ((const float4*)in)[i];
        ushort_t o0 = f2bf(v.x), o1 = f2bf(v.y), o2 = f2bf(v.z), o3 = f2bf(v.w);
        unsigned int lo = (unsigned int)o0 | ((unsigned int)o1 << 16);
        unsigned int hi = (unsigned int)o2 | ((unsigned int)o3 << 16);
        ((uint2*)out)[i] = make_uint2(lo, hi);
    }
}

// xproj weight: 64x1024 fp32 -> 128x1024 bf16 with zero-padded rows 64..127
__global__ void cast_xproj_kernel(const float* __restrict__ in, ushort_t* __restrict__ out)
{
    int i = blockIdx.x*256 + threadIdx.x;  // 131072 total
    int r = i >> 10;
    out[i] = (r < 64) ? f2bf(in[i]) : (ushort_t)0;
}

// reduce 4 split-K partials: XD = sum_z XDP[z]
__global__ void reduce_xd_kernel(const float* __restrict__ xdp, float* __restrict__ xd)
{
    int i = blockIdx.x*256 + threadIdx.x;   // BL*64 total
    const size_t S = (size_t)BL*64;
    xd[i] = xdp[i] + xdp[i+S] + xdp[i+2*S] + xdp[i+3*S];
}

// ---------------- fp32 tiled GEMM (dt only): C = softplus(A @ W^T + bias) ----------------
__launch_bounds__(256)
__global__ void gemm_sp_kernel(const float* __restrict__ A, int lda,
                               const float* __restrict__ W,
                               const float* __restrict__ bias,
                               float* __restrict__ C, int ldc, int K)
{
    __shared__ float As[BKT][BMT];
    __shared__ float Ws[BKT][BNT];
    int t  = threadIdx.x;
    int lr = t >> 2;
    int lc = (t & 3) << 2;
    const float* Ag = A + (size_t)(blockIdx.y*BMT + lr)*lda + lc;
    const float* Wg = W + (size_t)(blockIdx.x*BNT + lr)*K   + lc;
    int tm = (t & 15) << 2;
    int tn = (t >> 4) << 2;
    float acc[4][4] = {};
    for (int kt = 0; kt < K; kt += BKT) {
        float4 av = *(const float4*)(Ag + kt);
        float4 wv = *(const float4*)(Wg + kt);
        __syncthreads();
        As[lc+0][lr]=av.x; As[lc+1][lr]=av.y; As[lc+2][lr]=av.z; As[lc+3][lr]=av.w;
        Ws[lc+0][lr]=wv.x; Ws[lc+1][lr]=wv.y; Ws[lc+2][lr]=wv.z; Ws[lc+3][lr]=wv.w;
        __syncthreads();
        #pragma unroll
        for (int k = 0; k < BKT; ++k) {
            const float4 a4 = *(const float4*)&As[k][tm];
            const float4 w4 = *(const float4*)&Ws[k][tn];
            float ar[4] = {a4.x,a4.y,a4.z,a4.w};
            float wr[4] = {w4.x,w4.y,w4.z,w4.w};
            #pragma unroll
            for (int i=0;i<4;++i)
                #pragma unroll
                for (int j=0;j<4;++j)
                    acc[i][j] = fmaf(ar[i], wr[j], acc[i][j]);
        }
    }
    size_t crow = (size_t)(blockIdx.y*BMT + tm);
    int ccol = blockIdx.x*BNT + tn;
    #pragma unroll
    for (int i=0;i<4;++i) {
        float* Cp = C + (crow+i)*ldc + ccol;
        #pragma unroll
        for (int j=0;j<4;++j) {
            float v = acc[i][j] + bias[ccol+j];
            Cp[j] = (v > 20.f) ? v : __logf(1.f + __expf(v));
        }
    }
}

// ---------------- bf16-native MFMA GEMM (m97 structure) ----------------
// C[m][n] = epi( sum_k A[m][k]*W[n][k] + bias[n] )
// 128x128 tile, BK=32, 4 waves 2x2, each wave 64x64 via 4x4 frags 16x16x32.
// Split-K via blockIdx.z: K-range [z*Ksub, (z+1)*Ksub), C offset z*zstride.
// EPI: 0 none, 2 gelu, 3 silu, 4 emul*silu.  C and Cb (bf16 mirror) nullable.
template<int EPI>
__launch_bounds__(256)
__global__ void bgemm(const ushort_t* __restrict__ A, int lda,
                      const ushort_t* __restrict__ W,
                      const float* __restrict__ bias,
                      const float* __restrict__ emul,
                      float* __restrict__ C,
                      ushort_t* __restrict__ Cb,
                      int ldc, int Ksub, int Nvalid, int accflag, size_t zstride)
{
    __shared__ __align__(16) ushort_t As[128*32];
    __shared__ __align__(16) ushort_t Bs[128*32];
    int t = threadIdx.x;
    int lane = t & 63;
    int w  = t >> 6;
    int wr = w >> 1, wc = w & 1;
    int l15 = lane & 15, quad = lane >> 4;
    const int tileM = blockIdx.y * 128;
    const int tileN = blockIdx.x * 128;
    const int kbeg = blockIdx.z * Ksub;
    const int kend = kbeg + Ksub;

    int srow = w*32 + (lane >> 2);
    int scol = (lane & 3) * 8;
    const ushort_t* gA0 = A + (size_t)(tileM + srow)*lda + scol;
    const ushort_t* gA1 = gA0 + (size_t)16*lda;
    const ushort_t* gW0 = W + (size_t)(tileN + srow)*Ksub*gridDim.z + scol;
    const ushort_t* gW1 = gW0 + (size_t)16*Ksub*gridDim.z;
    ushort_t* ldsA = As + w*1024;   // wave-uniform
    ushort_t* ldsB = Bs + w*1024;

    f32x4_t acc[4][4];
    #pragma unroll
    for (int i=0;i<4;++i)
        #pragma unroll
        for (int j=0;j<4;++j)
            acc[i][j] = (f32x4_t){0.f,0.f,0.f,0.f};

    for (int kt = kbeg; kt < kend; kt += 32) {
        __syncthreads();   // previous iter's ds_reads done before overwrite
        gload16(gA0 + kt, ldsA);
        gload16(gA1 + kt, ldsA + 512);
        gload16(gW0 + kt, ldsB);
        gload16(gW1 + kt, ldsB + 512);
        __syncthreads();   // compiler drains vmcnt(0) -> staged data visible
        short8_t af[4], bfv[4];
        #pragma unroll
        for (int mi=0;mi<4;++mi)
            af[mi] = *(const short8_t*)&As[(wr*64 + mi*16 + l15)*32 + quad*8];
        #pragma unroll
        for (int ni=0;ni<4;++ni)
            bfv[ni] = *(const short8_t*)&Bs[(wc*64 + ni*16 + l15)*32 + quad*8];
        #pragma unroll
        for (int mi=0;mi<4;++mi)
            #pragma unroll
            for (int ni=0;ni<4;++ni)
                acc[mi][ni] = __builtin_amdgcn_mfma_f32_16x16x32_bf16(af[mi], bfv[ni], acc[mi][ni], 0, 0, 0);
    }

    // epilogue: C/D layout col=lane&15, row=quad*4+reg
    size_t cbase = zstride * blockIdx.z;
    #pragma unroll
    for (int mi=0;mi<4;++mi) {
        #pragma unroll
        for (int ni=0;ni<4;++ni) {
            int gm0 = tileM + wr*64 + mi*16 + quad*4;
            int gn  = tileN + wc*64 + ni*16 + l15;
            if (gn >= Nvalid) continue;
            float bv = bias ? bias[gn] : 0.f;
            #pragma unroll
            for (int r=0;r<4;++r) {
                size_t off = cbase + (size_t)(gm0 + r)*ldc + gn;
                float v = acc[mi][ni][r] + bv;
                if (EPI==2) v = 0.5f*v*(1.f+erff(v*0.70710678118654752440f));
                else if (EPI==3) v = v*sigmoidf_(v);
                else if (EPI==4) v = emul[off] * (v*sigmoidf_(v));
                if (C) { if (accflag) C[off] += v; else C[off] = v; }
                if (Cb) Cb[off] = f2bf(v);
            }
        }
    }
}

// ---------------- depthwise causal conv (k=4) + silu -> bf16 ----------------
__launch_bounds__(256)
__global__ void conv_silu_kernel(const float* __restrict__ xz,
                                 const float* __restrict__ cw,
                                 const float* __restrict__ cb,
                                 ushort_t* __restrict__ xcb, int rev)
{
    size_t idx = (size_t)blockIdx.x*256 + threadIdx.x;
    int c = (int)(idx & (DI-1));
    size_t bl = idx >> 10;
    int l = (int)(bl & (SEQ-1));
    int b = (int)(bl >> 11);
    float accv = cb[c];
    #pragma unroll
    for (int k = 0; k < 4; ++k) {
        int ts = l + k - 3;
        if (ts >= 0) {
            int tin = rev ? (SEQ-1-ts) : ts;
            accv = fmaf(cw[c*4+k], xz[((size_t)b*SEQ + tin)*2048 + c], accv);
        }
    }
    xcb[idx] = f2bf(accv * sigmoidf_(accv));
}

// ================= chunked parallel selective scan =================
// xd rows shared by the whole block -> staged in LDS (broadcast reads).
__launch_bounds__(256)
__global__ void scan_ph_a(const float* __restrict__ dl,
                          const ushort_t* __restrict__ xcb,
                          const float* __restrict__ xd,
                          const float* __restrict__ A_log,
                          float* __restrict__ hout,
                          float* __restrict__ aprod)
{
    __shared__ float sxd[CH*64];   // 16 KB: this chunk's x_dbl rows
    int d = blockIdx.x*256 + threadIdx.x;
    int c = blockIdx.y;
    int b = blockIdx.z;
    size_t row0 = (size_t)b*SEQ + (size_t)c*CH;
    {
        const float4* src = (const float4*)(xd + row0*64);
        float4* dst = (float4*)sxd;
        #pragma unroll
        for (int i = threadIdx.x; i < CH*16; i += 256) dst[i] = src[i];
    }
    float An[DS];
    #pragma unroll
    for (int n=0;n<DS;++n) An[n] = -__expf(A_log[d*DS+n]);
    float h[DS], P[DS];
    #pragma unroll
    for (int n=0;n<DS;++n) { h[n]=0.f; P[n]=1.f; }
    __syncthreads();
    for (int t=0;t<CH;++t) {
        size_t row = row0 + t;
        float dv = dl[row*DI + d];
        float uv = bf2f(xcb[row*DI + d]);
        float du = dv*uv;
        const float* Bv = &sxd[t*64 + 32];
        #pragma unroll
        for (int n=0;n<DS;++n) {
            float dA = __expf(dv*An[n]);
            h[n] = fmaf(dA, h[n], du*Bv[n]);
            P[n] *= dA;
        }
    }
    size_t o = (((size_t)b*NC + c)*DI + d)*DS;
    #pragma unroll
    for (int q=0;q<4;++q) {
        *(float4*)(hout  + o + 4*q) = make_float4(h[4*q],h[4*q+1],h[4*q+2],h[4*q+3]);
        *(float4*)(aprod + o + 4*q) = make_float4(P[4*q],P[4*q+1],P[4*q+2],P[4*q+3]);
    }
}

__launch_bounds__(256)
__global__ void scan_ph_b(const float* __restrict__ hout,
                          const float* __restrict__ aprod,
                          float* __restrict__ hin)
{
    int idx = blockIdx.x*256 + threadIdx.x;
    int b  = idx >> 14;
    int dn = idx & (DI*DS - 1);
    float hc = 0.f;
    for (int c=0;c<NC;++c) {
        size_t o = ((size_t)b*NC + c)*(DI*DS) + dn;
        hin[o] = hc;
        hc = fmaf(aprod[o], hc, hout[o]);
    }
}

__launch_bounds__(256)
__global__ void scan_ph_c(const float* __restrict__ dl,
                          const ushort_t* __restrict__ xcb,
                          const float* __restrict__ xd,
                          const float* __restrict__ xz,
                          const float* __restrict__ A_log,
                          const float* __restrict__ Dp,
                          const float* __restrict__ hin,
                          float* __restrict__ yg, int rev, int accf)
{
    __shared__ float sxd[CH*64];
    int d = blockIdx.x*256 + threadIdx.x;
    int c = blockIdx.y;
    int b = blockIdx.z;
    size_t row0 = (size_t)b*SEQ + (size_t)c*CH;
    {
        const float4* src = (const float4*)(xd + row0*64);
        float4* dst = (float4*)sxd;
        #pragma unroll
        for (int i = threadIdx.x; i < CH*16; i += 256) dst[i] = src[i];
    }
    float An[DS];
    #pragma unroll
    for (int n=0;n<DS;++n) An[n] = -__expf(A_log[d*DS+n]);
    float h[DS];
    size_t o = (((size_t)b*NC + c)*DI + d)*DS;
    #pragma unroll
    for (int q=0;q<4;++q) {
        float4 hv = *(const float4*)(hin + o + 4*q);
        h[4*q]=hv.x; h[4*q+1]=hv.y; h[4*q+2]=hv.z; h[4*q+3]=hv.w;
    }
    float Dd = Dp[d];
    __syncthreads();
    for (int t=0;t<CH;++t) {
        size_t row = row0 + t;
        float dv = dl[row*DI + d];
        float uv = bf2f(xcb[row*DI + d]);
        float du = dv*uv;
        const float* Bv = &sxd[t*64 + 32];
        const float* Cv = &sxd[t*64 + 48];
        int l = c*CH + t;
        int tz = rev ? (SEQ-1-l) : l;
        float zv = xz[((size_t)b*SEQ + tz)*2048 + DI + d];
        float y = 0.f;
        #pragma unroll
        for (int n=0;n<DS;++n) {
            float dA = __expf(dv*An[n]);
            h[n] = fmaf(dA, h[n], du*Bv[n]);
            y = fmaf(h[n], Cv[n], y);
        }
        float val = (y + uv*Dd) * (zv * sigmoidf_(zv));
        if (accf) yg[row*DI + d] += val; else yg[row*DI + d] = val;
    }
}

// ---------------- layernorm over d=512 (optional residual + bf16 mirror) ----------------
__launch_bounds__(256)
__global__ void ln_kernel(const float* __restrict__ a, const float* __restrict__ res,
                          const float* __restrict__ g, const float* __restrict__ bta,
                          float* __restrict__ out, ushort_t* __restrict__ outb, float eps)
{
    size_t row = blockIdx.x;
    int t = threadIdx.x;
    const float* ap = a + row*DM;
    float v0 = ap[t], v1 = ap[t+256];
    if (res) { const float* rp = res + row*DM; v0 += rp[t]; v1 += rp[t+256]; }
    float s = v0+v1, q = v0*v0 + v1*v1;
    #pragma unroll
    for (int o=32;o>0;o>>=1){ s += __shfl_xor(s,o); q += __shfl_xor(q,o); }
    __shared__ float ss[4], sq[4];
    int w = t>>6;
    if ((t&63)==0){ ss[w]=s; sq[w]=q; }
    __syncthreads();
    s = ss[0]+ss[1]+ss[2]+ss[3];
    q = sq[0]+sq[1]+sq[2]+sq[3];
    float mean = s * (1.f/DM);
    float var  = q * (1.f/DM) - mean*mean;
    var = var < 0.f ? 0.f : var;
    float rstd = rsqrtf(var + eps);
    float o0 = (v0-mean)*rstd*g[t]     + bta[t];
    float o1 = (v1-mean)*rstd*g[t+256] + bta[t+256];
    if (out) { out[row*DM+t] = o0; out[row*DM+t+256] = o1; }
    if (outb){ outb[row*DM+t] = f2bf(o0); outb[row*DM+t+256] = f2bf(o1); }
}

__launch_bounds__(256)
__global__ void gate_ln_kernel(const float* __restrict__ ha, const float* __restrict__ hb,
                               const float* __restrict__ mo,
                               const float* __restrict__ g, const float* __restrict__ bta,
                               float* __restrict__ out, ushort_t* __restrict__ outb, float eps)
{
    size_t row = blockIdx.x;
    int t = threadIdx.x;
    size_t i0 = row*DM + t, i1 = i0 + 256;
    float a0 = ha[i0], a1 = ha[i1];
    float v0 = fmaf(a0, hb[i0], a0) + mo[i0];
    float v1 = fmaf(a1, hb[i1], a1) + mo[i1];
    float s = v0+v1, q = v0*v0 + v1*v1;
    #pragma unroll
    for (int o=32;o>0;o>>=1){ s += __shfl_xor(s,o); q += __shfl_xor(q,o); }
    __shared__ float ss[4], sq[4];
    int w = t>>6;
    if ((t&63)==0){ ss[w]=s; sq[w]=q; }
    __syncthreads();
    s = ss[0]+ss[1]+ss[2]+ss[3];
    q = sq[0]+sq[1]+sq[2]+sq[3];
    float mean = s * (1.f/DM);
    float var  = q * (1.f/DM) - mean*mean;
    var = var < 0.f ? 0.f : var;
    float rstd = rsqrtf(var + eps);
    float o0 = (v0-mean)*rstd*g[t]     + bta[t];
    float o1 = (v1-mean)*rstd*g[t+256] + bta[t+256];
    out[i0] = o0; out[i1] = o1;
    outb[row*DM+t] = f2bf(o0); outb[row*DM+t+256] = f2bf(o1);
}

// ================= host side =================
static void launch_bgemm(int epi, const ushort_t* A, int lda, const ushort_t* W,
                         const float* bias, const float* emul,
                         float* C, ushort_t* Cb, int ldc, int Ngrid, int K,
                         int Nvalid, int accf, hipStream_t s)
{
    dim3 g(Ngrid/128, BL/128, 1);
    switch (epi) {
    case 0: bgemm<0><<<g,256,0,s>>>(A,lda,W,bias,emul,C,Cb,ldc,K,Nvalid,accf,0); break;
    case 2: bgemm<2><<<g,256,0,s>>>(A,lda,W,bias,emul,C,Cb,ldc,K,Nvalid,accf,0); break;
    case 3: bgemm<3><<<g,256,0,s>>>(A,lda,W,bias,emul,C,Cb,ldc,K,Nvalid,accf,0); break;
    case 4: bgemm<4><<<g,256,0,s>>>(A,lda,W,bias,emul,C,Cb,ldc,K,Nvalid,accf,0); break;
    }
}

static void cast4(const float* in, ushort_t* out, int n, hipStream_t s)
{
    cast4_kernel<<<(n/4 + 255)/256, 256, 0, s>>>(in, out, n/4);
}

extern "C" void kernel_launch(void* const* d_in, const int* in_sizes, int n_in,
                              void* d_out, int out_size, void* d_ws, size_t ws_size,
                              hipStream_t stream)
{
    const float* x        = (const float*)d_in[0];
    const float* fre      = (const float*)d_in[1];
    const float* fim      = (const float*)d_in[2];
    const float* cutoff   = (const float*)d_in[3];
    const float* ln0_g    = (const float*)d_in[4];
    const float* ln0_b    = (const float*)d_in[5];
    const float* l1_w     = (const float*)d_in[6];
    const float* l1_b     = (const float*)d_in[7];
    const float* l2_w     = (const float*)d_in[8];
    const float* l2_b     = (const float*)d_in[9];
    const float* in_w     = (const float*)d_in[10];
    const float* conv_w   = (const float*)d_in[11];
    const float* conv_b   = (const float*)d_in[12];
    const float* xproj_w  = (const float*)d_in[13];
    const float* dt_w     = (const float*)d_in[14];
    const float* dt_b     = (const float*)d_in[15];
    const float* A_log    = (const float*)d_in[16];
    const float* Dp       = (const float*)d_in[17];
    const float* out_w    = (const float*)d_in[18];
    const float* ln1_g    = (const float*)d_in[19];
    const float* ln1_b    = (const float*)d_in[20];
    const float* d1_w     = (const float*)d_in[21];
    const float* d1_b     = (const float*)d_in[22];
    const float* d2_w     = (const float*)d_in[23];
    const float* d2_b     = (const float*)d_in[24];
    const float* ln2_g    = (const float*)d_in[25];
    const float* ln2_b    = (const float*)d_in[26];
    const float* ffn_w1   = (const float*)d_in[27];
    const float* ffn_b1   = (const float*)d_in[28];
    const float* ffn_w2   = (const float*)d_in[29];
    const float* ffn_b2   = (const float*)d_in[30];
    const float* ffn_ln_g = (const float*)d_in[31];
    const float* ffn_ln_b = (const float*)d_in[32];

    float* ws = (float*)d_ws;
    // ---- fp32 regions ----
    float* RK = ws;                        // 1024 floats
    float* WF = RK + 1024;                 // weight bf16 pool backing
    float* XN = WF + 2555904;              // BL*DM fp32 (xn fp32 dead in branch loop -> XDP alias)
    float* XG = XN + (size_t)BL*DM;        // BL*DM fp32 (mo)
    float* T1 = XG + (size_t)BL*DM;        // BL*DM fp32 (l1-out/ha; HOUT+APR alias)
    float* T2 = T1 + (size_t)BL*DM;        // BL*DM fp32 (hb; HIN first half; XBx second half)
    float* XZ = T2 + (size_t)BL*DM;        // BL*2048 fp32 (xz; FHb bf16 aliases)
    float* XCF = XZ + (size_t)BL*2048;     // BL*DI/2 floats backing XCb (bf16)
    float* XD = XCF + (size_t)BL*DI/2;     // BL*64 fp32
    float* DL = XD + (size_t)BL*64;        // BL*DI fp32 (delta; YGb+MOb alias after)
    float* YG = DL + (size_t)BL*DI;        // BL*DI fp32 (branch-accumulated scan out; xi alias)
    float* MS = YG + (size_t)BL*DI;        // BL*DM fp32 (branch sum; XNb+XGb alias)
    // ---- bf16 weight pool (inside WF) ----
    ushort_t* MCb  = (ushort_t*)WF;        // 512*512
    ushort_t* L1b  = MCb  + 262144;        // 512*512
    ushort_t* L2b  = L1b  + 262144;
    ushort_t* INb  = L2b  + 262144;        // 2048*512
    ushort_t* OUTb = INb  + 1048576;       // 512*1024
    ushort_t* D1b  = OUTb + 524288;
    ushort_t* D2b  = D1b  + 262144;
    ushort_t* F1b  = D2b  + 262144;        // 2048*512
    ushort_t* F2b  = F1b  + 1048576;       // 512*2048
    ushort_t* XPb  = F2b  + 1048576;       // 128*1024 (padded xproj)
    // ---- bf16 activation mirrors / scan state (aliased into dead fp32 regions) ----
    const size_t SCNT = (size_t)BATCH*NC*DI*DS;       // 2,097,152 floats
    float*    HOUT = T1;
    float*    APR  = T1 + SCNT;
    float*    HIN  = T2;
    ushort_t* XBx  = (ushort_t*)(T2 + SCNT);          // bf16 x
    ushort_t* XCb  = (ushort_t*)XCF;                  // bf16 conv-out (u)
    ushort_t* FHb  = (ushort_t*)XZ;                   // bf16 ffn hidden (stage 6)
    ushort_t* YGb  = (ushort_t*)DL;                   // bf16 yg (after branches)
    ushort_t* MOb  = (ushort_t*)(DL + (size_t)BL*DI/2); // bf16 mo
    ushort_t* XNb  = (ushort_t*)MS;                   // bf16 xn / hs
    ushort_t* XGb  = (ushort_t*)(MS + (size_t)BL*DM/2); // bf16 xg
    float*    XDP  = XN;                              // split-K partials: 4*BL*64 = 2M floats
    float* XI = YG;                                   // xi alias
    float* OUT = (float*)d_out;

    // 0) weight conversions (once per launch)
    cast4(l1_w,  L1b,  512*512,  stream);
    cast4(l2_w,  L2b,  512*512,  stream);
    cast4(in_w,  INb,  2048*512, stream);
    cast4(out_w, OUTb, 512*1024, stream);
    cast4(d1_w,  D1b,  512*512,  stream);
    cast4(d2_w,  D2b,  512*512,  stream);
    cast4(ffn_w1,F1b,  2048*512, stream);
    cast4(ffn_w2,F2b,  512*2048, stream);
    cast_xproj_kernel<<<512,256,0,stream>>>(xproj_w, XPb);
    cast4(x, XBx, BL*DM, stream);

    // 1) frequency filter as circulant bf16 GEMM, then LN(xi + x)
    build_filter_kernel<<<512,256,0,stream>>>(fre, fim, cutoff, RK);
    circ_expand_kernel<<<512,512,0,stream>>>(RK, MCb);
    launch_bgemm(0, XBx,DM, MCb, nullptr, nullptr, XI,nullptr, DM, DM, DM, DM, 0, stream);
    ln_kernel<<<BL,256,0,stream>>>(XI, x, ln0_g, ln0_b, XN, XNb, 1e-5f);

    // 2) xg = (xn@l1^T+b1) * silu(xn@l2^T+b2)  -> bf16-only XGb
    launch_bgemm(0, XNb,DM, L1b, l1_b, nullptr, T1,nullptr, DM, DM, DM, DM, 0, stream);
    launch_bgemm(4, XNb,DM, L2b, l2_b, T1, nullptr,XGb, DM, DM, DM, DM, 0, stream);

    // 3) three mamba branches; yg accumulated fp32 in YG
    launch_bgemm(0, XGb,DM, INb, nullptr, nullptr, XZ,nullptr, 2048, 2048, DM, 2048, 0, stream);
    for (int br = 0; br < 3; ++br) {
        if (br == 2)
            launch_bgemm(0, XBx,DM, INb, nullptr, nullptr, XZ,nullptr, 2048, 2048, DM, 2048, 0, stream);
        int rev = (br == 1) ? 1 : 0;
        conv_silu_kernel<<<(BL*DI)/256,256,0,stream>>>(XZ, conv_w, conv_b, XCb, rev);
        // xproj: split-K x4 into XDP (aliases dead XN), then reduce -> XD
        bgemm<0><<<dim3(1, BL/128, 4),256,0,stream>>>(XCb,DI, XPb, nullptr, nullptr,
                                                      XDP,nullptr, 64, DI/4, 64, 0, (size_t)BL*64);
        reduce_xd_kernel<<<(BL*64)/256,256,0,stream>>>(XDP, XD);
        gemm_sp_kernel<<<dim3(DI/BNT, BL/BMT),256,0,stream>>>(XD,64, dt_w, dt_b, DL,DI, DR);
        {
            dim3 ga(DI/256, NC, BATCH);
            scan_ph_a<<<ga,256,0,stream>>>(DL, XCb, XD, A_log, HOUT, APR);
            scan_ph_b<<<(BATCH*DI*DS)/256,256,0,stream>>>(HOUT, APR, HIN);
            scan_ph_c<<<ga,256,0,stream>>>(DL, XCb, XD, XZ, A_log, Dp, HIN, YG, rev, (br==0)?0:1);
        }
    }
    // cast accumulated yg -> bf16 (DL dead), single out_proj
    cast4(YG, YGb, BL*DI, stream);
    launch_bgemm(0, YGb,DI, OUTb, nullptr, nullptr, MS,nullptr, DM, DM, DI, DM, 0, stream);

    // 4) mo = LN(m1+m2+m3)
    ln_kernel<<<BL,256,0,stream>>>(MS, nullptr, ln1_g, ln1_b, XG, MOb, 1e-12f);

    // 5) ha/hb gate + LN -> hs
    launch_bgemm(3, MOb,DM, D1b, d1_b, nullptr, T2,nullptr, DM, DM, DM, DM, 0, stream);  // hb
    launch_bgemm(0, MOb,DM, D2b, d2_b, nullptr, T1,nullptr, DM, DM, DM, DM, 0, stream);  // ha
    gate_ln_kernel<<<BL,256,0,stream>>>(T1, T2, XG, ln2_g, ln2_b, XN, XNb, 1e-12f);

    // 6) FFN: gelu(hs@w1^T+b1) -> bf16 hidden; @w2^T + b2 ; out = LN(h + hs)
    launch_bgemm(2, XNb,DM, F1b, ffn_b1, nullptr, nullptr,FHb, 2048, 2048, DM, 2048, 0, stream);
    launch_bgemm(0, FHb,2048, F2b, ffn_b2, nullptr, T1,nullptr, DM, DM, 2048, DM, 0, stream);
    ln_kernel<<<BL,256,0,stream>>>(T1, XN, ffn_ln_g, ffn_ln_b, OUT, nullptr, 1e-12f);
}

// Round 8
// 947.282 us; speedup vs baseline: 11.7221x; 1.1924x over previous
//
#include <hip/hip_runtime.h>
#include <math.h>

#define BATCH 4
#define SEQ   2048
#define DM    512
#define DI    1024
#define DS    16
#define DR    32
#define BL    (BATCH*SEQ)   // 8192 tokens

#define CH 128              // scan chunk length
#define NC (SEQ/CH)         // 16 chunks per sequence

typedef __attribute__((ext_vector_type(8))) short short8_t;   // 8 bf16 = 4 VGPRs
typedef __attribute__((ext_vector_type(4))) float f32x4_t;    // MFMA acc
typedef unsigned short ushort_t;

// fast sigmoid: v_exp_f32 + v_rcp_f32
__device__ __forceinline__ float sigmoidf_(float x){
    return __builtin_amdgcn_rcpf(1.f + __expf(-x));
}

// fp32 -> bf16 bits (RNE)
__device__ __forceinline__ ushort_t f2bf(float f){
    unsigned int u = __float_as_uint(f);
    unsigned int r = (u + 0x7fffu + ((u >> 16) & 1u)) >> 16;
    return (ushort_t)r;
}
__device__ __forceinline__ float bf2f(ushort_t b){
    return __uint_as_float(((unsigned int)b) << 16);
}

// async global->LDS, 16 B per lane
__device__ __forceinline__ void gload16(const ushort_t* g, ushort_t* lds){
    __builtin_amdgcn_global_load_lds(
        (const __attribute__((address_space(1))) unsigned int*)g,
        (__attribute__((address_space(3))) unsigned int*)lds, 16, 0, 0);
}

// ---------------- FFT filter as circulant kernel ----------------
__global__ void build_filter_kernel(const float* __restrict__ fre,
                                    const float* __restrict__ fim,
                                    const float* __restrict__ cut,
                                    float* __restrict__ rker)
{
    int j = blockIdx.x;
    int t = threadIdx.x;
    float c0 = cut[0];
    double acc = 0.0;
    for (int k = t; k < 512; k += 256) {
        float fr = (float)(k < 256 ? k : k - 512) / 512.0f;
        float mask = (fr >= c0 || fr <= -c0) ? 1.f : 0.f;
        double gre = (double)mask + (double)fre[k];
        double gim = (double)fim[k];
        int pr = (j * k) & 511;
        double ang = 6.283185307179586476925286766559 * (double)pr / 512.0;
        acc += gre * cos(ang) - gim * sin(ang);
    }
    #pragma unroll
    for (int o = 32; o > 0; o >>= 1) acc += __shfl_xor(acc, o);
    __shared__ double sd[4];
    int w = t >> 6;
    if ((t & 63) == 0) sd[w] = acc;
    __syncthreads();
    if (t == 0) rker[j] = (float)((sd[0] + sd[1] + sd[2] + sd[3]) / 512.0);
}

__global__ void circ_expand_kernel(const float* __restrict__ rker, ushort_t* __restrict__ Mc)
{
    int n = blockIdx.x, m = threadIdx.x;
    Mc[n*512 + m] = f2bf(rker[(n - m) & 511]);
}

__global__ void cast4_kernel(const float* __restrict__ in, ushort_t* __restrict__ out, int n4)
{
    int i = blockIdx.x*256 + threadIdx.x;
    if (i < n4) {
        float4 v = ((const float4*)in)[i];
        unsigned int lo = (unsigned int)f2bf(v.x) | ((unsigned int)f2bf(v.y) << 16);
        unsigned int hi = (unsigned int)f2bf(v.z) | ((unsigned int)f2bf(v.w) << 16);
        ((uint2*)out)[i] = make_uint2(lo, hi);
    }
}

// xproj weight: 64x1024 fp32 -> 128x1024 bf16 zero-padded
__global__ void cast_xproj_kernel(const float* __restrict__ in, ushort_t* __restrict__ out)
{
    int i = blockIdx.x*256 + threadIdx.x;
    int r = i >> 10;
    out[i] = (r < 64) ? f2bf(in[i]) : (ushort_t)0;
}

// reduce 4 split-K partials over 3BL x 64
__global__ void reduce_xd_kernel(const float* __restrict__ xdp, float* __restrict__ xd)
{
    int i = blockIdx.x*256 + threadIdx.x;
    const size_t S = (size_t)3*BL*64;
    xd[i] = xdp[i] + xdp[i+S] + xdp[i+2*S] + xdp[i+3*S];
}

// sum 3 branch yg (bf16) -> bf16
__global__ void sum3_kernel(const ushort_t* __restrict__ a, ushort_t* __restrict__ out)
{
    int i = blockIdx.x*256 + threadIdx.x;
    const size_t S = (size_t)BL*DI;
    out[i] = f2bf(bf2f(a[i]) + bf2f(a[i+S]) + bf2f(a[i+2*S]));
}

// ---------------- bf16-native MFMA GEMM (m97 structure) ----------------
// C[m][n] = epi( sum_k A[m][k]*W[n][k] + bias[n] )
// 128x128 tile, BK=32, 4 waves 2x2, wave 64x64 via 4x4 frags 16x16x32.
// Split-K via blockIdx.z; W row stride = Ksub*gridDim.z.
// EPI: 0 none, 2 gelu, 3 silu, 4 emul*silu.  C and Cb nullable.
template<int EPI>
__launch_bounds__(256)
__global__ void bgemm(const ushort_t* __restrict__ A, int lda,
                      const ushort_t* __restrict__ W,
                      const float* __restrict__ bias,
                      const float* __restrict__ emul,
                      float* __restrict__ C,
                      ushort_t* __restrict__ Cb,
                      int ldc, int Ksub, int Nvalid, int accflag, size_t zstride)
{
    __shared__ __align__(16) ushort_t As[128*32];
    __shared__ __align__(16) ushort_t Bs[128*32];
    int t = threadIdx.x;
    int lane = t & 63;
    int w  = t >> 6;
    int wr = w >> 1, wc = w & 1;
    int l15 = lane & 15, quad = lane >> 4;
    const int tileM = blockIdx.y * 128;
    const int tileN = blockIdx.x * 128;
    const int kbeg = blockIdx.z * Ksub;
    const int kend = kbeg + Ksub;

    int srow = w*32 + (lane >> 2);
    int scol = (lane & 3) * 8;
    const ushort_t* gA0 = A + (size_t)(tileM + srow)*lda + scol;
    const ushort_t* gA1 = gA0 + (size_t)16*lda;
    const ushort_t* gW0 = W + (size_t)(tileN + srow)*Ksub*gridDim.z + scol;
    const ushort_t* gW1 = gW0 + (size_t)16*Ksub*gridDim.z;
    ushort_t* ldsA = As + w*1024;
    ushort_t* ldsB = Bs + w*1024;

    f32x4_t acc[4][4];
    #pragma unroll
    for (int i=0;i<4;++i)
        #pragma unroll
        for (int j=0;j<4;++j)
            acc[i][j] = (f32x4_t){0.f,0.f,0.f,0.f};

    for (int kt = kbeg; kt < kend; kt += 32) {
        __syncthreads();
        gload16(gA0 + kt, ldsA);
        gload16(gA1 + kt, ldsA + 512);
        gload16(gW0 + kt, ldsB);
        gload16(gW1 + kt, ldsB + 512);
        __syncthreads();
        short8_t af[4], bfv[4];
        #pragma unroll
        for (int mi=0;mi<4;++mi)
            af[mi] = *(const short8_t*)&As[(wr*64 + mi*16 + l15)*32 + quad*8];
        #pragma unroll
        for (int ni=0;ni<4;++ni)
            bfv[ni] = *(const short8_t*)&Bs[(wc*64 + ni*16 + l15)*32 + quad*8];
        #pragma unroll
        for (int mi=0;mi<4;++mi)
            #pragma unroll
            for (int ni=0;ni<4;++ni)
                acc[mi][ni] = __builtin_amdgcn_mfma_f32_16x16x32_bf16(af[mi], bfv[ni], acc[mi][ni], 0, 0, 0);
    }

    size_t cbase = zstride * blockIdx.z;
    #pragma unroll
    for (int mi=0;mi<4;++mi) {
        #pragma unroll
        for (int ni=0;ni<4;++ni) {
            int gm0 = tileM + wr*64 + mi*16 + quad*4;
            int gn  = tileN + wc*64 + ni*16 + l15;
            if (gn >= Nvalid) continue;
            float bv = bias ? bias[gn] : 0.f;
            #pragma unroll
            for (int r=0;r<4;++r) {
                size_t off = cbase + (size_t)(gm0 + r)*ldc + gn;
                float v = acc[mi][ni][r] + bv;
                if (EPI==2) v = 0.5f*v*(1.f+erff(v*0.70710678118654752440f));
                else if (EPI==3) v = v*sigmoidf_(v);
                else if (EPI==4) v = emul[off] * (v*sigmoidf_(v));
                if (C) { if (accflag) C[off] += v; else C[off] = v; }
                if (Cb) Cb[off] = f2bf(v);
            }
        }
    }
}

// ---------------- batched depthwise causal conv (k=4) + silu, 3 branches ----------------
// xz1 (xg in_proj, bf16), xz2 (x in_proj, bf16); branch 1 reads xz1 time-reversed.
__launch_bounds__(256)
__global__ void conv3_kernel(const ushort_t* __restrict__ xz1,
                             const ushort_t* __restrict__ xz2,
                             const float* __restrict__ cw,
                             const float* __restrict__ cb,
                             ushort_t* __restrict__ xc3)
{
    size_t idx = (size_t)blockIdx.x*256 + threadIdx.x;   // 3*BL*DI
    int d = (int)(idx & (DI-1));
    size_t rowg = idx >> 10;              // 0..3*BL-1
    int l  = (int)(rowg & (SEQ-1));
    int zb = (int)(rowg >> 11);           // br*4 + b
    int b  = zb & 3, br = zb >> 2;
    int rev = (br == 1);
    const ushort_t* xz = (br < 2) ? xz1 : xz2;
    float accv = cb[d];
    #pragma unroll
    for (int k = 0; k < 4; ++k) {
        int ts = l + k - 3;
        if (ts >= 0) {
            int tin = rev ? (SEQ-1-ts) : ts;
            accv = fmaf(cw[d*4+k], bf2f(xz[((size_t)b*SEQ + tin)*2048 + d]), accv);
        }
    }
    xc3[idx] = f2bf(accv * sigmoidf_(accv));
}

// ================= batched chunked selective scan (3 branches, dt fused) =================
// delta = softplus(xd[:, :32] @ dtw[d] + dtb[d]) computed in-kernel from LDS-resident xd.
__launch_bounds__(256)
__global__ void scan3_a(const ushort_t* __restrict__ xc3,
                        const float* __restrict__ xd3,
                        const float* __restrict__ dtw,
                        const float* __restrict__ dtb,
                        const float* __restrict__ A_log,
                        float* __restrict__ hout,
                        float* __restrict__ aprod)
{
    __shared__ float sxd[CH*64];   // 32 KB
    int d  = blockIdx.x*256 + threadIdx.x;
    int c  = blockIdx.y;
    int zb = blockIdx.z;           // br*4 + b
    int b  = zb & 3, br = zb >> 2;
    size_t rbase = (size_t)br*BL + (size_t)b*SEQ + (size_t)c*CH;
    {
        const float4* src = (const float4*)(xd3 + rbase*64);
        float4* dst = (float4*)sxd;
        for (int i = threadIdx.x; i < CH*16; i += 256) dst[i] = src[i];
    }
    float dw[DR];
    #pragma unroll
    for (int j=0;j<DR;j+=4) {
        float4 v = *(const float4*)(dtw + (size_t)d*DR + j);
        dw[j]=v.x; dw[j+1]=v.y; dw[j+2]=v.z; dw[j+3]=v.w;
    }
    float db = dtb[d];
    float An[DS];
    #pragma unroll
    for (int n=0;n<DS;++n) An[n] = -__expf(A_log[d*DS+n]);
    float h[DS], P[DS];
    #pragma unroll
    for (int n=0;n<DS;++n) { h[n]=0.f; P[n]=1.f; }
    __syncthreads();
    for (int t=0;t<CH;++t) {
        float acc = db;
        #pragma unroll
        for (int j=0;j<DR;++j) acc = fmaf(dw[j], sxd[t*64+j], acc);
        float dv = (acc > 20.f) ? acc : __logf(1.f + __expf(acc));
        float uv = bf2f(xc3[(rbase+t)*DI + d]);
        float du = dv*uv;
        const float* Bv = &sxd[t*64 + 32];
        #pragma unroll
        for (int n=0;n<DS;++n) {
            float dA = __expf(dv*An[n]);
            h[n] = fmaf(dA, h[n], du*Bv[n]);
            P[n] *= dA;
        }
    }
    size_t o = (((size_t)zb*NC + c)*DI + d)*DS;
    #pragma unroll
    for (int q=0;q<4;++q) {
        *(float4*)(hout  + o + 4*q) = make_float4(h[4*q],h[4*q+1],h[4*q+2],h[4*q+3]);
        *(float4*)(aprod + o + 4*q) = make_float4(P[4*q],P[4*q+1],P[4*q+2],P[4*q+3]);
    }
}

// Phase B: sequential over chunks; in-place hin into hout.
__launch_bounds__(256)
__global__ void scan3_b(float* __restrict__ hout,
                        const float* __restrict__ aprod)
{
    int idx = blockIdx.x*256 + threadIdx.x;   // 3*BATCH*DI*DS
    int zb = idx >> 14;
    int dn = idx & (DI*DS - 1);
    float hc = 0.f;
    for (int c=0;c<NC;++c) {
        size_t o = ((size_t)zb*NC + c)*(DI*DS) + dn;
        float a = aprod[o], hh = hout[o];
        hout[o] = hc;                 // hin
        hc = fmaf(a, hc, hh);
    }
}

// Phase C: seeded local scan, delta refused, y/D/z-gate, bf16 per-branch output.
__launch_bounds__(256)
__global__ void scan3_c(const ushort_t* __restrict__ xc3,
                        const float* __restrict__ xd3,
                        const ushort_t* __restrict__ xz1,
                        const ushort_t* __restrict__ xz2,
                        const float* __restrict__ dtw,
                        const float* __restrict__ dtb,
                        const float* __restrict__ A_log,
                        const float* __restrict__ Dp,
                        const float* __restrict__ hin,
                        ushort_t* __restrict__ yg3)
{
    __shared__ float sxd[CH*64];
    int d  = blockIdx.x*256 + threadIdx.x;
    int c  = blockIdx.y;
    int zb = blockIdx.z;
    int b  = zb & 3, br = zb >> 2;
    int rev = (br == 1);
    const ushort_t* xz = (br < 2) ? xz1 : xz2;
    size_t rbase = (size_t)br*BL + (size_t)b*SEQ + (size_t)c*CH;
    {
        const float4* src = (const float4*)(xd3 + rbase*64);
        float4* dst = (float4*)sxd;
        for (int i = threadIdx.x; i < CH*16; i += 256) dst[i] = src[i];
    }
    float dw[DR];
    #pragma unroll
    for (int j=0;j<DR;j+=4) {
        float4 v = *(const float4*)(dtw + (size_t)d*DR + j);
        dw[j]=v.x; dw[j+1]=v.y; dw[j+2]=v.z; dw[j+3]=v.w;
    }
    float db = dtb[d];
    float An[DS];
    #pragma unroll
    for (int n=0;n<DS;++n) An[n] = -__expf(A_log[d*DS+n]);
    float h[DS];
    size_t o = (((size_t)zb*NC + c)*DI + d)*DS;
    #pragma unroll
    for (int q=0;q<4;++q) {
        float4 hv = *(const float4*)(hin + o + 4*q);
        h[4*q]=hv.x; h[4*q+1]=hv.y; h[4*q+2]=hv.z; h[4*q+3]=hv.w;
    }
    float Dd = Dp[d];
    __syncthreads();
    for (int t=0;t<CH;++t) {
        float acc = db;
        #pragma unroll
        for (int j=0;j<DR;++j) acc = fmaf(dw[j], sxd[t*64+j], acc);
        float dv = (acc > 20.f) ? acc : __logf(1.f + __expf(acc));
        float uv = bf2f(xc3[(rbase+t)*DI + d]);
        float du = dv*uv;
        const float* Bv = &sxd[t*64 + 32];
        const float* Cv = &sxd[t*64 + 48];
        int l = c*CH + t;
        int tz = rev ? (SEQ-1-l) : l;
        float zv = bf2f(xz[((size_t)b*SEQ + tz)*2048 + DI + d]);
        float y = 0.f;
        #pragma unroll
        for (int n=0;n<DS;++n) {
            float dA = __expf(dv*An[n]);
            h[n] = fmaf(dA, h[n], du*Bv[n]);
            y = fmaf(h[n], Cv[n], y);
        }
        float val = (y + uv*Dd) * (zv * sigmoidf_(zv));
        yg3[(rbase+t)*DI + d] = f2bf(val);
    }
}

// ---------------- layernorm over d=512 (optional residual, fp32/bf16 outs) ----------------
__launch_bounds__(256)
__global__ void ln_kernel(const float* __restrict__ a, const float* __restrict__ res,
                          const float* __restrict__ g, const float* __restrict__ bta,
                          float* __restrict__ out, ushort_t* __restrict__ outb, float eps)
{
    size_t row = blockIdx.x;
    int t = threadIdx.x;
    const float* ap = a + row*DM;
    float v0 = ap[t], v1 = ap[t+256];
    if (res) { const float* rp = res + row*DM; v0 += rp[t]; v1 += rp[t+256]; }
    float s = v0+v1, q = v0*v0 + v1*v1;
    #pragma unroll
    for (int o=32;o>0;o>>=1){ s += __shfl_xor(s,o); q += __shfl_xor(q,o); }
    __shared__ float ss[4], sq[4];
    int w = t>>6;
    if ((t&63)==0){ ss[w]=s; sq[w]=q; }
    __syncthreads();
    s = ss[0]+ss[1]+ss[2]+ss[3];
    q = sq[0]+sq[1]+sq[2]+sq[3];
    float mean = s * (1.f/DM);
    float var  = q * (1.f/DM) - mean*mean;
    var = var < 0.f ? 0.f : var;
    float rstd = rsqrtf(var + eps);
    float o0 = (v0-mean)*rstd*g[t]     + bta[t];
    float o1 = (v1-mean)*rstd*g[t+256] + bta[t+256];
    if (out) { out[row*DM+t] = o0; out[row*DM+t+256] = o1; }
    if (outb){ outb[row*DM+t] = f2bf(o0); outb[row*DM+t+256] = f2bf(o1); }
}

__launch_bounds__(256)
__global__ void gate_ln_kernel(const float* __restrict__ ha, const float* __restrict__ hb,
                               const float* __restrict__ mo,
                               const float* __restrict__ g, const float* __restrict__ bta,
                               float* __restrict__ out, ushort_t* __restrict__ outb, float eps)
{
    size_t row = blockIdx.x;
    int t = threadIdx.x;
    size_t i0 = row*DM + t, i1 = i0 + 256;
    float a0 = ha[i0], a1 = ha[i1];
    float v0 = fmaf(a0, hb[i0], a0) + mo[i0];
    float v1 = fmaf(a1, hb[i1], a1) + mo[i1];
    float s = v0+v1, q = v0*v0 + v1*v1;
    #pragma unroll
    for (int o=32;o>0;o>>=1){ s += __shfl_xor(s,o); q += __shfl_xor(q,o); }
    __shared__ float ss[4], sq[4];
    int w = t>>6;
    if ((t&63)==0){ ss[w]=s; sq[w]=q; }
    __syncthreads();
    s = ss[0]+ss[1]+ss[2]+ss[3];
    q = sq[0]+sq[1]+sq[2]+sq[3];
    float mean = s * (1.f/DM);
    float var  = q * (1.f/DM) - mean*mean;
    var = var < 0.f ? 0.f : var;
    float rstd = rsqrtf(var + eps);
    float o0 = (v0-mean)*rstd*g[t]     + bta[t];
    float o1 = (v1-mean)*rstd*g[t+256] + bta[t+256];
    out[i0] = o0; out[i1] = o1;
    outb[row*DM+t] = f2bf(o0); outb[row*DM+t+256] = f2bf(o1);
}

// ================= host side =================
static void launch_bgemm(int epi, const ushort_t* A, int lda, const ushort_t* W,
                         const float* bias, const float* emul,
                         float* C, ushort_t* Cb, int ldc, int Mrows, int Ngrid, int K,
                         int Nvalid, int accf, hipStream_t s)
{
    dim3 g(Ngrid/128, Mrows/128, 1);
    switch (epi) {
    case 0: bgemm<0><<<g,256,0,s>>>(A,lda,W,bias,emul,C,Cb,ldc,K,Nvalid,accf,0); break;
    case 2: bgemm<2><<<g,256,0,s>>>(A,lda,W,bias,emul,C,Cb,ldc,K,Nvalid,accf,0); break;
    case 3: bgemm<3><<<g,256,0,s>>>(A,lda,W,bias,emul,C,Cb,ldc,K,Nvalid,accf,0); break;
    case 4: bgemm<4><<<g,256,0,s>>>(A,lda,W,bias,emul,C,Cb,ldc,K,Nvalid,accf,0); break;
    }
}

static void cast4(const float* in, ushort_t* out, int n, hipStream_t s)
{
    cast4_kernel<<<(n/4 + 255)/256, 256, 0, s>>>(in, out, n/4);
}

extern "C" void kernel_launch(void* const* d_in, const int* in_sizes, int n_in,
                              void* d_out, int out_size, void* d_ws, size_t ws_size,
                              hipStream_t stream)
{
    const float* x        = (const float*)d_in[0];
    const float* fre      = (const float*)d_in[1];
    const float* fim      = (const float*)d_in[2];
    const float* cutoff   = (const float*)d_in[3];
    const float* ln0_g    = (const float*)d_in[4];
    const float* ln0_b    = (const float*)d_in[5];
    const float* l1_w     = (const float*)d_in[6];
    const float* l1_b     = (const float*)d_in[7];
    const float* l2_w     = (const float*)d_in[8];
    const float* l2_b     = (const float*)d_in[9];
    const float* in_w     = (const float*)d_in[10];
    const float* conv_w   = (const float*)d_in[11];
    const float* conv_b   = (const float*)d_in[12];
    const float* xproj_w  = (const float*)d_in[13];
    const float* dt_w     = (const float*)d_in[14];
    const float* dt_b     = (const float*)d_in[15];
    const float* A_log    = (const float*)d_in[16];
    const float* Dp       = (const float*)d_in[17];
    const float* out_w    = (const float*)d_in[18];
    const float* ln1_g    = (const float*)d_in[19];
    const float* ln1_b    = (const float*)d_in[20];
    const float* d1_w     = (const float*)d_in[21];
    const float* d1_b     = (const float*)d_in[22];
    const float* d2_w     = (const float*)d_in[23];
    const float* d2_b     = (const float*)d_in[24];
    const float* ln2_g    = (const float*)d_in[25];
    const float* ln2_b    = (const float*)d_in[26];
    const float* ffn_w1   = (const float*)d_in[27];
    const float* ffn_b1   = (const float*)d_in[28];
    const float* ffn_w2   = (const float*)d_in[29];
    const float* ffn_b2   = (const float*)d_in[30];
    const float* ffn_ln_g = (const float*)d_in[31];
    const float* ffn_ln_b = (const float*)d_in[32];

    float* ws = (float*)d_ws;
    float* RK = ws;                                  // 1024
    float* WFf = RK + 1024;                          // bf16 weight pool backing
    ushort_t* MCb  = (ushort_t*)WFf;                 // 512*512
    ushort_t* L1b  = MCb  + 262144;
    ushort_t* L2b  = L1b  + 262144;
    ushort_t* INb  = L2b  + 262144;                  // 2048*512
    ushort_t* OUTb = INb  + 1048576;                 // 512*1024
    ushort_t* D1b  = OUTb + 524288;
    ushort_t* D2b  = D1b  + 262144;
    ushort_t* F1b  = D2b  + 262144;                  // 2048*512
    ushort_t* F2b  = F1b  + 1048576;                 // 512*2048
    ushort_t* XPb  = F2b  + 1048576;                 // 128*1024
    float* P = WFf + 2555904;                        // 20,971,520-float multi-stage pool
    // -- stage 1-2 (until in_proj#2 consumed) --
    ushort_t* XNb = (ushort_t*)P;                    // bf16 xn
    ushort_t* XGb = (ushort_t*)(P + 2097152);        // bf16 xg
    float*    T1a = P + 4194304;                     // fp32 l1-out
    ushort_t* XBx = (ushort_t*)(P + 8388608);        // bf16 x
    // -- stage 3 (branches) --
    float*    XD3  = P;                              // 3BL*64          (1,572,864)
    ushort_t* YG3b = (ushort_t*)(P + 1572864);       // 3*BL*DI bf16    (12,582,912 f)
    float*    XDP  = P + 14155776;                   // 4*3BL*64        (6,291,456) transient
    float*    HOUT = P + 14155776;                   // 3,145,728 (after XDP dead)
    float*    APR  = P + 17301504;                   // 3,145,728
    // -- stage 4-6 --
    float*    MOf = P;                               // fp32 mo
    ushort_t* MOb = (ushort_t*)(P + 4194304);        // bf16 mo
    float*    T2g = P + 6291456;                     // fp32 hb
    float*    T1g = P + 10485760;                    // fp32 ha, then ffn2-out
    float*    HSf = P + 14680064;                    // fp32 hs
    ushort_t* HSb = (ushort_t*)(P + 18874368);       // bf16 hs
    // -- large bf16 activations --
    float* XZ1f = P + 20971520;
    ushort_t* XZ1b = (ushort_t*)XZ1f;                // BL*2048 bf16 (xz of xg); later FFN hidden
    ushort_t* FHb  = XZ1b;
    float* XZ2f = XZ1f + 8388608;
    ushort_t* XZ2b = (ushort_t*)XZ2f;                // BL*2048 bf16 (xz of x)
    float* XC3f = XZ2f + 8388608;
    ushort_t* XC3b = (ushort_t*)XC3f;                // 3*BL*DI bf16 conv-out
    float*    XI   = XC3f;                           // fp32 xi (dead before conv)
    ushort_t* YGb  = (ushort_t*)XC3f;                // bf16 summed yg (after XC dead)
    float* MS = XC3f + 12582912;                     // fp32 out_proj result
    float* OUT = (float*)d_out;

    // 0) weight conversions
    cast4(l1_w,  L1b,  512*512,  stream);
    cast4(l2_w,  L2b,  512*512,  stream);
    cast4(in_w,  INb,  2048*512, stream);
    cast4(out_w, OUTb, 512*1024, stream);
    cast4(d1_w,  D1b,  512*512,  stream);
    cast4(d2_w,  D2b,  512*512,  stream);
    cast4(ffn_w1,F1b,  2048*512, stream);
    cast4(ffn_w2,F2b,  512*2048, stream);
    cast_xproj_kernel<<<512,256,0,stream>>>(xproj_w, XPb);
    cast4(x, XBx, BL*DM, stream);

    // 1) circulant bf16 GEMM, then LN(xi + x) -> bf16 xn
    build_filter_kernel<<<512,256,0,stream>>>(fre, fim, cutoff, RK);
    circ_expand_kernel<<<512,512,0,stream>>>(RK, MCb);
    launch_bgemm(0, XBx,DM, MCb, nullptr, nullptr, XI,nullptr, DM, BL, DM, DM, DM, 0, stream);
    ln_kernel<<<BL,256,0,stream>>>(XI, x, ln0_g, ln0_b, nullptr, XNb, 1e-5f);

    // 2) xg = (xn@l1^T+b1) * silu(xn@l2^T+b2) -> bf16 XGb
    launch_bgemm(0, XNb,DM, L1b, l1_b, nullptr, T1a,nullptr, DM, BL, DM, DM, DM, 0, stream);
    launch_bgemm(4, XNb,DM, L2b, l2_b, T1a, nullptr,XGb, DM, BL, DM, DM, DM, 0, stream);

    // 3) mamba: two in_proj (bf16 xz), batched conv/xproj/scan over 3 branches
    launch_bgemm(0, XGb,DM, INb, nullptr, nullptr, nullptr,XZ1b, 2048, BL, 2048, DM, 2048, 0, stream);
    launch_bgemm(0, XBx,DM, INb, nullptr, nullptr, nullptr,XZ2b, 2048, BL, 2048, DM, 2048, 0, stream);
    conv3_kernel<<<(3*BL*DI)/256,256,0,stream>>>(XZ1b, XZ2b, conv_w, conv_b, XC3b);
    // xproj over 3BL rows, split-K x4 -> XDP -> XD3
    bgemm<0><<<dim3(1, (3*BL)/128, 4),256,0,stream>>>(XC3b,DI, XPb, nullptr, nullptr,
                                                      XDP,nullptr, 64, DI/4, 64, 0, (size_t)3*BL*64);
    reduce_xd_kernel<<<(3*BL*64)/256,256,0,stream>>>(XDP, XD3);
    {
        dim3 ga(DI/256, NC, 12);
        scan3_a<<<ga,256,0,stream>>>(XC3b, XD3, dt_w, dt_b, A_log, HOUT, APR);
        scan3_b<<<(3*BATCH*DI*DS)/256,256,0,stream>>>(HOUT, APR);
        scan3_c<<<ga,256,0,stream>>>(XC3b, XD3, XZ1b, XZ2b, dt_w, dt_b, A_log, Dp, HOUT, YG3b);
    }
    sum3_kernel<<<(BL*DI)/256,256,0,stream>>>(YG3b, YGb);
    launch_bgemm(0, YGb,DI, OUTb, nullptr, nullptr, MS,nullptr, DM, BL, DM, DI, DM, 0, stream);

    // 4) mo = LN(m1+m2+m3)
    ln_kernel<<<BL,256,0,stream>>>(MS, nullptr, ln1_g, ln1_b, MOf, MOb, 1e-12f);

    // 5) ha/hb gate + LN -> hs
    launch_bgemm(3, MOb,DM, D1b, d1_b, nullptr, T2g,nullptr, DM, BL, DM, DM, DM, 0, stream);  // hb
    launch_bgemm(0, MOb,DM, D2b, d2_b, nullptr, T1g,nullptr, DM, BL, DM, DM, DM, 0, stream);  // ha
    gate_ln_kernel<<<BL,256,0,stream>>>(T1g, T2g, MOf, ln2_g, ln2_b, HSf, HSb, 1e-12f);

    // 6) FFN: gelu(hs@w1^T+b1) -> bf16 hidden; @w2^T+b2; out = LN(h + hs)
    launch_bgemm(2, HSb,DM, F1b, ffn_b1, nullptr, nullptr,FHb, 2048, BL, 2048, DM, 2048, 0, stream);
    launch_bgemm(0, FHb,2048, F2b, ffn_b2, nullptr, T1g,nullptr, DM, BL, DM, 2048, DM, 0, stream);
    ln_kernel<<<BL,256,0,stream>>>(T1g, HSf, ffn_ln_g, ffn_ln_b, OUT, nullptr, 1e-12f);
}

// Round 10
// 913.579 us; speedup vs baseline: 12.1546x; 1.0369x over previous
//
#include <hip/hip_runtime.h>
#include <math.h>

#define BATCH 4
#define SEQ   2048
#define DM    512
#define DI    1024
#define DS    16
#define DR    32
#define BL    (BATCH*SEQ)   // 8192 tokens

#define CH 128              // scan chunk length
#define NC (SEQ/CH)         // 16 chunks per sequence
#define TG 32               // delta t-group (MFMA sub-chunk)

typedef __attribute__((ext_vector_type(8))) short short8_t;   // 8 bf16 = 4 VGPRs
typedef __attribute__((ext_vector_type(4))) float f32x4_t;    // MFMA acc
typedef unsigned short ushort_t;

// fast sigmoid: v_exp_f32 + v_rcp_f32
__device__ __forceinline__ float sigmoidf_(float x){
    return __builtin_amdgcn_rcpf(1.f + __expf(-x));
}

// fp32 -> bf16 bits (RNE)
__device__ __forceinline__ ushort_t f2bf(float f){
    unsigned int u = __float_as_uint(f);
    unsigned int r = (u + 0x7fffu + ((u >> 16) & 1u)) >> 16;
    return (ushort_t)r;
}
__device__ __forceinline__ float bf2f(ushort_t b){
    return __uint_as_float(((unsigned int)b) << 16);
}

// async global->LDS, 16 B per lane
__device__ __forceinline__ void gload16(const ushort_t* g, ushort_t* lds){
    __builtin_amdgcn_global_load_lds(
        (const __attribute__((address_space(1))) unsigned int*)g,
        (__attribute__((address_space(3))) unsigned int*)lds, 16, 0, 0);
}

// ---------------- FFT filter as circulant kernel ----------------
__global__ void build_filter_kernel(const float* __restrict__ fre,
                                    const float* __restrict__ fim,
                                    const float* __restrict__ cut,
                                    float* __restrict__ rker)
{
    int j = blockIdx.x;
    int t = threadIdx.x;
    float c0 = cut[0];
    double acc = 0.0;
    for (int k = t; k < 512; k += 256) {
        float fr = (float)(k < 256 ? k : k - 512) / 512.0f;
        float mask = (fr >= c0 || fr <= -c0) ? 1.f : 0.f;
        double gre = (double)mask + (double)fre[k];
        double gim = (double)fim[k];
        int pr = (j * k) & 511;
        double ang = 6.283185307179586476925286766559 * (double)pr / 512.0;
        acc += gre * cos(ang) - gim * sin(ang);
    }
    #pragma unroll
    for (int o = 32; o > 0; o >>= 1) acc += __shfl_xor(acc, o);
    __shared__ double sd[4];
    int w = t >> 6;
    if ((t & 63) == 0) sd[w] = acc;
    __syncthreads();
    if (t == 0) rker[j] = (float)((sd[0] + sd[1] + sd[2] + sd[3]) / 512.0);
}

__global__ void circ_expand_kernel(const float* __restrict__ rker, ushort_t* __restrict__ Mc)
{
    int n = blockIdx.x, m = threadIdx.x;
    Mc[n*512 + m] = f2bf(rker[(n - m) & 511]);
}

__global__ void cast4_kernel(const float* __restrict__ in, ushort_t* __restrict__ out, int n4)
{
    int i = blockIdx.x*256 + threadIdx.x;
    if (i < n4) {
        float4 v = ((const float4*)in)[i];
        unsigned int lo = (unsigned int)f2bf(v.x) | ((unsigned int)f2bf(v.y) << 16);
        unsigned int hi = (unsigned int)f2bf(v.z) | ((unsigned int)f2bf(v.w) << 16);
        ((uint2*)out)[i] = make_uint2(lo, hi);
    }
}

// xproj weight: 64x1024 fp32 -> 128x1024 bf16 zero-padded
__global__ void cast_xproj_kernel(const float* __restrict__ in, ushort_t* __restrict__ out)
{
    int i = blockIdx.x*256 + threadIdx.x;
    int r = i >> 10;
    out[i] = (r < 64) ? f2bf(in[i]) : (ushort_t)0;
}

// reduce 4 split-K partials over 3BL x 64 -> compact fp32 B/C (cols 32..63)
// and bf16 dt-input (cols 0..31)
__global__ void reduce_xd_kernel(const float* __restrict__ xdp,
                                 float* __restrict__ xdbc,
                                 ushort_t* __restrict__ dti)
{
    int i = blockIdx.x*256 + threadIdx.x;   // 3BL*64
    const size_t S = (size_t)3*BL*64;
    float s = xdp[i] + xdp[i+S] + xdp[i+2*S] + xdp[i+3*S];
    int col = i & 63;
    int row = i >> 6;
    if (col < 32) dti[(size_t)row*32 + col] = f2bf(s);
    else          xdbc[(size_t)row*32 + col - 32] = s;
}

// sum 3 branch yg (bf16) -> bf16
__global__ void sum3_kernel(const ushort_t* __restrict__ a, ushort_t* __restrict__ out)
{
    int i = blockIdx.x*256 + threadIdx.x;
    const size_t S = (size_t)BL*DI;
    out[i] = f2bf(bf2f(a[i]) + bf2f(a[i+S]) + bf2f(a[i+2*S]));
}

// ---------------- bf16-native MFMA GEMM (m97 structure) ----------------
// EPI: 0 none, 2 gelu, 3 silu, 4 emul*silu, 5 silu on cols>=DI (in_proj z-half)
template<int EPI>
__launch_bounds__(256)
__global__ void bgemm(const ushort_t* __restrict__ A, int lda,
                      const ushort_t* __restrict__ W,
                      const float* __restrict__ bias,
                      const float* __restrict__ emul,
                      float* __restrict__ C,
                      ushort_t* __restrict__ Cb,
                      int ldc, int Ksub, int Nvalid, int accflag, size_t zstride)
{
    __shared__ __align__(16) ushort_t As[128*32];
    __shared__ __align__(16) ushort_t Bs[128*32];
    int t = threadIdx.x;
    int lane = t & 63;
    int w  = t >> 6;
    int wr = w >> 1, wc = w & 1;
    int l15 = lane & 15, quad = lane >> 4;
    const int tileM = blockIdx.y * 128;
    const int tileN = blockIdx.x * 128;
    const int kbeg = blockIdx.z * Ksub;
    const int kend = kbeg + Ksub;

    int srow = w*32 + (lane >> 2);
    int scol = (lane & 3) * 8;
    const ushort_t* gA0 = A + (size_t)(tileM + srow)*lda + scol;
    const ushort_t* gA1 = gA0 + (size_t)16*lda;
    const ushort_t* gW0 = W + (size_t)(tileN + srow)*Ksub*gridDim.z + scol;
    const ushort_t* gW1 = gW0 + (size_t)16*Ksub*gridDim.z;
    ushort_t* ldsA = As + w*1024;
    ushort_t* ldsB = Bs + w*1024;

    f32x4_t acc[4][4];
    #pragma unroll
    for (int i=0;i<4;++i)
        #pragma unroll
        for (int j=0;j<4;++j)
            acc[i][j] = (f32x4_t){0.f,0.f,0.f,0.f};

    for (int kt = kbeg; kt < kend; kt += 32) {
        __syncthreads();
        gload16(gA0 + kt, ldsA);
        gload16(gA1 + kt, ldsA + 512);
        gload16(gW0 + kt, ldsB);
        gload16(gW1 + kt, ldsB + 512);
        __syncthreads();
        short8_t af[4], bfv[4];
        #pragma unroll
        for (int mi=0;mi<4;++mi)
            af[mi] = *(const short8_t*)&As[(wr*64 + mi*16 + l15)*32 + quad*8];
        #pragma unroll
        for (int ni=0;ni<4;++ni)
            bfv[ni] = *(const short8_t*)&Bs[(wc*64 + ni*16 + l15)*32 + quad*8];
        #pragma unroll
        for (int mi=0;mi<4;++mi)
            #pragma unroll
            for (int ni=0;ni<4;++ni)
                acc[mi][ni] = __builtin_amdgcn_mfma_f32_16x16x32_bf16(af[mi], bfv[ni], acc[mi][ni], 0, 0, 0);
    }

    size_t cbase = zstride * blockIdx.z;
    #pragma unroll
    for (int mi=0;mi<4;++mi) {
        #pragma unroll
        for (int ni=0;ni<4;++ni) {
            int gm0 = tileM + wr*64 + mi*16 + quad*4;
            int gn  = tileN + wc*64 + ni*16 + l15;
            if (gn >= Nvalid) continue;
            float bv = bias ? bias[gn] : 0.f;
            #pragma unroll
            for (int r=0;r<4;++r) {
                size_t off = cbase + (size_t)(gm0 + r)*ldc + gn;
                float v = acc[mi][ni][r] + bv;
                if (EPI==2) v = 0.5f*v*(1.f+erff(v*0.70710678118654752440f));
                else if (EPI==3) v = v*sigmoidf_(v);
                else if (EPI==4) v = emul[off] * (v*sigmoidf_(v));
                else if (EPI==5) { if (gn >= DI) v = v*sigmoidf_(v); }
                if (C) { if (accflag) C[off] += v; else C[off] = v; }
                if (Cb) Cb[off] = f2bf(v);
            }
        }
    }
}

// ---------------- batched depthwise causal conv (k=4) + silu, 3 branches ----------------
__launch_bounds__(256)
__global__ void conv3_kernel(const ushort_t* __restrict__ xz1,
                             const ushort_t* __restrict__ xz2,
                             const float* __restrict__ cw,
                             const float* __restrict__ cb,
                             ushort_t* __restrict__ xc3)
{
    size_t idx = (size_t)blockIdx.x*256 + threadIdx.x;   // 3*BL*DI
    int d = (int)(idx & (DI-1));
    size_t rowg = idx >> 10;
    int l  = (int)(rowg & (SEQ-1));
    int zb = (int)(rowg >> 11);           // br*4 + b
    int b  = zb & 3, br = zb >> 2;
    int rev = (br == 1);
    const ushort_t* xz = (br < 2) ? xz1 : xz2;
    float accv = cb[d];
    #pragma unroll
    for (int k = 0; k < 4; ++k) {
        int ts = l + k - 3;
        if (ts >= 0) {
            int tin = rev ? (SEQ-1-ts) : ts;
            accv = fmaf(cw[d*4+k], bf2f(xz[((size_t)b*SEQ + tin)*2048 + d]), accv);
        }
    }
    xc3[idx] = f2bf(accv * sigmoidf_(accv));
}

// ================= batched chunked selective scan =================
// delta computed per t-group via MFMA (idle matrix pipe) from bf16 dt-input;
// B/C staged compact fp32; z pre-silu'd in in_proj epilogue.
__launch_bounds__(256)
__global__ void scan3_a(const ushort_t* __restrict__ xc3,
                        const float* __restrict__ xdbc,
                        const ushort_t* __restrict__ dti,
                        const ushort_t* __restrict__ dtwb,
                        const float* __restrict__ dtb,
                        const float* __restrict__ A_log,
                        float* __restrict__ hout,
                        float* __restrict__ aprod)
{
    __shared__ __align__(16) float    sbc[CH*32];    // B/C cols, 16 KB
    __shared__ __align__(16) ushort_t sdta[CH*32];   // dt-input bf16, 8 KB
    __shared__ ushort_t sdel[TG*256];                // delta bf16, 16 KB
    int tid = threadIdx.x;
    int lane = tid & 63, w = tid >> 6;
    int l15 = lane & 15, quad = lane >> 4;
    int c = blockIdx.y, zb = blockIdx.z;
    int d0 = blockIdx.x*256;
    int d  = d0 + tid;
    size_t rbase = (size_t)zb*SEQ + (size_t)c*CH;
    {
        const float4* s = (const float4*)(xdbc + rbase*32);
        for (int i = tid; i < CH*8; i += 256) ((float4*)sbc)[i] = s[i];
        const uint4* s2 = (const uint4*)(dti + rbase*32);
        for (int i = tid; i < CH*4; i += 256) ((uint4*)sdta)[i] = s2[i];
    }
    short8_t bfr[4]; float dtbl[4];
    #pragma unroll
    for (int j=0;j<4;++j){
        int dl = w*64 + j*16 + l15;
        bfr[j] = *(const short8_t*)(dtwb + (size_t)(d0+dl)*DR + quad*8);
        dtbl[j] = dtb[d0+dl];
    }
    float An[DS];
    #pragma unroll
    for (int n=0;n<DS;++n) An[n] = -__expf(A_log[(size_t)d*DS+n]);
    float h[DS], P[DS];
    #pragma unroll
    for (int n=0;n<DS;++n) { h[n]=0.f; P[n]=1.f; }
    __syncthreads();
    for (int g=0; g<CH/TG; ++g) {
        if (g) __syncthreads();
        #pragma unroll
        for (int tt=0; tt<2; ++tt) {
            short8_t af = *(const short8_t*)&sdta[(g*TG + tt*16 + l15)*32 + quad*8];
            #pragma unroll
            for (int j=0;j<4;++j) {
                f32x4_t dacc = (f32x4_t){0.f,0.f,0.f,0.f};
                dacc = __builtin_amdgcn_mfma_f32_16x16x32_bf16(af, bfr[j], dacc, 0,0,0);
                int dl = w*64 + j*16 + l15;
                #pragma unroll
                for (int r=0;r<4;++r) {
                    float v = dacc[r] + dtbl[j];
                    v = (v > 20.f) ? v : __logf(1.f + __expf(v));
                    sdel[(tt*16 + quad*4 + r)*256 + dl] = f2bf(v);
                }
            }
        }
        __syncthreads();
        int tb = g*TG;
        for (int t=tb; t<tb+TG; ++t) {
            float dv = bf2f(sdel[(t-tb)*256 + tid]);
            float uv = bf2f(xc3[(rbase+t)*DI + d]);
            float du = dv*uv;
            const float* Bv = &sbc[t*32];
            #pragma unroll
            for (int n=0;n<DS;++n) {
                float dA = __expf(dv*An[n]);
                h[n] = fmaf(dA, h[n], du*Bv[n]);
                P[n] *= dA;
            }
        }
    }
    size_t o = (((size_t)zb*NC + c)*DI + d)*DS;
    #pragma unroll
    for (int q=0;q<4;++q) {
        *(float4*)(hout  + o + 4*q) = make_float4(h[4*q],h[4*q+1],h[4*q+2],h[4*q+3]);
        *(float4*)(aprod + o + 4*q) = make_float4(P[4*q],P[4*q+1],P[4*q+2],P[4*q+3]);
    }
}

__launch_bounds__(256)
__global__ void scan3_b(float* __restrict__ hout,
                        const float* __restrict__ aprod)
{
    int idx = blockIdx.x*256 + threadIdx.x;   // 3*BATCH*DI*DS
    int zb = idx >> 14;
    int dn = idx & (DI*DS - 1);
    float hc = 0.f;
    for (int c=0;c<NC;++c) {
        size_t o = ((size_t)zb*NC + c)*(DI*DS) + dn;
        float a = aprod[o], hh = hout[o];
        hout[o] = hc;                 // hin
        hc = fmaf(a, hc, hh);
    }
}

__launch_bounds__(256)
__global__ void scan3_c(const ushort_t* __restrict__ xc3,
                        const float* __restrict__ xdbc,
                        const ushort_t* __restrict__ dti,
                        const ushort_t* __restrict__ xz1,
                        const ushort_t* __restrict__ xz2,
                        const ushort_t* __restrict__ dtwb,
                        const float* __restrict__ dtb,
                        const float* __restrict__ A_log,
                        const float* __restrict__ Dp,
                        const float* __restrict__ hin,
                        ushort_t* __restrict__ yg3)
{
    __shared__ __align__(16) float    sbc[CH*32];
    __shared__ __align__(16) ushort_t sdta[CH*32];
    __shared__ ushort_t sdel[TG*256];
    int tid = threadIdx.x;
    int lane = tid & 63, w = tid >> 6;
    int l15 = lane & 15, quad = lane >> 4;
    int c = blockIdx.y, zb = blockIdx.z;
    int b  = zb & 3, br = zb >> 2;
    int rev = (br == 1);
    const ushort_t* xz = (br < 2) ? xz1 : xz2;
    int d0 = blockIdx.x*256;
    int d  = d0 + tid;
    size_t rbase = (size_t)zb*SEQ + (size_t)c*CH;
    {
        const float4* s = (const float4*)(xdbc + rbase*32);
        for (int i = tid; i < CH*8; i += 256) ((float4*)sbc)[i] = s[i];
        const uint4* s2 = (const uint4*)(dti + rbase*32);
        for (int i = tid; i < CH*4; i += 256) ((uint4*)sdta)[i] = s2[i];
    }
    short8_t bfr[4]; float dtbl[4];
    #pragma unroll
    for (int j=0;j<4;++j){
        int dl = w*64 + j*16 + l15;
        bfr[j] = *(const short8_t*)(dtwb + (size_t)(d0+dl)*DR + quad*8);
        dtbl[j] = dtb[d0+dl];
    }
    float An[DS];
    #pragma unroll
    for (int n=0;n<DS;++n) An[n] = -__expf(A_log[(size_t)d*DS+n]);
    float h[DS];
    size_t o = (((size_t)zb*NC + c)*DI + d)*DS;
    #pragma unroll
    for (int q=0;q<4;++q) {
        float4 hv = *(const float4*)(hin + o + 4*q);
        h[4*q]=hv.x; h[4*q+1]=hv.y; h[4*q+2]=hv.z; h[4*q+3]=hv.w;
    }
    float Dd = Dp[d];
    __syncthreads();
    for (int g=0; g<CH/TG; ++g) {
        if (g) __syncthreads();
        #pragma unroll
        for (int tt=0; tt<2; ++tt) {
            short8_t af = *(const short8_t*)&sdta[(g*TG + tt*16 + l15)*32 + quad*8];
            #pragma unroll
            for (int j=0;j<4;++j) {
                f32x4_t dacc = (f32x4_t){0.f,0.f,0.f,0.f};
                dacc = __builtin_amdgcn_mfma_f32_16x16x32_bf16(af, bfr[j], dacc, 0,0,0);
                int dl = w*64 + j*16 + l15;
                #pragma unroll
                for (int r=0;r<4;++r) {
                    float v = dacc[r] + dtbl[j];
                    v = (v > 20.f) ? v : __logf(1.f + __expf(v));
                    sdel[(tt*16 + quad*4 + r)*256 + dl] = f2bf(v);
                }
            }
        }
        __syncthreads();
        int tb = g*TG;
        for (int t=tb; t<tb+TG; ++t) {
            float dv = bf2f(sdel[(t-tb)*256 + tid]);
            float uv = bf2f(xc3[(rbase+t)*DI + d]);
            float du = dv*uv;
            const float* Bv = &sbc[t*32];
            const float* Cv = &sbc[t*32 + 16];
            int l = c*CH + t;
            int tz = rev ? (SEQ-1-l) : l;
            float zg = bf2f(xz[((size_t)b*SEQ + tz)*2048 + DI + d]);  // pre-silu'd
            float y = 0.f;
            #pragma unroll
            for (int n=0;n<DS;++n) {
                float dA = __expf(dv*An[n]);
                h[n] = fmaf(dA, h[n], du*Bv[n]);
                y = fmaf(h[n], Cv[n], y);
            }
            yg3[(rbase+t)*DI + d] = f2bf((y + uv*Dd) * zg);
        }
    }
}

// ---------------- layernorm over d=512 ----------------
__launch_bounds__(256)
__global__ void ln_kernel(const float* __restrict__ a, const float* __restrict__ res,
                          const float* __restrict__ g, const float* __restrict__ bta,
                          float* __restrict__ out, ushort_t* __restrict__ outb, float eps)
{
    size_t row = blockIdx.x;
    int t = threadIdx.x;
    const float* ap = a + row*DM;
    float v0 = ap[t], v1 = ap[t+256];
    if (res) { const float* rp = res + row*DM; v0 += rp[t]; v1 += rp[t+256]; }
    float s = v0+v1, q = v0*v0 + v1*v1;
    #pragma unroll
    for (int o=32;o>0;o>>=1){ s += __shfl_xor(s,o); q += __shfl_xor(q,o); }
    __shared__ float ss[4], sq[4];
    int w = t>>6;
    if ((t&63)==0){ ss[w]=s; sq[w]=q; }
    __syncthreads();
    s = ss[0]+ss[1]+ss[2]+ss[3];
    q = sq[0]+sq[1]+sq[2]+sq[3];
    float mean = s * (1.f/DM);
    float var  = q * (1.f/DM) - mean*mean;
    var = var < 0.f ? 0.f : var;
    float rstd = rsqrtf(var + eps);
    float o0 = (v0-mean)*rstd*g[t]     + bta[t];
    float o1 = (v1-mean)*rstd*g[t+256] + bta[t+256];
    if (out) { out[row*DM+t] = o0; out[row*DM+t+256] = o1; }
    if (outb){ outb[row*DM+t] = f2bf(o0); outb[row*DM+t+256] = f2bf(o1); }
}

__launch_bounds__(256)
__global__ void gate_ln_kernel(const float* __restrict__ ha, const float* __restrict__ hb,
                               const float* __restrict__ mo,
                               const float* __restrict__ g, const float* __restrict__ bta,
                               float* __restrict__ out, ushort_t* __restrict__ outb, float eps)
{
    size_t row = blockIdx.x;
    int t = threadIdx.x;
    size_t i0 = row*DM + t, i1 = i0 + 256;
    float a0 = ha[i0], a1 = ha[i1];
    float v0 = fmaf(a0, hb[i0], a0) + mo[i0];
    float v1 = fmaf(a1, hb[i1], a1) + mo[i1];
    float s = v0+v1, q = v0*v0 + v1*v1;
    #pragma unroll
    for (int o=32;o>0;o>>=1){ s += __shfl_xor(s,o); q += __shfl_xor(q,o); }
    __shared__ float ss[4], sq[4];
    int w = t>>6;
    if ((t&63)==0){ ss[w]=s; sq[w]=q; }
    __syncthreads();
    s = ss[0]+ss[1]+ss[2]+ss[3];
    q = sq[0]+sq[1]+sq[2]+sq[3];
    float mean = s * (1.f/DM);
    float var  = q * (1.f/DM) - mean*mean;
    var = var < 0.f ? 0.f : var;
    float rstd = rsqrtf(var + eps);
    float o0 = (v0-mean)*rstd*g[t]     + bta[t];
    float o1 = (v1-mean)*rstd*g[t+256] + bta[t+256];
    out[i0] = o0; out[i1] = o1;
    outb[row*DM+t] = f2bf(o0); outb[row*DM+t+256] = f2bf(o1);
}

// ================= host side =================
static void launch_bgemm(int epi, const ushort_t* A, int lda, const ushort_t* W,
                         const float* bias, const float* emul,
                         float* C, ushort_t* Cb, int ldc, int Mrows, int Ngrid, int K,
                         int Nvalid, int accf, hipStream_t s)
{
    dim3 g(Ngrid/128, Mrows/128, 1);
    switch (epi) {
    case 0: bgemm<0><<<g,256,0,s>>>(A,lda,W,bias,emul,C,Cb,ldc,K,Nvalid,accf,0); break;
    case 2: bgemm<2><<<g,256,0,s>>>(A,lda,W,bias,emul,C,Cb,ldc,K,Nvalid,accf,0); break;
    case 3: bgemm<3><<<g,256,0,s>>>(A,lda,W,bias,emul,C,Cb,ldc,K,Nvalid,accf,0); break;
    case 4: bgemm<4><<<g,256,0,s>>>(A,lda,W,bias,emul,C,Cb,ldc,K,Nvalid,accf,0); break;
    case 5: bgemm<5><<<g,256,0,s>>>(A,lda,W,bias,emul,C,Cb,ldc,K,Nvalid,accf,0); break;
    }
}

static void cast4(const float* in, ushort_t* out, int n, hipStream_t s)
{
    cast4_kernel<<<(n/4 + 255)/256, 256, 0, s>>>(in, out, n/4);
}

extern "C" void kernel_launch(void* const* d_in, const int* in_sizes, int n_in,
                              void* d_out, int out_size, void* d_ws, size_t ws_size,
                              hipStream_t stream)
{
    const float* x        = (const float*)d_in[0];
    const float* fre      = (const float*)d_in[1];
    const float* fim      = (const float*)d_in[2];
    const float* cutoff   = (const float*)d_in[3];
    const float* ln0_g    = (const float*)d_in[4];
    const float* ln0_b    = (const float*)d_in[5];
    const float* l1_w     = (const float*)d_in[6];
    const float* l1_b     = (const float*)d_in[7];
    const float* l2_w     = (const float*)d_in[8];
    const float* l2_b     = (const float*)d_in[9];
    const float* in_w     = (const float*)d_in[10];
    const float* conv_w   = (const float*)d_in[11];
    const float* conv_b   = (const float*)d_in[12];
    const float* xproj_w  = (const float*)d_in[13];
    const float* dt_w     = (const float*)d_in[14];
    const float* dt_b     = (const float*)d_in[15];
    const float* A_log    = (const float*)d_in[16];
    const float* Dp       = (const float*)d_in[17];
    const float* out_w    = (const float*)d_in[18];
    const float* ln1_g    = (const float*)d_in[19];
    const float* ln1_b    = (const float*)d_in[20];
    const float* d1_w     = (const float*)d_in[21];
    const float* d1_b     = (const float*)d_in[22];
    const float* d2_w     = (const float*)d_in[23];
    const float* d2_b     = (const float*)d_in[24];
    const float* ln2_g    = (const float*)d_in[25];
    const float* ln2_b    = (const float*)d_in[26];
    const float* ffn_w1   = (const float*)d_in[27];
    const float* ffn_b1   = (const float*)d_in[28];
    const float* ffn_w2   = (const float*)d_in[29];
    const float* ffn_b2   = (const float*)d_in[30];
    const float* ffn_ln_g = (const float*)d_in[31];
    const float* ffn_ln_b = (const float*)d_in[32];

    float* ws = (float*)d_ws;
    float* RK = ws;                                  // 1024
    float* WFf = RK + 1024;                          // bf16 weight pool backing
    ushort_t* MCb  = (ushort_t*)WFf;                 // 512*512
    ushort_t* L1b  = MCb  + 262144;
    ushort_t* L2b  = L1b  + 262144;
    ushort_t* INb  = L2b  + 262144;                  // 2048*512
    ushort_t* OUTb = INb  + 1048576;                 // 512*1024
    ushort_t* D1b  = OUTb + 524288;
    ushort_t* D2b  = D1b  + 262144;
    ushort_t* F1b  = D2b  + 262144;                  // 2048*512
    ushort_t* F2b  = F1b  + 1048576;                 // 512*2048
    ushort_t* XPb  = F2b  + 1048576;                 // 128*1024
    ushort_t* DTWb = XPb  + 131072;                  // 1024*32
    float* P = WFf + 2572288;                        // 20,971,520-float multi-stage pool
    // -- stage 1-2 --
    ushort_t* XNb = (ushort_t*)P;                    // bf16 xn
    ushort_t* XGb = (ushort_t*)(P + 2097152);        // bf16 xg
    float*    T1a = P + 4194304;                     // fp32 l1-out
    ushort_t* XBx = (ushort_t*)(P + 8388608);        // bf16 x
    // -- stage 3 --
    float*    XDbc = P;                              // 3BL*32 fp32 (B/C)     786,432
    ushort_t* DTi  = (ushort_t*)(P + 786432);        // 3BL*32 bf16           393,216 f
    ushort_t* YG3b = (ushort_t*)(P + 1179648);       // 3*BL*DI bf16       12,582,912 f
    float*    XDP  = P + 13762560;                   // 4*3BL*64 transient  6,291,456
    float*    HOUT = P + 13762560;                   // 3,145,728 (after XDP dead)
    float*    APR  = P + 16908288;                   // 3,145,728 -> ends 20,054,016
    // -- stage 4-6 --
    float*    MOf = P;                               // fp32 mo
    ushort_t* MOb = (ushort_t*)(P + 4194304);        // bf16 mo
    float*    T2g = P + 6291456;                     // fp32 hb
    float*    T1g = P + 10485760;                    // fp32 ha, then ffn2-out
    float*    HSf = P + 14680064;                    // fp32 hs
    ushort_t* HSb = (ushort_t*)(P + 18874368);       // bf16 hs
    // -- large bf16 activations --
    float* XZ1f = P + 20971520;
    ushort_t* XZ1b = (ushort_t*)XZ1f;                // BL*2048 bf16; later FFN hidden
    ushort_t* FHb  = XZ1b;
    float* XZ2f = XZ1f + 8388608;
    ushort_t* XZ2b = (ushort_t*)XZ2f;                // BL*2048 bf16
    float* XC3f = XZ2f + 8388608;
    ushort_t* XC3b = (ushort_t*)XC3f;                // 3*BL*DI bf16 conv-out
    float*    XI   = XC3f;                           // fp32 xi (dead before conv)
    ushort_t* YGb  = (ushort_t*)XC3f;                // bf16 summed yg (after XC dead)
    float* MS = XC3f + 12582912;                     // fp32 out_proj result
    float* OUT = (float*)d_out;

    // 0) weight conversions
    cast4(l1_w,  L1b,  512*512,  stream);
    cast4(l2_w,  L2b,  512*512,  stream);
    cast4(in_w,  INb,  2048*512, stream);
    cast4(out_w, OUTb, 512*1024, stream);
    cast4(d1_w,  D1b,  512*512,  stream);
    cast4(d2_w,  D2b,  512*512,  stream);
    cast4(ffn_w1,F1b,  2048*512, stream);
    cast4(ffn_w2,F2b,  512*2048, stream);
    cast4(dt_w,  DTWb, 1024*32,  stream);
    cast_xproj_kernel<<<512,256,0,stream>>>(xproj_w, XPb);
    cast4(x, XBx, BL*DM, stream);

    // 1) circulant bf16 GEMM, then LN(xi + x) -> bf16 xn
    build_filter_kernel<<<512,256,0,stream>>>(fre, fim, cutoff, RK);
    circ_expand_kernel<<<512,512,0,stream>>>(RK, MCb);
    launch_bgemm(0, XBx,DM, MCb, nullptr, nullptr, XI,nullptr, DM, BL, DM, DM, DM, 0, stream);
    ln_kernel<<<BL,256,0,stream>>>(XI, x, ln0_g, ln0_b, nullptr, XNb, 1e-5f);

    // 2) xg = (xn@l1^T+b1) * silu(xn@l2^T+b2) -> bf16 XGb
    launch_bgemm(0, XNb,DM, L1b, l1_b, nullptr, T1a,nullptr, DM, BL, DM, DM, DM, 0, stream);
    launch_bgemm(4, XNb,DM, L2b, l2_b, T1a, nullptr,XGb, DM, BL, DM, DM, DM, 0, stream);

    // 3) mamba: two in_proj (z-half pre-silu'd), batched conv/xproj/scan
    launch_bgemm(5, XGb,DM, INb, nullptr, nullptr, nullptr,XZ1b, 2048, BL, 2048, DM, 2048, 0, stream);
    launch_bgemm(5, XBx,DM, INb, nullptr, nullptr, nullptr,XZ2b, 2048, BL, 2048, DM, 2048, 0, stream);
    conv3_kernel<<<(3*BL*DI)/256,256,0,stream>>>(XZ1b, XZ2b, conv_w, conv_b, XC3b);
    bgemm<0><<<dim3(1, (3*BL)/128, 4),256,0,stream>>>(XC3b,DI, XPb, nullptr, nullptr,
                                                      XDP,nullptr, 64, DI/4, 64, 0, (size_t)3*BL*64);
    reduce_xd_kernel<<<(3*BL*64)/256,256,0,stream>>>(XDP, XDbc, DTi);
    {
        dim3 ga(DI/256, NC, 12);
        scan3_a<<<ga,256,0,stream>>>(XC3b, XDbc, DTi, DTWb, dt_b, A_log, HOUT, APR);
        scan3_b<<<(3*BATCH*DI*DS)/256,256,0,stream>>>(HOUT, APR);
        scan3_c<<<ga,256,0,stream>>>(XC3b, XDbc, DTi, XZ1b, XZ2b, DTWb, dt_b, A_log, Dp, HOUT, YG3b);
    }
    sum3_kernel<<<(BL*DI)/256,256,0,stream>>>(YG3b, YGb);
    launch_bgemm(0, YGb,DI, OUTb, nullptr, nullptr, MS,nullptr, DM, BL, DM, DI, DM, 0, stream);

    // 4) mo = LN(m1+m2+m3)
    ln_kernel<<<BL,256,0,stream>>>(MS, nullptr, ln1_g, ln1_b, MOf, MOb, 1e-12f);

    // 5) ha/hb gate + LN -> hs
    launch_bgemm(3, MOb,DM, D1b, d1_b, nullptr, T2g,nullptr, DM, BL, DM, DM, DM, 0, stream);  // hb
    launch_bgemm(0, MOb,DM, D2b, d2_b, nullptr, T1g,nullptr, DM, BL, DM, DM, DM, 0, stream);  // ha
    gate_ln_kernel<<<BL,256,0,stream>>>(T1g, T2g, MOf, ln2_g, ln2_b, HSf, HSb, 1e-12f);

    // 6) FFN
    launch_bgemm(2, HSb,DM, F1b, ffn_b1, nullptr, nullptr,FHb, 2048, BL, 2048, DM, 2048, 0, stream);
    launch_bgemm(0, FHb,2048, F2b, ffn_b2, nullptr, T1g,nullptr, DM, BL, DM, 2048, DM, 0, stream);
    ln_kernel<<<BL,256,0,stream>>>(T1g, HSf, ffn_ln_g, ffn_ln_b, OUT, nullptr, 1e-12f);
}